// Round 3
// baseline (288.347 us; speedup 1.0000x reference)
//
#include <hip/hip_runtime.h>
#include <hip/hip_bf16.h>

typedef short bf16x8 __attribute__((ext_vector_type(8)));
typedef float f32x4  __attribute__((ext_vector_type(4)));

typedef __attribute__((address_space(3))) void lds_t;
typedef __attribute__((address_space(1))) void gbl_t;

#define MFMA16(a,b,c) __builtin_amdgcn_mfma_f32_16x16x32_bf16((a),(b),(c),0,0,0)

__device__ __forceinline__ unsigned short f2bf(float f) {
    __hip_bfloat16 h = __float2bfloat16(f);
    return __builtin_bit_cast(unsigned short, h);
}
__device__ __forceinline__ float bf2f(unsigned short u) {
    __hip_bfloat16 h = __builtin_bit_cast(__hip_bfloat16, u);
    return __bfloat162float(h);
}

// Split f32 rows [R][1024] -> dst [R][2048] = [hi | lo] bf16.  float4 vectorized.
__global__ void prep_split_rows(const float* __restrict__ src,
                                unsigned short* __restrict__ dst, int total4) {
    for (int idx = blockIdx.x * blockDim.x + threadIdx.x; idx < total4;
         idx += gridDim.x * blockDim.x) {
        int base = idx * 4;
        int m = base >> 10, c = base & 1023;
        float4 v = *reinterpret_cast<const float4*>(src + base);
        ushort4 hi, lo;
        hi.x = f2bf(v.x); lo.x = f2bf(v.x - bf2f(hi.x));
        hi.y = f2bf(v.y); lo.y = f2bf(v.y - bf2f(hi.y));
        hi.z = f2bf(v.z); lo.z = f2bf(v.z - bf2f(hi.z));
        hi.w = f2bf(v.w); lo.w = f2bf(v.w - bf2f(hi.w));
        *reinterpret_cast<ushort4*>(dst + (size_t)m * 2048 + c) = hi;
        *reinterpret_cast<ushort4*>(dst + (size_t)m * 2048 + 1024 + c) = lo;
    }
}

// w_qkv [3072][1024] with einops row permute: output row n = which*1024 + h*64 + d
// reads source row d*48 + which*16 + h.  dst [3072][2048] = [hi | lo]
__global__ void prep_split_wqkv(const float* __restrict__ w,
                                unsigned short* __restrict__ dst) {
    for (int idx = blockIdx.x * blockDim.x + threadIdx.x; idx < 3072 * 256;
         idx += gridDim.x * blockDim.x) {
        int base = idx * 4;
        int n = base >> 10, c = base & 1023;
        int d = n & 63, which = n >> 10, h = (n >> 6) & 15;
        int srow = d * 48 + which * 16 + h;
        float4 v = *reinterpret_cast<const float4*>(w + (size_t)srow * 1024 + c);
        ushort4 hi, lo;
        hi.x = f2bf(v.x); lo.x = f2bf(v.x - bf2f(hi.x));
        hi.y = f2bf(v.y); lo.y = f2bf(v.y - bf2f(hi.y));
        hi.z = f2bf(v.z); lo.z = f2bf(v.z - bf2f(hi.z));
        hi.w = f2bf(v.w); lo.w = f2bf(v.w - bf2f(hi.w));
        *reinterpret_cast<ushort4*>(dst + (size_t)n * 2048 + c) = hi;
        *reinterpret_cast<ushort4*>(dst + (size_t)n * 2048 + 1024 + c) = lo;
    }
}

// ============================================================================
// 256x256 8-phase split-GEMM for QKV.  Virtual K = 3072 (96 steps of 32) over
// A=[hi|hi|lo], B=[hi|lo|hi] (stored [rows][2048]).  512 thr / 8 waves (2Mx4N),
// per-wave 128x64 output (acc[8][4]).  LDS: per operand a 4-slot ring of
// (256 rows x 32 cols) bf16 = 16KB/slot; slot(s) = s&3.  Stage slot s+2 while
// computing s (counted vmcnt(4), never 0 in steady state).  16B-chunk XOR
// swizzle chunk^= (row>>1)&3 (inverse-swizzled global source, swizzled read):
// 2-way bank aliasing = free.  2 phases x 16 MFMA per K-step, setprio wrapped.
// ============================================================================
__global__ __launch_bounds__(512, 2) void gemm256_split(
    const unsigned short* __restrict__ A, const unsigned short* __restrict__ B,
    unsigned short* __restrict__ outQ, unsigned short* __restrict__ outK,
    unsigned short* __restrict__ outV) {
    __shared__ unsigned short lds[65536];  // 128 KB: A ring [0,32768) shorts, B ring [32768,65536)
    const int tid = threadIdx.x;
    const int wid = tid >> 6, lane = tid & 63;
    const int lrow = lane & 15, lgrp = lane >> 4;
    const int wr = wid >> 2, wc = wid & 3;
    const int mtile = blockIdx.y * 256, ntile = blockIdx.x * 256;

    // LDS read offsets (shorts).  Row = 32 shorts (64B); chunk = 8 shorts (16B).
    // Swizzled chunk depends only on lrow (i*16 and wave offsets are 0 mod 8 rows).
    const int csw = lgrp ^ ((lrow >> 1) & 3);
    const int aoff = (wr * 128 + lrow) * 32 + csw * 8;            // + i*512, + slot*8192
    const int boff = 32768 + (wc * 64 + lrow) * 32 + csw * 8;     // + j*512, + slot*8192

    // Staging: each wave writes 2x 1KB regions/slot; lane covers 16B linear.
    // LDS linear (row, cswz) <- global (row, cswz ^ ((row>>1)&3)).
    const int sreg = wid * 2;
    const int srow0 = sreg * 16 + (lane >> 2);
    const int srow1 = (sreg + 1) * 16 + (lane >> 2);
    const int schunk = (lane & 3) ^ ((lane >> 3) & 3);
    const int sdst0 = sreg * 512;          // shorts within slot (+512 for q=1)

    f32x4 acc[8][4];
#pragma unroll
    for (int i = 0; i < 8; ++i)
#pragma unroll
        for (int j = 0; j < 4; ++j) {
            f32x4 z = {0.f, 0.f, 0.f, 0.f};
            acc[i][j] = z;
        }

    // ---- prologue: stage steps 0,1 (segment cols = kb for kb<1024) ----
#pragma unroll
    for (int s0 = 0; s0 < 2; ++s0) {
        const int kb = s0 * 32;
        __builtin_amdgcn_global_load_lds(
            (const gbl_t*)(A + (size_t)(mtile + srow0) * 2048 + kb + schunk * 8),
            (lds_t*)(lds + s0 * 8192 + sdst0), 16, 0, 0);
        __builtin_amdgcn_global_load_lds(
            (const gbl_t*)(A + (size_t)(mtile + srow1) * 2048 + kb + schunk * 8),
            (lds_t*)(lds + s0 * 8192 + sdst0 + 512), 16, 0, 0);
        __builtin_amdgcn_global_load_lds(
            (const gbl_t*)(B + (size_t)(ntile + srow0) * 2048 + kb + schunk * 8),
            (lds_t*)(lds + 32768 + s0 * 8192 + sdst0), 16, 0, 0);
        __builtin_amdgcn_global_load_lds(
            (const gbl_t*)(B + (size_t)(ntile + srow1) * 2048 + kb + schunk * 8),
            (lds_t*)(lds + 32768 + s0 * 8192 + sdst0 + 512), 16, 0, 0);
    }
    asm volatile("s_waitcnt vmcnt(4)" ::: "memory");  // step-0 slots landed
    __syncthreads();

    for (int s = 0; s < 96; ++s) {
        const int sa = s & 3;
        const unsigned short* sbase = lds + sa * 8192;

        // ---- phase A: A-frags(8) + B j0/j1, stage A(s+2), 16 MFMA ----
        bf16x8 af[8];
#pragma unroll
        for (int i = 0; i < 8; ++i)
            af[i] = *reinterpret_cast<const bf16x8*>(sbase + aoff + i * 512);
        bf16x8 b0 = *reinterpret_cast<const bf16x8*>(sbase + boff);
        bf16x8 b1 = *reinterpret_cast<const bf16x8*>(sbase + boff + 512);
        if (s <= 93) {
            const int kb2 = (s + 2) * 32;
            const int ac2 = (kb2 < 1024) ? kb2 : kb2 - 1024;
            const int s2 = (s + 2) & 3;
            __builtin_amdgcn_global_load_lds(
                (const gbl_t*)(A + (size_t)(mtile + srow0) * 2048 + ac2 + schunk * 8),
                (lds_t*)(lds + s2 * 8192 + sdst0), 16, 0, 0);
            __builtin_amdgcn_global_load_lds(
                (const gbl_t*)(A + (size_t)(mtile + srow1) * 2048 + ac2 + schunk * 8),
                (lds_t*)(lds + s2 * 8192 + sdst0 + 512), 16, 0, 0);
        }
        __syncthreads();
        __builtin_amdgcn_s_setprio(1);
#pragma unroll
        for (int i = 0; i < 8; ++i) {
            acc[i][0] = MFMA16(af[i], b0, acc[i][0]);
            acc[i][1] = MFMA16(af[i], b1, acc[i][1]);
        }
        __builtin_amdgcn_s_setprio(0);
        __syncthreads();

        // ---- phase B: B j2/j3, stage B(s+2), 16 MFMA ----
        bf16x8 b2 = *reinterpret_cast<const bf16x8*>(sbase + boff + 1024);
        bf16x8 b3 = *reinterpret_cast<const bf16x8*>(sbase + boff + 1536);
        if (s <= 93) {
            const int kb2 = (s + 2) * 32;
            const int bc2 = (kb2 < 2048) ? kb2 : kb2 - 2048;
            const int s2 = (s + 2) & 3;
            __builtin_amdgcn_global_load_lds(
                (const gbl_t*)(B + (size_t)(ntile + srow0) * 2048 + bc2 + schunk * 8),
                (lds_t*)(lds + 32768 + s2 * 8192 + sdst0), 16, 0, 0);
            __builtin_amdgcn_global_load_lds(
                (const gbl_t*)(B + (size_t)(ntile + srow1) * 2048 + bc2 + schunk * 8),
                (lds_t*)(lds + 32768 + s2 * 8192 + sdst0 + 512), 16, 0, 0);
        }
        __syncthreads();
        __builtin_amdgcn_s_setprio(1);
#pragma unroll
        for (int i = 0; i < 8; ++i) {
            acc[i][2] = MFMA16(af[i], b2, acc[i][2]);
            acc[i][3] = MFMA16(af[i], b3, acc[i][3]);
        }
        __builtin_amdgcn_s_setprio(0);
        // ---- end-of-step: counted wait for next step's slots, never 0 mid-loop ----
        if (s < 95) {
            if (s <= 93)
                asm volatile("s_waitcnt vmcnt(4)" ::: "memory");
            else
                asm volatile("s_waitcnt vmcnt(0)" ::: "memory");
            __syncthreads();
        }
    }

    // ---- epilogue: scatter bf16 into q/k/v [bh][t][64] ----
#pragma unroll
    for (int i = 0; i < 8; ++i) {
#pragma unroll
        for (int j = 0; j < 4; ++j) {
#pragma unroll
            for (int r = 0; r < 4; ++r) {
                float v = acc[i][j][r];
                int m = mtile + wr * 128 + i * 16 + lgrp * 4 + r;
                int n = ntile + wc * 64 + j * 16 + lrow;
                int which = n >> 10;
                int hh = (n >> 6) & 15;
                int d = n & 63;
                int b = m >> 10, t = m & 1023;
                unsigned short* dstp =
                    (which == 0) ? outQ : ((which == 1) ? outK : outV);
                dstp[((size_t)((b << 4) + hh) * 1024 + t) * 64 + d] = f2bf(v);
            }
        }
    }
}

// Split GEMM (128x128 tile, m97 structure) — used for the out-projection only.
__global__ __launch_bounds__(256) void gemm_split_out(
    const unsigned short* __restrict__ A, const unsigned short* __restrict__ B,
    float* __restrict__ outF, int N) {
    __shared__ unsigned short As[128 * 32];
    __shared__ unsigned short Bs[128 * 32];
    const int tid = threadIdx.x;
    const int w = tid >> 6, lane = tid & 63;
    const int lrow = lane & 15, lgrp = lane >> 4;
    const int wrow = w >> 1, wcol = w & 1;
    const int mtile = blockIdx.y * 128, ntile = blockIdx.x * 128;

    f32x4 acc[4][4];
#pragma unroll
    for (int i = 0; i < 4; i++)
#pragma unroll
        for (int j = 0; j < 4; j++) {
            f32x4 z = {0.f, 0.f, 0.f, 0.f};
            acc[i][j] = z;
        }

    const int srow = w * 32 + (lane >> 2);
    const int scol = (lane & 3) * 8;

    for (int ks = 0; ks < 96; ++ks) {
        const int kb = ks * 32;
        const int ac = (kb < 1024) ? kb : kb - 1024;
        const int bc = (kb < 2048) ? kb : kb - 2048;
        __syncthreads();
#pragma unroll
        for (int i = 0; i < 2; ++i) {
            const unsigned short* ga =
                A + (size_t)(mtile + srow + i * 16) * 2048 + ac + scol;
            __builtin_amdgcn_global_load_lds((const gbl_t*)ga,
                                             (lds_t*)(As + w * 1024 + i * 512),
                                             16, 0, 0);
        }
#pragma unroll
        for (int i = 0; i < 2; ++i) {
            const unsigned short* gb =
                B + (size_t)(ntile + srow + i * 16) * 2048 + bc + scol;
            __builtin_amdgcn_global_load_lds((const gbl_t*)gb,
                                             (lds_t*)(Bs + w * 1024 + i * 512),
                                             16, 0, 0);
        }
        asm volatile("s_waitcnt vmcnt(0)" ::: "memory");
        __syncthreads();

        bf16x8 af[4], bfv[4];
#pragma unroll
        for (int i = 0; i < 4; i++)
            af[i] = *reinterpret_cast<const bf16x8*>(
                As + (wrow * 64 + i * 16 + lrow) * 32 + lgrp * 8);
#pragma unroll
        for (int j = 0; j < 4; j++)
            bfv[j] = *reinterpret_cast<const bf16x8*>(
                Bs + (wcol * 64 + j * 16 + lrow) * 32 + lgrp * 8);
#pragma unroll
        for (int i = 0; i < 4; i++)
#pragma unroll
            for (int j = 0; j < 4; j++)
                acc[i][j] = MFMA16(af[i], bfv[j], acc[i][j]);
    }

#pragma unroll
    for (int i = 0; i < 4; i++)
#pragma unroll
        for (int j = 0; j < 4; j++)
#pragma unroll
            for (int r = 0; r < 4; r++) {
                int m = mtile + wrow * 64 + i * 16 + lgrp * 4 + r;
                int n = ntile + wcol * 64 + j * 16 + lrow;
                outF[(size_t)m * N + n] = acc[i][j][r];
            }
}

// V [bh][1024][64] -> V^T [bh][64][1024], LDS-tiled, coalesced both sides.
__global__ __launch_bounds__(256) void transpose_v(
    const unsigned short* __restrict__ Vb, unsigned short* __restrict__ Vtg) {
    __shared__ unsigned short L[64][72];
    const int tt = blockIdx.x, bh = blockIdx.y;
    const int tid = threadIdx.x;
#pragma unroll
    for (int e = 0; e < 2; ++e) {
        int chunk = e * 256 + tid;
        int r = chunk >> 3, c = (chunk & 7) * 8;
        uint4 v = *reinterpret_cast<const uint4*>(
            Vb + ((size_t)bh * 1024 + tt * 64 + r) * 64 + c);
        *reinterpret_cast<uint4*>(&L[r][c]) = v;
    }
    __syncthreads();
#pragma unroll
    for (int e = 0; e < 2; ++e) {
        int chunk = e * 256 + tid;
        int d = chunk >> 3, t0 = (chunk & 7) * 8;
        unsigned short tmp[8];
#pragma unroll
        for (int u = 0; u < 8; ++u) tmp[u] = L[t0 + u][d];
        *reinterpret_cast<uint4*>(Vtg + ((size_t)bh * 64 + d) * 1024 + tt * 64 +
                                  t0) = *reinterpret_cast<const uint4*>(tmp);
    }
}

// Flash attention, bf16 MFMA 16x16x32.  4 waves x 16 q-rows (QBLK=64), KVBLK=64.
// K and V^T double-buffered in LDS via global_load_lds, XOR chunk-swizzle.
__global__ __launch_bounds__(256) void attn_kernel(
    const unsigned short* __restrict__ Qb, const unsigned short* __restrict__ Kb,
    const unsigned short* __restrict__ Vtg, const float* __restrict__ rel_bias,
    unsigned short* __restrict__ A3) {
    const int qt = blockIdx.x;  // 0..15
    const int bh = blockIdx.y;  // 0..63
    const int b = bh >> 4, h = bh & 15;
    const int tid = threadIdx.x;
    const int w = tid >> 6, lane = tid & 63;
    const int lrow = lane & 15, lgrp = lane >> 4;

    __shared__ unsigned short Ks[2][64 * 64];
    __shared__ unsigned short Vs[2][64 * 64];
    __shared__ unsigned short Ps[4][16 * 64];
    __shared__ float Bias2[2][128];

    const unsigned short* Ktile = Kb + (size_t)bh * 1024 * 64;
    const unsigned short* Vtile = Vtg + (size_t)bh * 64 * 1024;

    const unsigned short* Qp =
        Qb + ((size_t)bh * 1024 + qt * 64 + w * 16 + lrow) * 64;
    bf16x8 qa0 = *reinterpret_cast<const bf16x8*>(Qp + lgrp * 8);
    bf16x8 qa1 = *reinterpret_cast<const bf16x8*>(Qp + 32 + lgrp * 8);

    const int sr0 = w * 16 + (lane >> 3);
    const int sc_lo = lane & 7;

    float m_run[4], l_run[4];
    f32x4 o_acc[4];
#pragma unroll
    for (int r = 0; r < 4; r++) {
        m_run[r] = -3.0e38f;
        l_run[r] = 0.f;
    }
#pragma unroll
    for (int n = 0; n < 4; n++) {
        f32x4 z = {0.f, 0.f, 0.f, 0.f};
        o_acc[n] = z;
    }

    const int i_loc = w * 16 + lgrp * 4;

    {
#pragma unroll
        for (int i = 0; i < 2; ++i) {
            int r = sr0 + i * 8;
            int c = sc_lo ^ (r & 7);
            __builtin_amdgcn_global_load_lds(
                (const gbl_t*)(Ktile + (size_t)r * 64 + c * 8),
                (lds_t*)(&Ks[0][0] + w * 1024 + i * 512), 16, 0, 0);
            __builtin_amdgcn_global_load_lds(
                (const gbl_t*)(Vtile + (size_t)r * 1024 + c * 8),
                (lds_t*)(&Vs[0][0] + w * 1024 + i * 512), 16, 0, 0);
        }
        if (tid < 128) {
            int rowi = 0 - qt * 64 + 960 + tid;
            rowi = (rowi < 2046) ? rowi : 2046;
            Bias2[0][tid] = rel_bias[(size_t)rowi * 16 + h];
        }
        asm volatile("s_waitcnt vmcnt(0)" ::: "memory");
        __syncthreads();
    }

    for (int kv = 0; kv < 16; ++kv) {
        const int cur = kv & 1;
        if (kv < 15) {
            const int j0n = (kv + 1) * 64;
#pragma unroll
            for (int i = 0; i < 2; ++i) {
                int r = sr0 + i * 8;
                int c = sc_lo ^ (r & 7);
                __builtin_amdgcn_global_load_lds(
                    (const gbl_t*)(Ktile + (size_t)(j0n + r) * 64 + c * 8),
                    (lds_t*)(&Ks[cur ^ 1][0] + w * 1024 + i * 512), 16, 0, 0);
                __builtin_amdgcn_global_load_lds(
                    (const gbl_t*)(Vtile + (size_t)r * 1024 + j0n + c * 8),
                    (lds_t*)(&Vs[cur ^ 1][0] + w * 1024 + i * 512), 16, 0, 0);
            }
            if (tid < 128) {
                int rowi = j0n - qt * 64 + 960 + tid;
                rowi = (rowi < 2046) ? rowi : 2046;
                Bias2[cur ^ 1][tid] = rel_bias[(size_t)rowi * 16 + h];
            }
        }

        const unsigned short* kbuf = &Ks[cur][0];
        f32x4 s[4];
        __builtin_amdgcn_s_setprio(1);
#pragma unroll
        for (int f = 0; f < 4; ++f) {
            int krow = f * 16 + lrow;
            int sw0 = (lgrp ^ (lrow & 7)) * 8;
            int sw1 = ((4 | lgrp) ^ (lrow & 7)) * 8;
            bf16x8 kb0 = *reinterpret_cast<const bf16x8*>(kbuf + krow * 64 + sw0);
            bf16x8 kb1 = *reinterpret_cast<const bf16x8*>(kbuf + krow * 64 + sw1);
            f32x4 z = {0.f, 0.f, 0.f, 0.f};
            z = MFMA16(qa0, kb0, z);
            z = MFMA16(qa1, kb1, z);
            s[f] = z;
        }
        __builtin_amdgcn_s_setprio(0);

        float p[4][4];
        float tmax[4];
#pragma unroll
        for (int r = 0; r < 4; r++) tmax[r] = -3.0e38f;
#pragma unroll
        for (int f = 0; f < 4; ++f) {
            int jl = f * 16 + lrow;
#pragma unroll
            for (int r = 0; r < 4; r++) {
                float sv = s[f][r] * 0.125f + Bias2[cur][jl - (i_loc + r) + 63];
                p[f][r] = sv;
                tmax[r] = fmaxf(tmax[r], sv);
            }
        }
#pragma unroll
        for (int r = 0; r < 4; r++) {
            float t = tmax[r];
            t = fmaxf(t, __shfl_xor(t, 1));
            t = fmaxf(t, __shfl_xor(t, 2));
            t = fmaxf(t, __shfl_xor(t, 4));
            t = fmaxf(t, __shfl_xor(t, 8));
            tmax[r] = t;
        }
        float corr[4];
#pragma unroll
        for (int r = 0; r < 4; r++) {
            float nm = fmaxf(m_run[r], tmax[r]);
            corr[r] = __expf(m_run[r] - nm);
            m_run[r] = nm;
            float su = 0.f;
#pragma unroll
            for (int f = 0; f < 4; ++f) {
                float pv = __expf(p[f][r] - nm);
                p[f][r] = pv;
                su += pv;
            }
            su += __shfl_xor(su, 1);
            su += __shfl_xor(su, 2);
            su += __shfl_xor(su, 4);
            su += __shfl_xor(su, 8);
            l_run[r] = l_run[r] * corr[r] + su;
        }
#pragma unroll
        for (int n = 0; n < 4; n++)
#pragma unroll
            for (int r = 0; r < 4; r++) o_acc[n][r] *= corr[r];

#pragma unroll
        for (int f = 0; f < 4; ++f)
#pragma unroll
            for (int r = 0; r < 4; r++) {
                int prow = lgrp * 4 + r;
                int cs = (2 * f + (lrow >> 3)) ^ (prow & 7);
                Ps[w][prow * 64 + cs * 8 + (lrow & 7)] = f2bf(p[f][r]);
            }

        const unsigned short* vbuf = &Vs[cur][0];
        __builtin_amdgcn_s_setprio(1);
#pragma unroll
        for (int jc = 0; jc < 2; ++jc) {
            int pc = ((4 * jc + lgrp) ^ (lrow & 7)) * 8;
            bf16x8 pa =
                *reinterpret_cast<const bf16x8*>(&Ps[w][0] + lrow * 64 + pc);
#pragma unroll
            for (int n = 0; n < 4; n++) {
                int vrow = n * 16 + lrow;
                bf16x8 vb =
                    *reinterpret_cast<const bf16x8*>(vbuf + vrow * 64 + pc);
                o_acc[n] = MFMA16(pa, vb, o_acc[n]);
            }
        }
        __builtin_amdgcn_s_setprio(0);

        if (kv < 15) {
            asm volatile("s_waitcnt vmcnt(0)" ::: "memory");
            __syncthreads();
        }
    }

#pragma unroll
    for (int n = 0; n < 4; n++) {
#pragma unroll
        for (int r = 0; r < 4; r++) {
            float val = o_acc[n][r] / l_run[r];
            int ia = qt * 64 + w * 16 + lgrp * 4 + r;
            size_t m = (size_t)b * 1024 + ia;
            int col = h * 64 + n * 16 + lrow;
            unsigned short hi = f2bf(val);
            float rres = val - bf2f(hi);
            A3[m * 2048 + col] = hi;
            A3[m * 2048 + 1024 + col] = f2bf(rres);
        }
    }
}

extern "C" void kernel_launch(void* const* d_in, const int* in_sizes, int n_in,
                              void* d_out, int out_size, void* d_ws,
                              size_t ws_size, hipStream_t stream) {
    const float* x = (const float*)d_in[0];
    const float* w_qkv = (const float*)d_in[1];
    const float* w_out = (const float*)d_in[2];
    const float* rel_bias = (const float*)d_in[3];
    float* out = (float*)d_out;

    char* ws = (char*)d_ws;
    size_t off = 0;
    auto alloc = [&](size_t bytes) {
        char* p = ws + off;
        off += (bytes + 255) & ~(size_t)255;
        return p;
    };
    unsigned short* A1s = (unsigned short*)alloc((size_t)4096 * 2048 * 2);
    unsigned short* W1s = (unsigned short*)alloc((size_t)3072 * 2048 * 2);
    unsigned short* Qb = (unsigned short*)alloc((size_t)64 * 1024 * 64 * 2);
    unsigned short* Kb = (unsigned short*)alloc((size_t)64 * 1024 * 64 * 2);
    unsigned short* Vb = (unsigned short*)alloc((size_t)64 * 1024 * 64 * 2);
    unsigned short* A3s = (unsigned short*)alloc((size_t)4096 * 2048 * 2);
    unsigned short* W3s = (unsigned short*)alloc((size_t)1024 * 2048 * 2);
    // V^T aliases A1s: A1s is dead after gemm256_split, transpose_v runs after.
    unsigned short* Vtg = A1s;

    hipLaunchKernelGGL(prep_split_rows, dim3(1024), dim3(256), 0, stream, x, A1s,
                       4096 * 256);
    hipLaunchKernelGGL(prep_split_wqkv, dim3(768), dim3(256), 0, stream, w_qkv,
                       W1s);
    hipLaunchKernelGGL(prep_split_rows, dim3(256), dim3(256), 0, stream, w_out,
                       W3s, 1024 * 256);
    hipLaunchKernelGGL(gemm256_split, dim3(12, 16), dim3(512), 0, stream, A1s,
                       W1s, Qb, Kb, Vb);
    hipLaunchKernelGGL(transpose_v, dim3(16, 64), dim3(256), 0, stream, Vb, Vtg);
    hipLaunchKernelGGL(attn_kernel, dim3(16, 64), dim3(256), 0, stream, Qb, Kb,
                       Vtg, rel_bias, A3s);
    hipLaunchKernelGGL(gemm_split_out, dim3(8, 32), dim3(256), 0, stream, A3s,
                       W3s, out, 1024);
}

// Round 4
// 244.188 us; speedup vs baseline: 1.1808x; 1.1808x over previous
//
#include <hip/hip_runtime.h>
#include <hip/hip_bf16.h>

typedef short bf16x8 __attribute__((ext_vector_type(8)));
typedef float f32x4  __attribute__((ext_vector_type(4)));

typedef __attribute__((address_space(3))) void lds_t;
typedef __attribute__((address_space(1))) void gbl_t;

#define MFMA16(a,b,c) __builtin_amdgcn_mfma_f32_16x16x32_bf16((a),(b),(c),0,0,0)

__device__ __forceinline__ unsigned short f2bf(float f) {
    __hip_bfloat16 h = __float2bfloat16(f);
    return __builtin_bit_cast(unsigned short, h);
}
__device__ __forceinline__ float bf2f(unsigned short u) {
    __hip_bfloat16 h = __builtin_bit_cast(__hip_bfloat16, u);
    return __bfloat162float(h);
}

// Split f32 rows [R][1024] -> dst [R][2048] = [hi | lo] bf16.  float4 vectorized.
__global__ void prep_split_rows(const float* __restrict__ src,
                                unsigned short* __restrict__ dst, int total4) {
    for (int idx = blockIdx.x * blockDim.x + threadIdx.x; idx < total4;
         idx += gridDim.x * blockDim.x) {
        int base = idx * 4;
        int m = base >> 10, c = base & 1023;
        float4 v = *reinterpret_cast<const float4*>(src + base);
        ushort4 hi, lo;
        hi.x = f2bf(v.x); lo.x = f2bf(v.x - bf2f(hi.x));
        hi.y = f2bf(v.y); lo.y = f2bf(v.y - bf2f(hi.y));
        hi.z = f2bf(v.z); lo.z = f2bf(v.z - bf2f(hi.z));
        hi.w = f2bf(v.w); lo.w = f2bf(v.w - bf2f(hi.w));
        *reinterpret_cast<ushort4*>(dst + (size_t)m * 2048 + c) = hi;
        *reinterpret_cast<ushort4*>(dst + (size_t)m * 2048 + 1024 + c) = lo;
    }
}

// w_qkv [3072][1024] with einops row permute: output row n = which*1024 + h*64 + d
// reads source row d*48 + which*16 + h.  dst [3072][2048] = [hi | lo]
__global__ void prep_split_wqkv(const float* __restrict__ w,
                                unsigned short* __restrict__ dst) {
    for (int idx = blockIdx.x * blockDim.x + threadIdx.x; idx < 3072 * 256;
         idx += gridDim.x * blockDim.x) {
        int base = idx * 4;
        int n = base >> 10, c = base & 1023;
        int d = n & 63, which = n >> 10, h = (n >> 6) & 15;
        int srow = d * 48 + which * 16 + h;
        float4 v = *reinterpret_cast<const float4*>(w + (size_t)srow * 1024 + c);
        ushort4 hi, lo;
        hi.x = f2bf(v.x); lo.x = f2bf(v.x - bf2f(hi.x));
        hi.y = f2bf(v.y); lo.y = f2bf(v.y - bf2f(hi.y));
        hi.z = f2bf(v.z); lo.z = f2bf(v.z - bf2f(hi.z));
        hi.w = f2bf(v.w); lo.w = f2bf(v.w - bf2f(hi.w));
        *reinterpret_cast<ushort4*>(dst + (size_t)n * 2048 + c) = hi;
        *reinterpret_cast<ushort4*>(dst + (size_t)n * 2048 + 1024 + c) = lo;
    }
}

// ============================================================================
// 256x256 split-GEMM for QKV, 4-slot LDS ring, ONE {vmcnt;barrier} per K-step.
// Virtual K = 3072 (96 steps of 32) over A=[hi|hi|lo], B=[hi|lo|hi].
// 512 thr / 8 waves (2Mx4N), per-wave 128x64 output (acc[8][4]).
// Ring: slot(s)=s&3, 16KB/slot/operand; stage slot s+2 while computing s;
// the only cross-wave dependence is "slot s+1 (issued at s-1) landed" ->
// vmcnt(4) (this step's 4 loads may remain in flight) + one barrier.
// No mid-step barriers: ring slots never alias within a step, and lockstep
// barriers at 1 block/CU have no co-resident block to hide behind (R3 lesson).
// 16B-chunk XOR swizzle chunk^=(row>>1)&3 both-sides (0 bank conflicts, R3).
// ============================================================================
__global__ __launch_bounds__(512, 2) void gemm256_split(
    const unsigned short* __restrict__ A, const unsigned short* __restrict__ B,
    unsigned short* __restrict__ outQ, unsigned short* __restrict__ outK,
    unsigned short* __restrict__ outV) {
    __shared__ unsigned short lds[65536];  // A ring [0,32768) shorts, B ring [32768,65536)
    const int tid = threadIdx.x;
    const int wid = tid >> 6, lane = tid & 63;
    const int lrow = lane & 15, lgrp = lane >> 4;
    const int wr = wid >> 2, wc = wid & 3;
    const int mtile = blockIdx.y * 256, ntile = blockIdx.x * 256;

    const int csw = lgrp ^ ((lrow >> 1) & 3);
    const int aoff = (wr * 128 + lrow) * 32 + csw * 8;         // + i*512, + slot*8192
    const int boff = 32768 + (wc * 64 + lrow) * 32 + csw * 8;  // + j*512, + slot*8192

    const int sreg = wid * 2;
    const int srow0 = sreg * 16 + (lane >> 2);
    const int srow1 = (sreg + 1) * 16 + (lane >> 2);
    const int schunk = (lane & 3) ^ ((lane >> 3) & 3);
    const int sdst0 = sreg * 512;

    f32x4 acc[8][4];
#pragma unroll
    for (int i = 0; i < 8; ++i)
#pragma unroll
        for (int j = 0; j < 4; ++j) {
            f32x4 z = {0.f, 0.f, 0.f, 0.f};
            acc[i][j] = z;
        }

    // ---- prologue: stage steps 0,1 ----
#pragma unroll
    for (int s0 = 0; s0 < 2; ++s0) {
        const int kb = s0 * 32;
        __builtin_amdgcn_global_load_lds(
            (const gbl_t*)(A + (size_t)(mtile + srow0) * 2048 + kb + schunk * 8),
            (lds_t*)(lds + s0 * 8192 + sdst0), 16, 0, 0);
        __builtin_amdgcn_global_load_lds(
            (const gbl_t*)(A + (size_t)(mtile + srow1) * 2048 + kb + schunk * 8),
            (lds_t*)(lds + s0 * 8192 + sdst0 + 512), 16, 0, 0);
        __builtin_amdgcn_global_load_lds(
            (const gbl_t*)(B + (size_t)(ntile + srow0) * 2048 + kb + schunk * 8),
            (lds_t*)(lds + 32768 + s0 * 8192 + sdst0), 16, 0, 0);
        __builtin_amdgcn_global_load_lds(
            (const gbl_t*)(B + (size_t)(ntile + srow1) * 2048 + kb + schunk * 8),
            (lds_t*)(lds + 32768 + s0 * 8192 + sdst0 + 512), 16, 0, 0);
    }
    asm volatile("s_waitcnt vmcnt(4)" ::: "memory");  // step-0 slots landed
    __syncthreads();

    for (int s = 0; s < 96; ++s) {
        const int sa = s & 3;
        const unsigned short* sbase = lds + sa * 8192;

        // frags for this step (slot s is ready; reads race nothing)
        bf16x8 af[8];
#pragma unroll
        for (int i = 0; i < 8; ++i)
            af[i] = *reinterpret_cast<const bf16x8*>(sbase + aoff + i * 512);
        bf16x8 b0 = *reinterpret_cast<const bf16x8*>(sbase + boff);
        bf16x8 b1 = *reinterpret_cast<const bf16x8*>(sbase + boff + 512);

        // stage A(s+2) into slot (s+2)&3 — no reader until 2 barriers from now
        if (s <= 93) {
            const int kb2 = (s + 2) * 32;
            const int ac2 = (kb2 < 1024) ? kb2 : kb2 - 1024;
            const int s2 = (s + 2) & 3;
            __builtin_amdgcn_global_load_lds(
                (const gbl_t*)(A + (size_t)(mtile + srow0) * 2048 + ac2 + schunk * 8),
                (lds_t*)(lds + s2 * 8192 + sdst0), 16, 0, 0);
            __builtin_amdgcn_global_load_lds(
                (const gbl_t*)(A + (size_t)(mtile + srow1) * 2048 + ac2 + schunk * 8),
                (lds_t*)(lds + s2 * 8192 + sdst0 + 512), 16, 0, 0);
        }
        __builtin_amdgcn_s_setprio(1);
#pragma unroll
        for (int i = 0; i < 8; ++i) {
            acc[i][0] = MFMA16(af[i], b0, acc[i][0]);
            acc[i][1] = MFMA16(af[i], b1, acc[i][1]);
        }
        __builtin_amdgcn_s_setprio(0);

        bf16x8 b2 = *reinterpret_cast<const bf16x8*>(sbase + boff + 1024);
        bf16x8 b3 = *reinterpret_cast<const bf16x8*>(sbase + boff + 1536);
        if (s <= 93) {
            const int kb2 = (s + 2) * 32;
            const int bc2 = (kb2 < 2048) ? kb2 : kb2 - 2048;
            const int s2 = (s + 2) & 3;
            __builtin_amdgcn_global_load_lds(
                (const gbl_t*)(B + (size_t)(ntile + srow0) * 2048 + bc2 + schunk * 8),
                (lds_t*)(lds + 32768 + s2 * 8192 + sdst0), 16, 0, 0);
            __builtin_amdgcn_global_load_lds(
                (const gbl_t*)(B + (size_t)(ntile + srow1) * 2048 + bc2 + schunk * 8),
                (lds_t*)(lds + 32768 + s2 * 8192 + sdst0 + 512), 16, 0, 0);
        }
        __builtin_amdgcn_s_setprio(1);
#pragma unroll
        for (int i = 0; i < 8; ++i) {
            acc[i][2] = MFMA16(af[i], b2, acc[i][2]);
            acc[i][3] = MFMA16(af[i], b3, acc[i][3]);
        }
        __builtin_amdgcn_s_setprio(0);

        // ---- the ONE sync per step: slot s+1 (issued at step s-1) must land.
        // vmcnt(4): this step's own 4 loads may stay in flight (never drain to 0).
        if (s < 95) {
            if (s <= 93)
                asm volatile("s_waitcnt vmcnt(4)" ::: "memory");
            else
                asm volatile("s_waitcnt vmcnt(0)" ::: "memory");
            __syncthreads();
        }
    }

    // ---- epilogue: scatter bf16 into q/k/v [bh][t][64] ----
#pragma unroll
    for (int i = 0; i < 8; ++i) {
#pragma unroll
        for (int j = 0; j < 4; ++j) {
#pragma unroll
            for (int r = 0; r < 4; ++r) {
                float v = acc[i][j][r];
                int m = mtile + wr * 128 + i * 16 + lgrp * 4 + r;
                int n = ntile + wc * 64 + j * 16 + lrow;
                int which = n >> 10;
                int hh = (n >> 6) & 15;
                int d = n & 63;
                int b = m >> 10, t = m & 1023;
                unsigned short* dstp =
                    (which == 0) ? outQ : ((which == 1) ? outK : outV);
                dstp[((size_t)((b << 4) + hh) * 1024 + t) * 64 + d] = f2bf(v);
            }
        }
    }
}

// Split GEMM (128x128 tile, m97 structure) — used for the out-projection only.
__global__ __launch_bounds__(256) void gemm_split_out(
    const unsigned short* __restrict__ A, const unsigned short* __restrict__ B,
    float* __restrict__ outF, int N) {
    __shared__ unsigned short As[128 * 32];
    __shared__ unsigned short Bs[128 * 32];
    const int tid = threadIdx.x;
    const int w = tid >> 6, lane = tid & 63;
    const int lrow = lane & 15, lgrp = lane >> 4;
    const int wrow = w >> 1, wcol = w & 1;
    const int mtile = blockIdx.y * 128, ntile = blockIdx.x * 128;

    f32x4 acc[4][4];
#pragma unroll
    for (int i = 0; i < 4; i++)
#pragma unroll
        for (int j = 0; j < 4; j++) {
            f32x4 z = {0.f, 0.f, 0.f, 0.f};
            acc[i][j] = z;
        }

    const int srow = w * 32 + (lane >> 2);
    const int scol = (lane & 3) * 8;

    for (int ks = 0; ks < 96; ++ks) {
        const int kb = ks * 32;
        const int ac = (kb < 1024) ? kb : kb - 1024;
        const int bc = (kb < 2048) ? kb : kb - 2048;
        __syncthreads();
#pragma unroll
        for (int i = 0; i < 2; ++i) {
            const unsigned short* ga =
                A + (size_t)(mtile + srow + i * 16) * 2048 + ac + scol;
            __builtin_amdgcn_global_load_lds((const gbl_t*)ga,
                                             (lds_t*)(As + w * 1024 + i * 512),
                                             16, 0, 0);
        }
#pragma unroll
        for (int i = 0; i < 2; ++i) {
            const unsigned short* gb =
                B + (size_t)(ntile + srow + i * 16) * 2048 + bc + scol;
            __builtin_amdgcn_global_load_lds((const gbl_t*)gb,
                                             (lds_t*)(Bs + w * 1024 + i * 512),
                                             16, 0, 0);
        }
        asm volatile("s_waitcnt vmcnt(0)" ::: "memory");
        __syncthreads();

        bf16x8 af[4], bfv[4];
#pragma unroll
        for (int i = 0; i < 4; i++)
            af[i] = *reinterpret_cast<const bf16x8*>(
                As + (wrow * 64 + i * 16 + lrow) * 32 + lgrp * 8);
#pragma unroll
        for (int j = 0; j < 4; j++)
            bfv[j] = *reinterpret_cast<const bf16x8*>(
                Bs + (wcol * 64 + j * 16 + lrow) * 32 + lgrp * 8);
#pragma unroll
        for (int i = 0; i < 4; i++)
#pragma unroll
            for (int j = 0; j < 4; j++)
                acc[i][j] = MFMA16(af[i], bfv[j], acc[i][j]);
    }

#pragma unroll
    for (int i = 0; i < 4; i++)
#pragma unroll
        for (int j = 0; j < 4; j++)
#pragma unroll
            for (int r = 0; r < 4; r++) {
                int m = mtile + wrow * 64 + i * 16 + lgrp * 4 + r;
                int n = ntile + wcol * 64 + j * 16 + lrow;
                outF[(size_t)m * N + n] = acc[i][j][r];
            }
}

// V [bh][1024][64] -> V^T [bh][64][1024], LDS-tiled, coalesced both sides.
__global__ __launch_bounds__(256) void transpose_v(
    const unsigned short* __restrict__ Vb, unsigned short* __restrict__ Vtg) {
    __shared__ unsigned short L[64][72];
    const int tt = blockIdx.x, bh = blockIdx.y;
    const int tid = threadIdx.x;
#pragma unroll
    for (int e = 0; e < 2; ++e) {
        int chunk = e * 256 + tid;
        int r = chunk >> 3, c = (chunk & 7) * 8;
        uint4 v = *reinterpret_cast<const uint4*>(
            Vb + ((size_t)bh * 1024 + tt * 64 + r) * 64 + c);
        *reinterpret_cast<uint4*>(&L[r][c]) = v;
    }
    __syncthreads();
#pragma unroll
    for (int e = 0; e < 2; ++e) {
        int chunk = e * 256 + tid;
        int d = chunk >> 3, t0 = (chunk & 7) * 8;
        unsigned short tmp[8];
#pragma unroll
        for (int u = 0; u < 8; ++u) tmp[u] = L[t0 + u][d];
        *reinterpret_cast<uint4*>(Vtg + ((size_t)bh * 64 + d) * 1024 + tt * 64 +
                                  t0) = *reinterpret_cast<const uint4*>(tmp);
    }
}

// Flash attention, bf16 MFMA 16x16x32.  4 waves x 16 q-rows (QBLK=64), KVBLK=64.
// K and V^T double-buffered in LDS via global_load_lds, XOR chunk-swizzle.
__global__ __launch_bounds__(256) void attn_kernel(
    const unsigned short* __restrict__ Qb, const unsigned short* __restrict__ Kb,
    const unsigned short* __restrict__ Vtg, const float* __restrict__ rel_bias,
    unsigned short* __restrict__ A3) {
    const int qt = blockIdx.x;  // 0..15
    const int bh = blockIdx.y;  // 0..63
    const int b = bh >> 4, h = bh & 15;
    const int tid = threadIdx.x;
    const int w = tid >> 6, lane = tid & 63;
    const int lrow = lane & 15, lgrp = lane >> 4;

    __shared__ unsigned short Ks[2][64 * 64];
    __shared__ unsigned short Vs[2][64 * 64];
    __shared__ unsigned short Ps[4][16 * 64];
    __shared__ float Bias2[2][128];

    const unsigned short* Ktile = Kb + (size_t)bh * 1024 * 64;
    const unsigned short* Vtile = Vtg + (size_t)bh * 64 * 1024;

    const unsigned short* Qp =
        Qb + ((size_t)bh * 1024 + qt * 64 + w * 16 + lrow) * 64;
    bf16x8 qa0 = *reinterpret_cast<const bf16x8*>(Qp + lgrp * 8);
    bf16x8 qa1 = *reinterpret_cast<const bf16x8*>(Qp + 32 + lgrp * 8);

    const int sr0 = w * 16 + (lane >> 3);
    const int sc_lo = lane & 7;

    float m_run[4], l_run[4];
    f32x4 o_acc[4];
#pragma unroll
    for (int r = 0; r < 4; r++) {
        m_run[r] = -3.0e38f;
        l_run[r] = 0.f;
    }
#pragma unroll
    for (int n = 0; n < 4; n++) {
        f32x4 z = {0.f, 0.f, 0.f, 0.f};
        o_acc[n] = z;
    }

    const int i_loc = w * 16 + lgrp * 4;

    {
#pragma unroll
        for (int i = 0; i < 2; ++i) {
            int r = sr0 + i * 8;
            int c = sc_lo ^ (r & 7);
            __builtin_amdgcn_global_load_lds(
                (const gbl_t*)(Ktile + (size_t)r * 64 + c * 8),
                (lds_t*)(&Ks[0][0] + w * 1024 + i * 512), 16, 0, 0);
            __builtin_amdgcn_global_load_lds(
                (const gbl_t*)(Vtile + (size_t)r * 1024 + c * 8),
                (lds_t*)(&Vs[0][0] + w * 1024 + i * 512), 16, 0, 0);
        }
        if (tid < 128) {
            int rowi = 0 - qt * 64 + 960 + tid;
            rowi = (rowi < 2046) ? rowi : 2046;
            Bias2[0][tid] = rel_bias[(size_t)rowi * 16 + h];
        }
        asm volatile("s_waitcnt vmcnt(0)" ::: "memory");
        __syncthreads();
    }

    for (int kv = 0; kv < 16; ++kv) {
        const int cur = kv & 1;
        if (kv < 15) {
            const int j0n = (kv + 1) * 64;
#pragma unroll
            for (int i = 0; i < 2; ++i) {
                int r = sr0 + i * 8;
                int c = sc_lo ^ (r & 7);
                __builtin_amdgcn_global_load_lds(
                    (const gbl_t*)(Ktile + (size_t)(j0n + r) * 64 + c * 8),
                    (lds_t*)(&Ks[cur ^ 1][0] + w * 1024 + i * 512), 16, 0, 0);
                __builtin_amdgcn_global_load_lds(
                    (const gbl_t*)(Vtile + (size_t)r * 1024 + j0n + c * 8),
                    (lds_t*)(&Vs[cur ^ 1][0] + w * 1024 + i * 512), 16, 0, 0);
            }
            if (tid < 128) {
                int rowi = j0n - qt * 64 + 960 + tid;
                rowi = (rowi < 2046) ? rowi : 2046;
                Bias2[cur ^ 1][tid] = rel_bias[(size_t)rowi * 16 + h];
            }
        }

        const unsigned short* kbuf = &Ks[cur][0];
        f32x4 s[4];
        __builtin_amdgcn_s_setprio(1);
#pragma unroll
        for (int f = 0; f < 4; ++f) {
            int krow = f * 16 + lrow;
            int sw0 = (lgrp ^ (lrow & 7)) * 8;
            int sw1 = ((4 | lgrp) ^ (lrow & 7)) * 8;
            bf16x8 kb0 = *reinterpret_cast<const bf16x8*>(kbuf + krow * 64 + sw0);
            bf16x8 kb1 = *reinterpret_cast<const bf16x8*>(kbuf + krow * 64 + sw1);
            f32x4 z = {0.f, 0.f, 0.f, 0.f};
            z = MFMA16(qa0, kb0, z);
            z = MFMA16(qa1, kb1, z);
            s[f] = z;
        }
        __builtin_amdgcn_s_setprio(0);

        float p[4][4];
        float tmax[4];
#pragma unroll
        for (int r = 0; r < 4; r++) tmax[r] = -3.0e38f;
#pragma unroll
        for (int f = 0; f < 4; ++f) {
            int jl = f * 16 + lrow;
#pragma unroll
            for (int r = 0; r < 4; r++) {
                float sv = s[f][r] * 0.125f + Bias2[cur][jl - (i_loc + r) + 63];
                p[f][r] = sv;
                tmax[r] = fmaxf(tmax[r], sv);
            }
        }
#pragma unroll
        for (int r = 0; r < 4; r++) {
            float t = tmax[r];
            t = fmaxf(t, __shfl_xor(t, 1));
            t = fmaxf(t, __shfl_xor(t, 2));
            t = fmaxf(t, __shfl_xor(t, 4));
            t = fmaxf(t, __shfl_xor(t, 8));
            tmax[r] = t;
        }
        float corr[4];
#pragma unroll
        for (int r = 0; r < 4; r++) {
            float nm = fmaxf(m_run[r], tmax[r]);
            corr[r] = __expf(m_run[r] - nm);
            m_run[r] = nm;
            float su = 0.f;
#pragma unroll
            for (int f = 0; f < 4; ++f) {
                float pv = __expf(p[f][r] - nm);
                p[f][r] = pv;
                su += pv;
            }
            su += __shfl_xor(su, 1);
            su += __shfl_xor(su, 2);
            su += __shfl_xor(su, 4);
            su += __shfl_xor(su, 8);
            l_run[r] = l_run[r] * corr[r] + su;
        }
#pragma unroll
        for (int n = 0; n < 4; n++)
#pragma unroll
            for (int r = 0; r < 4; r++) o_acc[n][r] *= corr[r];

#pragma unroll
        for (int f = 0; f < 4; ++f)
#pragma unroll
            for (int r = 0; r < 4; r++) {
                int prow = lgrp * 4 + r;
                int cs = (2 * f + (lrow >> 3)) ^ (prow & 7);
                Ps[w][prow * 64 + cs * 8 + (lrow & 7)] = f2bf(p[f][r]);
            }

        const unsigned short* vbuf = &Vs[cur][0];
        __builtin_amdgcn_s_setprio(1);
#pragma unroll
        for (int jc = 0; jc < 2; ++jc) {
            int pc = ((4 * jc + lgrp) ^ (lrow & 7)) * 8;
            bf16x8 pa =
                *reinterpret_cast<const bf16x8*>(&Ps[w][0] + lrow * 64 + pc);
#pragma unroll
            for (int n = 0; n < 4; n++) {
                int vrow = n * 16 + lrow;
                bf16x8 vb =
                    *reinterpret_cast<const bf16x8*>(vbuf + vrow * 64 + pc);
                o_acc[n] = MFMA16(pa, vb, o_acc[n]);
            }
        }
        __builtin_amdgcn_s_setprio(0);

        if (kv < 15) {
            asm volatile("s_waitcnt vmcnt(0)" ::: "memory");
            __syncthreads();
        }
    }

#pragma unroll
    for (int n = 0; n < 4; n++) {
#pragma unroll
        for (int r = 0; r < 4; r++) {
            float val = o_acc[n][r] / l_run[r];
            int ia = qt * 64 + w * 16 + lgrp * 4 + r;
            size_t m = (size_t)b * 1024 + ia;
            int col = h * 64 + n * 16 + lrow;
            unsigned short hi = f2bf(val);
            float rres = val - bf2f(hi);
            A3[m * 2048 + col] = hi;
            A3[m * 2048 + 1024 + col] = f2bf(rres);
        }
    }
}

extern "C" void kernel_launch(void* const* d_in, const int* in_sizes, int n_in,
                              void* d_out, int out_size, void* d_ws,
                              size_t ws_size, hipStream_t stream) {
    const float* x = (const float*)d_in[0];
    const float* w_qkv = (const float*)d_in[1];
    const float* w_out = (const float*)d_in[2];
    const float* rel_bias = (const float*)d_in[3];
    float* out = (float*)d_out;

    char* ws = (char*)d_ws;
    size_t off = 0;
    auto alloc = [&](size_t bytes) {
        char* p = ws + off;
        off += (bytes + 255) & ~(size_t)255;
        return p;
    };
    unsigned short* A1s = (unsigned short*)alloc((size_t)4096 * 2048 * 2);
    unsigned short* W1s = (unsigned short*)alloc((size_t)3072 * 2048 * 2);
    unsigned short* Qb = (unsigned short*)alloc((size_t)64 * 1024 * 64 * 2);
    unsigned short* Kb = (unsigned short*)alloc((size_t)64 * 1024 * 64 * 2);
    unsigned short* Vb = (unsigned short*)alloc((size_t)64 * 1024 * 64 * 2);
    unsigned short* A3s = (unsigned short*)alloc((size_t)4096 * 2048 * 2);
    unsigned short* W3s = (unsigned short*)alloc((size_t)1024 * 2048 * 2);
    // V^T aliases A1s: A1s is dead after gemm256_split, transpose_v runs after.
    unsigned short* Vtg = A1s;

    hipLaunchKernelGGL(prep_split_rows, dim3(1024), dim3(256), 0, stream, x, A1s,
                       4096 * 256);
    hipLaunchKernelGGL(prep_split_wqkv, dim3(768), dim3(256), 0, stream, w_qkv,
                       W1s);
    hipLaunchKernelGGL(prep_split_rows, dim3(256), dim3(256), 0, stream, w_out,
                       W3s, 1024 * 256);
    hipLaunchKernelGGL(gemm256_split, dim3(12, 16), dim3(512), 0, stream, A1s,
                       W1s, Qb, Kb, Vb);
    hipLaunchKernelGGL(transpose_v, dim3(16, 64), dim3(256), 0, stream, Vb, Vtg);
    hipLaunchKernelGGL(attn_kernel, dim3(16, 64), dim3(256), 0, stream, Qb, Kb,
                       Vtg, rel_bias, A3s);
    hipLaunchKernelGGL(gemm_split_out, dim3(8, 32), dim3(256), 0, stream, A3s,
                       W3s, out, 1024);
}

// Round 5
// 191.214 us; speedup vs baseline: 1.5080x; 1.2770x over previous
//
#include <hip/hip_runtime.h>
#include <hip/hip_bf16.h>

typedef short bf16x8 __attribute__((ext_vector_type(8)));
typedef float f32x4  __attribute__((ext_vector_type(4)));

typedef __attribute__((address_space(3))) void lds_t;
typedef __attribute__((address_space(1))) void gbl_t;

#define MFMA16(a,b,c) __builtin_amdgcn_mfma_f32_16x16x32_bf16((a),(b),(c),0,0,0)

__device__ __forceinline__ unsigned short f2bf(float f) {
    __hip_bfloat16 h = __float2bfloat16(f);
    return __builtin_bit_cast(unsigned short, h);
}
__device__ __forceinline__ float bf2f(unsigned short u) {
    __hip_bfloat16 h = __builtin_bit_cast(__hip_bfloat16, u);
    return __bfloat162float(h);
}

// f32 [R][1024] -> bf16 hi-only compact [R][1024].  float4 vectorized.
__global__ void prep_hi_rows(const float* __restrict__ src,
                             unsigned short* __restrict__ dst, int total4) {
    for (int idx = blockIdx.x * blockDim.x + threadIdx.x; idx < total4;
         idx += gridDim.x * blockDim.x) {
        int base = idx * 4;
        float4 v = *reinterpret_cast<const float4*>(src + base);
        ushort4 hi;
        hi.x = f2bf(v.x);
        hi.y = f2bf(v.y);
        hi.z = f2bf(v.z);
        hi.w = f2bf(v.w);
        *reinterpret_cast<ushort4*>(dst + base) = hi;
    }
}

// w_qkv [3072][1024], einops row permute (out row n = which*1024+h*64+d reads
// src row d*48+which*16+h) -> bf16 hi-only compact [3072][1024].
__global__ void prep_hi_wqkv(const float* __restrict__ w,
                             unsigned short* __restrict__ dst) {
    for (int idx = blockIdx.x * blockDim.x + threadIdx.x; idx < 3072 * 256;
         idx += gridDim.x * blockDim.x) {
        int base = idx * 4;
        int n = base >> 10, c = base & 1023;
        int d = n & 63, which = n >> 10, h = (n >> 6) & 15;
        int srow = d * 48 + which * 16 + h;
        float4 v = *reinterpret_cast<const float4*>(w + (size_t)srow * 1024 + c);
        ushort4 hi;
        hi.x = f2bf(v.x);
        hi.y = f2bf(v.y);
        hi.z = f2bf(v.z);
        hi.w = f2bf(v.w);
        *reinterpret_cast<ushort4*>(dst + (size_t)n * 1024 + c) = hi;
    }
}

// Split f32 rows [R][1024] -> dst [R][2048] = [hi | lo] bf16 (out-proj weight).
__global__ void prep_split_rows(const float* __restrict__ src,
                                unsigned short* __restrict__ dst, int total4) {
    for (int idx = blockIdx.x * blockDim.x + threadIdx.x; idx < total4;
         idx += gridDim.x * blockDim.x) {
        int base = idx * 4;
        int m = base >> 10, c = base & 1023;
        float4 v = *reinterpret_cast<const float4*>(src + base);
        ushort4 hi, lo;
        hi.x = f2bf(v.x); lo.x = f2bf(v.x - bf2f(hi.x));
        hi.y = f2bf(v.y); lo.y = f2bf(v.y - bf2f(hi.y));
        hi.z = f2bf(v.z); lo.z = f2bf(v.z - bf2f(hi.z));
        hi.w = f2bf(v.w); lo.w = f2bf(v.w - bf2f(hi.w));
        *reinterpret_cast<ushort4*>(dst + (size_t)m * 2048 + c) = hi;
        *reinterpret_cast<ushort4*>(dst + (size_t)m * 2048 + 1024 + c) = lo;
    }
}

// ============================================================================
// 256x256 hi-only bf16 GEMM for QKV.  K = 1024 (32 steps of 32).  A,B compact
// [rows][1024].  512 thr / 8 waves (2Mx4N), per-wave 128x64 out (acc[8][4]).
// 4-slot LDS ring per operand (16KB/slot); stage slot s+2 while computing s;
// ONE {vmcnt(4); barrier} per K-step (R4 structure — R3's lockstep barriers
// regressed at 1 block/CU).  16B-chunk XOR swizzle chunk^=(row>>1)&3
// both-sides (0 bank conflicts, verified R3/R4).
// QKV precision note (R5): Q/K/V are stored bf16 anyway (storage rounding
// sigma ~2e-3 dominates), so hi-only compute (~2e-3) only grows total error
// ~1.4x; out-proj GEMM must stay split.
// ============================================================================
__global__ __launch_bounds__(512, 2) void gemm256_hi(
    const unsigned short* __restrict__ A, const unsigned short* __restrict__ B,
    unsigned short* __restrict__ outQ, unsigned short* __restrict__ outK,
    unsigned short* __restrict__ outV) {
    __shared__ unsigned short lds[65536];  // A ring [0,32768), B ring [32768,65536)
    const int tid = threadIdx.x;
    const int wid = tid >> 6, lane = tid & 63;
    const int lrow = lane & 15, lgrp = lane >> 4;
    const int wr = wid >> 2, wc = wid & 3;
    const int mtile = blockIdx.y * 256, ntile = blockIdx.x * 256;

    const int csw = lgrp ^ ((lrow >> 1) & 3);
    const int aoff = (wr * 128 + lrow) * 32 + csw * 8;         // + i*512, + slot*8192
    const int boff = 32768 + (wc * 64 + lrow) * 32 + csw * 8;  // + j*512, + slot*8192

    const int sreg = wid * 2;
    const int srow0 = sreg * 16 + (lane >> 2);
    const int srow1 = (sreg + 1) * 16 + (lane >> 2);
    const int schunk = (lane & 3) ^ ((lane >> 3) & 3);
    const int sdst0 = sreg * 512;

    f32x4 acc[8][4];
#pragma unroll
    for (int i = 0; i < 8; ++i)
#pragma unroll
        for (int j = 0; j < 4; ++j) {
            f32x4 z = {0.f, 0.f, 0.f, 0.f};
            acc[i][j] = z;
        }

    // ---- prologue: stage steps 0,1 ----
#pragma unroll
    for (int s0 = 0; s0 < 2; ++s0) {
        const int kb = s0 * 32;
        __builtin_amdgcn_global_load_lds(
            (const gbl_t*)(A + (size_t)(mtile + srow0) * 1024 + kb + schunk * 8),
            (lds_t*)(lds + s0 * 8192 + sdst0), 16, 0, 0);
        __builtin_amdgcn_global_load_lds(
            (const gbl_t*)(A + (size_t)(mtile + srow1) * 1024 + kb + schunk * 8),
            (lds_t*)(lds + s0 * 8192 + sdst0 + 512), 16, 0, 0);
        __builtin_amdgcn_global_load_lds(
            (const gbl_t*)(B + (size_t)(ntile + srow0) * 1024 + kb + schunk * 8),
            (lds_t*)(lds + 32768 + s0 * 8192 + sdst0), 16, 0, 0);
        __builtin_amdgcn_global_load_lds(
            (const gbl_t*)(B + (size_t)(ntile + srow1) * 1024 + kb + schunk * 8),
            (lds_t*)(lds + 32768 + s0 * 8192 + sdst0 + 512), 16, 0, 0);
    }
    asm volatile("s_waitcnt vmcnt(4)" ::: "memory");  // step-0 slots landed
    __syncthreads();

    for (int s = 0; s < 32; ++s) {
        const int sa = s & 3;
        const unsigned short* sbase = lds + sa * 8192;

        bf16x8 af[8];
#pragma unroll
        for (int i = 0; i < 8; ++i)
            af[i] = *reinterpret_cast<const bf16x8*>(sbase + aoff + i * 512);
        bf16x8 b0 = *reinterpret_cast<const bf16x8*>(sbase + boff);
        bf16x8 b1 = *reinterpret_cast<const bf16x8*>(sbase + boff + 512);

        if (s <= 29) {
            const int kb2 = (s + 2) * 32;
            const int s2 = (s + 2) & 3;
            __builtin_amdgcn_global_load_lds(
                (const gbl_t*)(A + (size_t)(mtile + srow0) * 1024 + kb2 + schunk * 8),
                (lds_t*)(lds + s2 * 8192 + sdst0), 16, 0, 0);
            __builtin_amdgcn_global_load_lds(
                (const gbl_t*)(A + (size_t)(mtile + srow1) * 1024 + kb2 + schunk * 8),
                (lds_t*)(lds + s2 * 8192 + sdst0 + 512), 16, 0, 0);
        }
        __builtin_amdgcn_s_setprio(1);
#pragma unroll
        for (int i = 0; i < 8; ++i) {
            acc[i][0] = MFMA16(af[i], b0, acc[i][0]);
            acc[i][1] = MFMA16(af[i], b1, acc[i][1]);
        }
        __builtin_amdgcn_s_setprio(0);

        bf16x8 b2 = *reinterpret_cast<const bf16x8*>(sbase + boff + 1024);
        bf16x8 b3 = *reinterpret_cast<const bf16x8*>(sbase + boff + 1536);
        if (s <= 29) {
            const int kb2 = (s + 2) * 32;
            const int s2 = (s + 2) & 3;
            __builtin_amdgcn_global_load_lds(
                (const gbl_t*)(B + (size_t)(ntile + srow0) * 1024 + kb2 + schunk * 8),
                (lds_t*)(lds + 32768 + s2 * 8192 + sdst0), 16, 0, 0);
            __builtin_amdgcn_global_load_lds(
                (const gbl_t*)(B + (size_t)(ntile + srow1) * 1024 + kb2 + schunk * 8),
                (lds_t*)(lds + 32768 + s2 * 8192 + sdst0 + 512), 16, 0, 0);
        }
        __builtin_amdgcn_s_setprio(1);
#pragma unroll
        for (int i = 0; i < 8; ++i) {
            acc[i][2] = MFMA16(af[i], b2, acc[i][2]);
            acc[i][3] = MFMA16(af[i], b3, acc[i][3]);
        }
        __builtin_amdgcn_s_setprio(0);

        if (s < 31) {
            if (s <= 29)
                asm volatile("s_waitcnt vmcnt(4)" ::: "memory");
            else
                asm volatile("s_waitcnt vmcnt(0)" ::: "memory");
            __syncthreads();
        }
    }

    // ---- epilogue: scatter bf16 into q/k/v [bh][t][64] ----
#pragma unroll
    for (int i = 0; i < 8; ++i) {
#pragma unroll
        for (int j = 0; j < 4; ++j) {
#pragma unroll
            for (int r = 0; r < 4; ++r) {
                float v = acc[i][j][r];
                int m = mtile + wr * 128 + i * 16 + lgrp * 4 + r;
                int n = ntile + wc * 64 + j * 16 + lrow;
                int which = n >> 10;
                int hh = (n >> 6) & 15;
                int d = n & 63;
                int b = m >> 10, t = m & 1023;
                unsigned short* dstp =
                    (which == 0) ? outQ : ((which == 1) ? outK : outV);
                dstp[((size_t)((b << 4) + hh) * 1024 + t) * 64 + d] = f2bf(v);
            }
        }
    }
}

// Split GEMM (128x128 tile, m97 structure) — out-projection only.
// Virtual K = 3072 over A=[hi|hi|lo], B=[hi|lo|hi] (stored [rows][2048]).
__global__ __launch_bounds__(256) void gemm_split_out(
    const unsigned short* __restrict__ A, const unsigned short* __restrict__ B,
    float* __restrict__ outF, int N) {
    __shared__ unsigned short As[128 * 32];
    __shared__ unsigned short Bs[128 * 32];
    const int tid = threadIdx.x;
    const int w = tid >> 6, lane = tid & 63;
    const int lrow = lane & 15, lgrp = lane >> 4;
    const int wrow = w >> 1, wcol = w & 1;
    const int mtile = blockIdx.y * 128, ntile = blockIdx.x * 128;

    f32x4 acc[4][4];
#pragma unroll
    for (int i = 0; i < 4; i++)
#pragma unroll
        for (int j = 0; j < 4; j++) {
            f32x4 z = {0.f, 0.f, 0.f, 0.f};
            acc[i][j] = z;
        }

    const int srow = w * 32 + (lane >> 2);
    const int scol = (lane & 3) * 8;

    for (int ks = 0; ks < 96; ++ks) {
        const int kb = ks * 32;
        const int ac = (kb < 1024) ? kb : kb - 1024;
        const int bc = (kb < 2048) ? kb : kb - 2048;
        __syncthreads();
#pragma unroll
        for (int i = 0; i < 2; ++i) {
            const unsigned short* ga =
                A + (size_t)(mtile + srow + i * 16) * 2048 + ac + scol;
            __builtin_amdgcn_global_load_lds((const gbl_t*)ga,
                                             (lds_t*)(As + w * 1024 + i * 512),
                                             16, 0, 0);
        }
#pragma unroll
        for (int i = 0; i < 2; ++i) {
            const unsigned short* gb =
                B + (size_t)(ntile + srow + i * 16) * 2048 + bc + scol;
            __builtin_amdgcn_global_load_lds((const gbl_t*)gb,
                                             (lds_t*)(Bs + w * 1024 + i * 512),
                                             16, 0, 0);
        }
        asm volatile("s_waitcnt vmcnt(0)" ::: "memory");
        __syncthreads();

        bf16x8 af[4], bfv[4];
#pragma unroll
        for (int i = 0; i < 4; i++)
            af[i] = *reinterpret_cast<const bf16x8*>(
                As + (wrow * 64 + i * 16 + lrow) * 32 + lgrp * 8);
#pragma unroll
        for (int j = 0; j < 4; j++)
            bfv[j] = *reinterpret_cast<const bf16x8*>(
                Bs + (wcol * 64 + j * 16 + lrow) * 32 + lgrp * 8);
#pragma unroll
        for (int i = 0; i < 4; i++)
#pragma unroll
            for (int j = 0; j < 4; j++)
                acc[i][j] = MFMA16(af[i], bfv[j], acc[i][j]);
    }

#pragma unroll
    for (int i = 0; i < 4; i++)
#pragma unroll
        for (int j = 0; j < 4; j++)
#pragma unroll
            for (int r = 0; r < 4; r++) {
                int m = mtile + wrow * 64 + i * 16 + lgrp * 4 + r;
                int n = ntile + wcol * 64 + j * 16 + lrow;
                outF[(size_t)m * N + n] = acc[i][j][r];
            }
}

// V [bh][1024][64] -> V^T [bh][64][1024], LDS-tiled, coalesced both sides.
__global__ __launch_bounds__(256) void transpose_v(
    const unsigned short* __restrict__ Vb, unsigned short* __restrict__ Vtg) {
    __shared__ unsigned short L[64][72];
    const int tt = blockIdx.x, bh = blockIdx.y;
    const int tid = threadIdx.x;
#pragma unroll
    for (int e = 0; e < 2; ++e) {
        int chunk = e * 256 + tid;
        int r = chunk >> 3, c = (chunk & 7) * 8;
        uint4 v = *reinterpret_cast<const uint4*>(
            Vb + ((size_t)bh * 1024 + tt * 64 + r) * 64 + c);
        *reinterpret_cast<uint4*>(&L[r][c]) = v;
    }
    __syncthreads();
#pragma unroll
    for (int e = 0; e < 2; ++e) {
        int chunk = e * 256 + tid;
        int d = chunk >> 3, t0 = (chunk & 7) * 8;
        unsigned short tmp[8];
#pragma unroll
        for (int u = 0; u < 8; ++u) tmp[u] = L[t0 + u][d];
        *reinterpret_cast<uint4*>(Vtg + ((size_t)bh * 64 + d) * 1024 + tt * 64 +
                                  t0) = *reinterpret_cast<const uint4*>(tmp);
    }
}

// Flash attention, bf16 MFMA 16x16x32.  4 waves x 16 q-rows (QBLK=64), KVBLK=64.
// K and V^T double-buffered in LDS via global_load_lds, XOR chunk-swizzle.
__global__ __launch_bounds__(256) void attn_kernel(
    const unsigned short* __restrict__ Qb, const unsigned short* __restrict__ Kb,
    const unsigned short* __restrict__ Vtg, const float* __restrict__ rel_bias,
    unsigned short* __restrict__ A3) {
    const int qt = blockIdx.x;  // 0..15
    const int bh = blockIdx.y;  // 0..63
    const int b = bh >> 4, h = bh & 15;
    const int tid = threadIdx.x;
    const int w = tid >> 6, lane = tid & 63;
    const int lrow = lane & 15, lgrp = lane >> 4;

    __shared__ unsigned short Ks[2][64 * 64];
    __shared__ unsigned short Vs[2][64 * 64];
    __shared__ unsigned short Ps[4][16 * 64];
    __shared__ float Bias2[2][128];

    const unsigned short* Ktile = Kb + (size_t)bh * 1024 * 64;
    const unsigned short* Vtile = Vtg + (size_t)bh * 64 * 1024;

    const unsigned short* Qp =
        Qb + ((size_t)bh * 1024 + qt * 64 + w * 16 + lrow) * 64;
    bf16x8 qa0 = *reinterpret_cast<const bf16x8*>(Qp + lgrp * 8);
    bf16x8 qa1 = *reinterpret_cast<const bf16x8*>(Qp + 32 + lgrp * 8);

    const int sr0 = w * 16 + (lane >> 3);
    const int sc_lo = lane & 7;

    float m_run[4], l_run[4];
    f32x4 o_acc[4];
#pragma unroll
    for (int r = 0; r < 4; r++) {
        m_run[r] = -3.0e38f;
        l_run[r] = 0.f;
    }
#pragma unroll
    for (int n = 0; n < 4; n++) {
        f32x4 z = {0.f, 0.f, 0.f, 0.f};
        o_acc[n] = z;
    }

    const int i_loc = w * 16 + lgrp * 4;

    {
#pragma unroll
        for (int i = 0; i < 2; ++i) {
            int r = sr0 + i * 8;
            int c = sc_lo ^ (r & 7);
            __builtin_amdgcn_global_load_lds(
                (const gbl_t*)(Ktile + (size_t)r * 64 + c * 8),
                (lds_t*)(&Ks[0][0] + w * 1024 + i * 512), 16, 0, 0);
            __builtin_amdgcn_global_load_lds(
                (const gbl_t*)(Vtile + (size_t)r * 1024 + c * 8),
                (lds_t*)(&Vs[0][0] + w * 1024 + i * 512), 16, 0, 0);
        }
        if (tid < 128) {
            int rowi = 0 - qt * 64 + 960 + tid;
            rowi = (rowi < 2046) ? rowi : 2046;
            Bias2[0][tid] = rel_bias[(size_t)rowi * 16 + h];
        }
        asm volatile("s_waitcnt vmcnt(0)" ::: "memory");
        __syncthreads();
    }

    for (int kv = 0; kv < 16; ++kv) {
        const int cur = kv & 1;
        if (kv < 15) {
            const int j0n = (kv + 1) * 64;
#pragma unroll
            for (int i = 0; i < 2; ++i) {
                int r = sr0 + i * 8;
                int c = sc_lo ^ (r & 7);
                __builtin_amdgcn_global_load_lds(
                    (const gbl_t*)(Ktile + (size_t)(j0n + r) * 64 + c * 8),
                    (lds_t*)(&Ks[cur ^ 1][0] + w * 1024 + i * 512), 16, 0, 0);
                __builtin_amdgcn_global_load_lds(
                    (const gbl_t*)(Vtile + (size_t)r * 1024 + j0n + c * 8),
                    (lds_t*)(&Vs[cur ^ 1][0] + w * 1024 + i * 512), 16, 0, 0);
            }
            if (tid < 128) {
                int rowi = j0n - qt * 64 + 960 + tid;
                rowi = (rowi < 2046) ? rowi : 2046;
                Bias2[cur ^ 1][tid] = rel_bias[(size_t)rowi * 16 + h];
            }
        }

        const unsigned short* kbuf = &Ks[cur][0];
        f32x4 s[4];
        __builtin_amdgcn_s_setprio(1);
#pragma unroll
        for (int f = 0; f < 4; ++f) {
            int krow = f * 16 + lrow;
            int sw0 = (lgrp ^ (lrow & 7)) * 8;
            int sw1 = ((4 | lgrp) ^ (lrow & 7)) * 8;
            bf16x8 kb0 = *reinterpret_cast<const bf16x8*>(kbuf + krow * 64 + sw0);
            bf16x8 kb1 = *reinterpret_cast<const bf16x8*>(kbuf + krow * 64 + sw1);
            f32x4 z = {0.f, 0.f, 0.f, 0.f};
            z = MFMA16(qa0, kb0, z);
            z = MFMA16(qa1, kb1, z);
            s[f] = z;
        }
        __builtin_amdgcn_s_setprio(0);

        float p[4][4];
        float tmax[4];
#pragma unroll
        for (int r = 0; r < 4; r++) tmax[r] = -3.0e38f;
#pragma unroll
        for (int f = 0; f < 4; ++f) {
            int jl = f * 16 + lrow;
#pragma unroll
            for (int r = 0; r < 4; r++) {
                float sv = s[f][r] * 0.125f + Bias2[cur][jl - (i_loc + r) + 63];
                p[f][r] = sv;
                tmax[r] = fmaxf(tmax[r], sv);
            }
        }
#pragma unroll
        for (int r = 0; r < 4; r++) {
            float t = tmax[r];
            t = fmaxf(t, __shfl_xor(t, 1));
            t = fmaxf(t, __shfl_xor(t, 2));
            t = fmaxf(t, __shfl_xor(t, 4));
            t = fmaxf(t, __shfl_xor(t, 8));
            tmax[r] = t;
        }
        float corr[4];
#pragma unroll
        for (int r = 0; r < 4; r++) {
            float nm = fmaxf(m_run[r], tmax[r]);
            corr[r] = __expf(m_run[r] - nm);
            m_run[r] = nm;
            float su = 0.f;
#pragma unroll
            for (int f = 0; f < 4; ++f) {
                float pv = __expf(p[f][r] - nm);
                p[f][r] = pv;
                su += pv;
            }
            su += __shfl_xor(su, 1);
            su += __shfl_xor(su, 2);
            su += __shfl_xor(su, 4);
            su += __shfl_xor(su, 8);
            l_run[r] = l_run[r] * corr[r] + su;
        }
#pragma unroll
        for (int n = 0; n < 4; n++)
#pragma unroll
            for (int r = 0; r < 4; r++) o_acc[n][r] *= corr[r];

#pragma unroll
        for (int f = 0; f < 4; ++f)
#pragma unroll
            for (int r = 0; r < 4; r++) {
                int prow = lgrp * 4 + r;
                int cs = (2 * f + (lrow >> 3)) ^ (prow & 7);
                Ps[w][prow * 64 + cs * 8 + (lrow & 7)] = f2bf(p[f][r]);
            }

        const unsigned short* vbuf = &Vs[cur][0];
        __builtin_amdgcn_s_setprio(1);
#pragma unroll
        for (int jc = 0; jc < 2; ++jc) {
            int pc = ((4 * jc + lgrp) ^ (lrow & 7)) * 8;
            bf16x8 pa =
                *reinterpret_cast<const bf16x8*>(&Ps[w][0] + lrow * 64 + pc);
#pragma unroll
            for (int n = 0; n < 4; n++) {
                int vrow = n * 16 + lrow;
                bf16x8 vb =
                    *reinterpret_cast<const bf16x8*>(vbuf + vrow * 64 + pc);
                o_acc[n] = MFMA16(pa, vb, o_acc[n]);
            }
        }
        __builtin_amdgcn_s_setprio(0);

        if (kv < 15) {
            asm volatile("s_waitcnt vmcnt(0)" ::: "memory");
            __syncthreads();
        }
    }

#pragma unroll
    for (int n = 0; n < 4; n++) {
#pragma unroll
        for (int r = 0; r < 4; r++) {
            float val = o_acc[n][r] / l_run[r];
            int ia = qt * 64 + w * 16 + lgrp * 4 + r;
            size_t m = (size_t)b * 1024 + ia;
            int col = h * 64 + n * 16 + lrow;
            unsigned short hi = f2bf(val);
            float rres = val - bf2f(hi);
            A3[m * 2048 + col] = hi;
            A3[m * 2048 + 1024 + col] = f2bf(rres);
        }
    }
}

extern "C" void kernel_launch(void* const* d_in, const int* in_sizes, int n_in,
                              void* d_out, int out_size, void* d_ws,
                              size_t ws_size, hipStream_t stream) {
    const float* x = (const float*)d_in[0];
    const float* w_qkv = (const float*)d_in[1];
    const float* w_out = (const float*)d_in[2];
    const float* rel_bias = (const float*)d_in[3];
    float* out = (float*)d_out;

    char* ws = (char*)d_ws;
    size_t off = 0;
    auto alloc = [&](size_t bytes) {
        char* p = ws + off;
        off += (bytes + 255) & ~(size_t)255;
        return p;
    };
    unsigned short* A1h = (unsigned short*)alloc((size_t)4096 * 1024 * 2);
    unsigned short* W1h = (unsigned short*)alloc((size_t)3072 * 1024 * 2);
    unsigned short* Qb = (unsigned short*)alloc((size_t)64 * 1024 * 64 * 2);
    unsigned short* Kb = (unsigned short*)alloc((size_t)64 * 1024 * 64 * 2);
    unsigned short* Vb = (unsigned short*)alloc((size_t)64 * 1024 * 64 * 2);
    unsigned short* A3s = (unsigned short*)alloc((size_t)4096 * 2048 * 2);
    unsigned short* W3s = (unsigned short*)alloc((size_t)1024 * 2048 * 2);
    // V^T aliases A1h (8 MB each): A1h dead after gemm256_hi; transpose_v after.
    unsigned short* Vtg = A1h;

    hipLaunchKernelGGL(prep_hi_rows, dim3(1024), dim3(256), 0, stream, x, A1h,
                       4096 * 256);
    hipLaunchKernelGGL(prep_hi_wqkv, dim3(768), dim3(256), 0, stream, w_qkv,
                       W1h);
    hipLaunchKernelGGL(prep_split_rows, dim3(256), dim3(256), 0, stream, w_out,
                       W3s, 1024 * 256);
    hipLaunchKernelGGL(gemm256_hi, dim3(12, 16), dim3(512), 0, stream, A1h, W1h,
                       Qb, Kb, Vb);
    hipLaunchKernelGGL(transpose_v, dim3(16, 64), dim3(256), 0, stream, Vb, Vtg);
    hipLaunchKernelGGL(attn_kernel, dim3(16, 64), dim3(256), 0, stream, Qb, Kb,
                       Vtg, rel_bias, A3s);
    hipLaunchKernelGGL(gemm_split_out, dim3(8, 32), dim3(256), 0, stream, A3s,
                       W3s, out, 1024);
}

// Round 6
// 174.524 us; speedup vs baseline: 1.6522x; 1.0956x over previous
//
#include <hip/hip_runtime.h>
#include <hip/hip_bf16.h>

typedef short bf16x8 __attribute__((ext_vector_type(8)));
typedef float f32x4  __attribute__((ext_vector_type(4)));

typedef __attribute__((address_space(3))) void lds_t;
typedef __attribute__((address_space(1))) void gbl_t;

#define MFMA16(a,b,c) __builtin_amdgcn_mfma_f32_16x16x32_bf16((a),(b),(c),0,0,0)

__device__ __forceinline__ unsigned short f2bf(float f) {
    __hip_bfloat16 h = __float2bfloat16(f);
    return __builtin_bit_cast(unsigned short, h);
}
__device__ __forceinline__ float bf2f(unsigned short u) {
    __hip_bfloat16 h = __builtin_bit_cast(__hip_bfloat16, u);
    return __bfloat162float(h);
}

// f32 [R][1024] -> bf16 hi-only compact [R][1024].  float4 vectorized.
__global__ void prep_hi_rows(const float* __restrict__ src,
                             unsigned short* __restrict__ dst, int total4) {
    for (int idx = blockIdx.x * blockDim.x + threadIdx.x; idx < total4;
         idx += gridDim.x * blockDim.x) {
        int base = idx * 4;
        float4 v = *reinterpret_cast<const float4*>(src + base);
        ushort4 hi;
        hi.x = f2bf(v.x);
        hi.y = f2bf(v.y);
        hi.z = f2bf(v.z);
        hi.w = f2bf(v.w);
        *reinterpret_cast<ushort4*>(dst + base) = hi;
    }
}

// w_qkv [3072][1024], einops row permute (out row n = which*1024+h*64+d reads
// src row d*48+which*16+h) -> bf16 hi-only compact [3072][1024].
__global__ void prep_hi_wqkv(const float* __restrict__ w,
                             unsigned short* __restrict__ dst) {
    for (int idx = blockIdx.x * blockDim.x + threadIdx.x; idx < 3072 * 256;
         idx += gridDim.x * blockDim.x) {
        int base = idx * 4;
        int n = base >> 10, c = base & 1023;
        int d = n & 63, which = n >> 10, h = (n >> 6) & 15;
        int srow = d * 48 + which * 16 + h;
        float4 v = *reinterpret_cast<const float4*>(w + (size_t)srow * 1024 + c);
        ushort4 hi;
        hi.x = f2bf(v.x);
        hi.y = f2bf(v.y);
        hi.z = f2bf(v.z);
        hi.w = f2bf(v.w);
        *reinterpret_cast<ushort4*>(dst + (size_t)n * 1024 + c) = hi;
    }
}

// Split f32 rows [R][1024] -> dst [R][2048] = [hi | lo] bf16 (out-proj weight).
__global__ void prep_split_rows(const float* __restrict__ src,
                                unsigned short* __restrict__ dst, int total4) {
    for (int idx = blockIdx.x * blockDim.x + threadIdx.x; idx < total4;
         idx += gridDim.x * blockDim.x) {
        int base = idx * 4;
        int m = base >> 10, c = base & 1023;
        float4 v = *reinterpret_cast<const float4*>(src + base);
        ushort4 hi, lo;
        hi.x = f2bf(v.x); lo.x = f2bf(v.x - bf2f(hi.x));
        hi.y = f2bf(v.y); lo.y = f2bf(v.y - bf2f(hi.y));
        hi.z = f2bf(v.z); lo.z = f2bf(v.z - bf2f(hi.z));
        hi.w = f2bf(v.w); lo.w = f2bf(v.w - bf2f(hi.w));
        *reinterpret_cast<ushort4*>(dst + (size_t)m * 2048 + c) = hi;
        *reinterpret_cast<ushort4*>(dst + (size_t)m * 2048 + 1024 + c) = lo;
    }
}

// ============================================================================
// 256x256 hi-only bf16 GEMM for QKV.  (unchanged from R5 — see R4/R5 notes)
// ============================================================================
__global__ __launch_bounds__(512, 2) void gemm256_hi(
    const unsigned short* __restrict__ A, const unsigned short* __restrict__ B,
    unsigned short* __restrict__ outQ, unsigned short* __restrict__ outK,
    unsigned short* __restrict__ outV) {
    __shared__ unsigned short lds[65536];  // A ring [0,32768), B ring [32768,65536)
    const int tid = threadIdx.x;
    const int wid = tid >> 6, lane = tid & 63;
    const int lrow = lane & 15, lgrp = lane >> 4;
    const int wr = wid >> 2, wc = wid & 3;
    const int mtile = blockIdx.y * 256, ntile = blockIdx.x * 256;

    const int csw = lgrp ^ ((lrow >> 1) & 3);
    const int aoff = (wr * 128 + lrow) * 32 + csw * 8;
    const int boff = 32768 + (wc * 64 + lrow) * 32 + csw * 8;

    const int sreg = wid * 2;
    const int srow0 = sreg * 16 + (lane >> 2);
    const int srow1 = (sreg + 1) * 16 + (lane >> 2);
    const int schunk = (lane & 3) ^ ((lane >> 3) & 3);
    const int sdst0 = sreg * 512;

    f32x4 acc[8][4];
#pragma unroll
    for (int i = 0; i < 8; ++i)
#pragma unroll
        for (int j = 0; j < 4; ++j) {
            f32x4 z = {0.f, 0.f, 0.f, 0.f};
            acc[i][j] = z;
        }

#pragma unroll
    for (int s0 = 0; s0 < 2; ++s0) {
        const int kb = s0 * 32;
        __builtin_amdgcn_global_load_lds(
            (const gbl_t*)(A + (size_t)(mtile + srow0) * 1024 + kb + schunk * 8),
            (lds_t*)(lds + s0 * 8192 + sdst0), 16, 0, 0);
        __builtin_amdgcn_global_load_lds(
            (const gbl_t*)(A + (size_t)(mtile + srow1) * 1024 + kb + schunk * 8),
            (lds_t*)(lds + s0 * 8192 + sdst0 + 512), 16, 0, 0);
        __builtin_amdgcn_global_load_lds(
            (const gbl_t*)(B + (size_t)(ntile + srow0) * 1024 + kb + schunk * 8),
            (lds_t*)(lds + 32768 + s0 * 8192 + sdst0), 16, 0, 0);
        __builtin_amdgcn_global_load_lds(
            (const gbl_t*)(B + (size_t)(ntile + srow1) * 1024 + kb + schunk * 8),
            (lds_t*)(lds + 32768 + s0 * 8192 + sdst0 + 512), 16, 0, 0);
    }
    asm volatile("s_waitcnt vmcnt(4)" ::: "memory");
    __syncthreads();

    for (int s = 0; s < 32; ++s) {
        const int sa = s & 3;
        const unsigned short* sbase = lds + sa * 8192;

        bf16x8 af[8];
#pragma unroll
        for (int i = 0; i < 8; ++i)
            af[i] = *reinterpret_cast<const bf16x8*>(sbase + aoff + i * 512);
        bf16x8 b0 = *reinterpret_cast<const bf16x8*>(sbase + boff);
        bf16x8 b1 = *reinterpret_cast<const bf16x8*>(sbase + boff + 512);

        if (s <= 29) {
            const int kb2 = (s + 2) * 32;
            const int s2 = (s + 2) & 3;
            __builtin_amdgcn_global_load_lds(
                (const gbl_t*)(A + (size_t)(mtile + srow0) * 1024 + kb2 + schunk * 8),
                (lds_t*)(lds + s2 * 8192 + sdst0), 16, 0, 0);
            __builtin_amdgcn_global_load_lds(
                (const gbl_t*)(A + (size_t)(mtile + srow1) * 1024 + kb2 + schunk * 8),
                (lds_t*)(lds + s2 * 8192 + sdst0 + 512), 16, 0, 0);
        }
        __builtin_amdgcn_s_setprio(1);
#pragma unroll
        for (int i = 0; i < 8; ++i) {
            acc[i][0] = MFMA16(af[i], b0, acc[i][0]);
            acc[i][1] = MFMA16(af[i], b1, acc[i][1]);
        }
        __builtin_amdgcn_s_setprio(0);

        bf16x8 b2 = *reinterpret_cast<const bf16x8*>(sbase + boff + 1024);
        bf16x8 b3 = *reinterpret_cast<const bf16x8*>(sbase + boff + 1536);
        if (s <= 29) {
            const int kb2 = (s + 2) * 32;
            const int s2 = (s + 2) & 3;
            __builtin_amdgcn_global_load_lds(
                (const gbl_t*)(B + (size_t)(ntile + srow0) * 1024 + kb2 + schunk * 8),
                (lds_t*)(lds + 32768 + s2 * 8192 + sdst0), 16, 0, 0);
            __builtin_amdgcn_global_load_lds(
                (const gbl_t*)(B + (size_t)(ntile + srow1) * 1024 + kb2 + schunk * 8),
                (lds_t*)(lds + 32768 + s2 * 8192 + sdst0 + 512), 16, 0, 0);
        }
        __builtin_amdgcn_s_setprio(1);
#pragma unroll
        for (int i = 0; i < 8; ++i) {
            acc[i][2] = MFMA16(af[i], b2, acc[i][2]);
            acc[i][3] = MFMA16(af[i], b3, acc[i][3]);
        }
        __builtin_amdgcn_s_setprio(0);

        if (s < 31) {
            if (s <= 29)
                asm volatile("s_waitcnt vmcnt(4)" ::: "memory");
            else
                asm volatile("s_waitcnt vmcnt(0)" ::: "memory");
            __syncthreads();
        }
    }

#pragma unroll
    for (int i = 0; i < 8; ++i) {
#pragma unroll
        for (int j = 0; j < 4; ++j) {
#pragma unroll
            for (int r = 0; r < 4; ++r) {
                float v = acc[i][j][r];
                int m = mtile + wr * 128 + i * 16 + lgrp * 4 + r;
                int n = ntile + wc * 64 + j * 16 + lrow;
                int which = n >> 10;
                int hh = (n >> 6) & 15;
                int d = n & 63;
                int b = m >> 10, t = m & 1023;
                unsigned short* dstp =
                    (which == 0) ? outQ : ((which == 1) ? outK : outV);
                dstp[((size_t)((b << 4) + hh) * 1024 + t) * 64 + d] = f2bf(v);
            }
        }
    }
}

// Split GEMM (128x128 tile, m97 structure) — out-projection only.
__global__ __launch_bounds__(256) void gemm_split_out(
    const unsigned short* __restrict__ A, const unsigned short* __restrict__ B,
    float* __restrict__ outF, int N) {
    __shared__ unsigned short As[128 * 32];
    __shared__ unsigned short Bs[128 * 32];
    const int tid = threadIdx.x;
    const int w = tid >> 6, lane = tid & 63;
    const int lrow = lane & 15, lgrp = lane >> 4;
    const int wrow = w >> 1, wcol = w & 1;
    const int mtile = blockIdx.y * 128, ntile = blockIdx.x * 128;

    f32x4 acc[4][4];
#pragma unroll
    for (int i = 0; i < 4; i++)
#pragma unroll
        for (int j = 0; j < 4; j++) {
            f32x4 z = {0.f, 0.f, 0.f, 0.f};
            acc[i][j] = z;
        }

    const int srow = w * 32 + (lane >> 2);
    const int scol = (lane & 3) * 8;

    for (int ks = 0; ks < 96; ++ks) {
        const int kb = ks * 32;
        const int ac = (kb < 1024) ? kb : kb - 1024;
        const int bc = (kb < 2048) ? kb : kb - 2048;
        __syncthreads();
#pragma unroll
        for (int i = 0; i < 2; ++i) {
            const unsigned short* ga =
                A + (size_t)(mtile + srow + i * 16) * 2048 + ac + scol;
            __builtin_amdgcn_global_load_lds((const gbl_t*)ga,
                                             (lds_t*)(As + w * 1024 + i * 512),
                                             16, 0, 0);
        }
#pragma unroll
        for (int i = 0; i < 2; ++i) {
            const unsigned short* gb =
                B + (size_t)(ntile + srow + i * 16) * 2048 + bc + scol;
            __builtin_amdgcn_global_load_lds((const gbl_t*)gb,
                                             (lds_t*)(Bs + w * 1024 + i * 512),
                                             16, 0, 0);
        }
        asm volatile("s_waitcnt vmcnt(0)" ::: "memory");
        __syncthreads();

        bf16x8 af[4], bfv[4];
#pragma unroll
        for (int i = 0; i < 4; i++)
            af[i] = *reinterpret_cast<const bf16x8*>(
                As + (wrow * 64 + i * 16 + lrow) * 32 + lgrp * 8);
#pragma unroll
        for (int j = 0; j < 4; j++)
            bfv[j] = *reinterpret_cast<const bf16x8*>(
                Bs + (wcol * 64 + j * 16 + lrow) * 32 + lgrp * 8);
#pragma unroll
        for (int i = 0; i < 4; i++)
#pragma unroll
            for (int j = 0; j < 4; j++)
                acc[i][j] = MFMA16(af[i], bfv[j], acc[i][j]);
    }

#pragma unroll
    for (int i = 0; i < 4; i++)
#pragma unroll
        for (int j = 0; j < 4; j++)
#pragma unroll
            for (int r = 0; r < 4; r++) {
                int m = mtile + wrow * 64 + i * 16 + lgrp * 4 + r;
                int n = ntile + wcol * 64 + j * 16 + lrow;
                outF[(size_t)m * N + n] = acc[i][j][r];
            }
}

// V [bh][1024][64] -> V^T [bh][64][1024], LDS-tiled, coalesced both sides.
__global__ __launch_bounds__(256) void transpose_v(
    const unsigned short* __restrict__ Vb, unsigned short* __restrict__ Vtg) {
    __shared__ unsigned short L[64][72];
    const int tt = blockIdx.x, bh = blockIdx.y;
    const int tid = threadIdx.x;
#pragma unroll
    for (int e = 0; e < 2; ++e) {
        int chunk = e * 256 + tid;
        int r = chunk >> 3, c = (chunk & 7) * 8;
        uint4 v = *reinterpret_cast<const uint4*>(
            Vb + ((size_t)bh * 1024 + tt * 64 + r) * 64 + c);
        *reinterpret_cast<uint4*>(&L[r][c]) = v;
    }
    __syncthreads();
#pragma unroll
    for (int e = 0; e < 2; ++e) {
        int chunk = e * 256 + tid;
        int d = chunk >> 3, t0 = (chunk & 7) * 8;
        unsigned short tmp[8];
#pragma unroll
        for (int u = 0; u < 8; ++u) tmp[u] = L[t0 + u][d];
        *reinterpret_cast<uint4*>(Vtg + ((size_t)bh * 64 + d) * 1024 + tt * 64 +
                                  t0) = *reinterpret_cast<const uint4*>(tmp);
    }
}

// ============================================================================
// Flash attention R6: SWAPPED QK^T (mfma(K,Q)) -> each lane owns ONE q-row
// (i = w*16 + lrow); S[j = f*16 + lgrp*4 + r][i] per lane.  Row-reduce:
// in-lane + 2 shfl_xor(16,32).  Softmax in exp2 domain (bias staged *log2e).
// l kept as per-lane PARTIAL (reduced once at epilogue).  Defer-max (T13):
// skip rescale unless max grew > 11.5 (exp2 units).  P packed via
// v_cvt_pk_bf16_f32 -> 4x ds_write_b64/tile into the SAME swizzled Ps layout
// as R5 ((j>>3)^(row&7)) so the PV read path is byte-identical.
// K/V staging, Ps/Vs layouts, GEMMs unchanged.
// ============================================================================
__global__ __launch_bounds__(256) void attn_kernel(
    const unsigned short* __restrict__ Qb, const unsigned short* __restrict__ Kb,
    const unsigned short* __restrict__ Vtg, const float* __restrict__ rel_bias,
    unsigned short* __restrict__ A3) {
    const int qt = blockIdx.x;  // 0..15
    const int bh = blockIdx.y;  // 0..63
    const int b = bh >> 4, h = bh & 15;
    const int tid = threadIdx.x;
    const int w = tid >> 6, lane = tid & 63;
    const int lrow = lane & 15, lgrp = lane >> 4;
    const float LOG2E = 1.4426950408889634f;
    const float SCALE2 = 0.125f * 1.4426950408889634f;
    const float THR = 11.5f;  // ~8 nats in exp2 units

    __shared__ unsigned short Ks[2][64 * 64];
    __shared__ unsigned short Vs[2][64 * 64];
    __shared__ unsigned short Ps[4][16 * 64];
    __shared__ float Bias2[2][128];

    const unsigned short* Ktile = Kb + (size_t)bh * 1024 * 64;
    const unsigned short* Vtile = Vtg + (size_t)bh * 64 * 1024;

    const unsigned short* Qp =
        Qb + ((size_t)bh * 1024 + qt * 64 + w * 16 + lrow) * 64;
    bf16x8 qa0 = *reinterpret_cast<const bf16x8*>(Qp + lgrp * 8);
    bf16x8 qa1 = *reinterpret_cast<const bf16x8*>(Qp + 32 + lgrp * 8);

    const int sr0 = w * 16 + (lane >> 3);
    const int sc_lo = lane & 7;

    float m_run = -3.0e38f;  // running row max (exp2 domain), per lane's row
    float l_run = 0.f;       // PARTIAL row sum (this lane's 16 j-slots)
    f32x4 o_acc[4];
#pragma unroll
    for (int n = 0; n < 4; n++) {
        f32x4 z = {0.f, 0.f, 0.f, 0.f};
        o_acc[n] = z;
    }

    // Bias2 LDS index for (f, r): bbase + f*16 + r  (range [0,126])
    const int bbase = lgrp * 4 + 63 - w * 16 - lrow;

    {
#pragma unroll
        for (int i = 0; i < 2; ++i) {
            int r = sr0 + i * 8;
            int c = sc_lo ^ (r & 7);
            __builtin_amdgcn_global_load_lds(
                (const gbl_t*)(Ktile + (size_t)r * 64 + c * 8),
                (lds_t*)(&Ks[0][0] + w * 1024 + i * 512), 16, 0, 0);
            __builtin_amdgcn_global_load_lds(
                (const gbl_t*)(Vtile + (size_t)r * 1024 + c * 8),
                (lds_t*)(&Vs[0][0] + w * 1024 + i * 512), 16, 0, 0);
        }
        if (tid < 128) {
            int rowi = 0 - qt * 64 + 960 + tid;
            rowi = (rowi < 2046) ? rowi : 2046;
            Bias2[0][tid] = rel_bias[(size_t)rowi * 16 + h] * LOG2E;
        }
        asm volatile("s_waitcnt vmcnt(0)" ::: "memory");
        __syncthreads();
    }

    for (int kv = 0; kv < 16; ++kv) {
        const int cur = kv & 1;
        if (kv < 15) {
            const int j0n = (kv + 1) * 64;
#pragma unroll
            for (int i = 0; i < 2; ++i) {
                int r = sr0 + i * 8;
                int c = sc_lo ^ (r & 7);
                __builtin_amdgcn_global_load_lds(
                    (const gbl_t*)(Ktile + (size_t)(j0n + r) * 64 + c * 8),
                    (lds_t*)(&Ks[cur ^ 1][0] + w * 1024 + i * 512), 16, 0, 0);
                __builtin_amdgcn_global_load_lds(
                    (const gbl_t*)(Vtile + (size_t)r * 1024 + j0n + c * 8),
                    (lds_t*)(&Vs[cur ^ 1][0] + w * 1024 + i * 512), 16, 0, 0);
            }
            if (tid < 128) {
                int rowi = j0n - qt * 64 + 960 + tid;
                rowi = (rowi < 2046) ? rowi : 2046;
                Bias2[cur ^ 1][tid] = rel_bias[(size_t)rowi * 16 + h] * LOG2E;
            }
        }

        // ---- S^T = K Q^T (swapped): lane holds S[j=f*16+lgrp*4+r][i=lrow] ----
        const unsigned short* kbuf = &Ks[cur][0];
        f32x4 s[4];
        __builtin_amdgcn_s_setprio(1);
#pragma unroll
        for (int f = 0; f < 4; ++f) {
            int krow = f * 16 + lrow;
            int sw0 = (lgrp ^ (lrow & 7)) * 8;
            int sw1 = ((4 | lgrp) ^ (lrow & 7)) * 8;
            bf16x8 kb0 = *reinterpret_cast<const bf16x8*>(kbuf + krow * 64 + sw0);
            bf16x8 kb1 = *reinterpret_cast<const bf16x8*>(kbuf + krow * 64 + sw1);
            f32x4 z = {0.f, 0.f, 0.f, 0.f};
            z = MFMA16(kb0, qa0, z);
            z = MFMA16(kb1, qa1, z);
            s[f] = z;
        }
        __builtin_amdgcn_s_setprio(0);

        // ---- softmax, row-local (exp2 domain) ----
        float x[4][4];
        float pm = -3.0e38f;
#pragma unroll
        for (int f = 0; f < 4; ++f)
#pragma unroll
            for (int r = 0; r < 4; ++r) {
                float xv = s[f][r] * SCALE2 + Bias2[cur][bbase + f * 16 + r];
                x[f][r] = xv;
                pm = fmaxf(pm, xv);
            }
        pm = fmaxf(pm, __shfl_xor(pm, 16));
        pm = fmaxf(pm, __shfl_xor(pm, 32));

        if (!__all(pm - m_run <= THR)) {
            float mnew = fmaxf(m_run, pm);
            float corr = __builtin_amdgcn_exp2f(m_run - mnew);
            m_run = mnew;
            l_run *= corr;
            float cb[4];
#pragma unroll
            for (int r = 0; r < 4; ++r) cb[r] = __shfl(corr, lgrp * 4 + r);
#pragma unroll
            for (int n = 0; n < 4; n++)
#pragma unroll
                for (int r = 0; r < 4; r++) o_acc[n][r] *= cb[r];
        }

        float su = 0.f;
#pragma unroll
        for (int f = 0; f < 4; ++f)
#pragma unroll
            for (int r = 0; r < 4; ++r) {
                float pv = __builtin_amdgcn_exp2f(x[f][r] - m_run);
                x[f][r] = pv;
                su += pv;
            }
        l_run += su;

        // ---- P -> Ps (same swizzled layout as R5; 4x b64 writes) ----
#pragma unroll
        for (int f = 0; f < 4; ++f) {
            unsigned int plo, phi;
            asm("v_cvt_pk_bf16_f32 %0, %1, %2"
                : "=v"(plo)
                : "v"(x[f][0]), "v"(x[f][1]));
            asm("v_cvt_pk_bf16_f32 %0, %1, %2"
                : "=v"(phi)
                : "v"(x[f][2]), "v"(x[f][3]));
            const int chunk = (f * 2 + (lgrp >> 1)) ^ (lrow & 7);
            uint2 pw;
            pw.x = plo;
            pw.y = phi;
            *reinterpret_cast<uint2*>(
                &Ps[w][lrow * 64 + chunk * 8 + (lgrp & 1) * 4]) = pw;
        }

        // ---- O += P V (unchanged read path) ----
        const unsigned short* vbuf = &Vs[cur][0];
        __builtin_amdgcn_s_setprio(1);
#pragma unroll
        for (int jc = 0; jc < 2; ++jc) {
            int pc = ((4 * jc + lgrp) ^ (lrow & 7)) * 8;
            bf16x8 pa =
                *reinterpret_cast<const bf16x8*>(&Ps[w][0] + lrow * 64 + pc);
#pragma unroll
            for (int n = 0; n < 4; n++) {
                int vrow = n * 16 + lrow;
                bf16x8 vb =
                    *reinterpret_cast<const bf16x8*>(vbuf + vrow * 64 + pc);
                o_acc[n] = MFMA16(pa, vb, o_acc[n]);
            }
        }
        __builtin_amdgcn_s_setprio(0);

        if (kv < 15) {
            asm volatile("s_waitcnt vmcnt(0)" ::: "memory");
            __syncthreads();
        }
    }

    // ---- epilogue: reduce l across the row's 4 lanes, broadcast, write ----
    float lt = l_run + __shfl_xor(l_run, 16);
    lt += __shfl_xor(lt, 32);
    float rl[4];
#pragma unroll
    for (int r = 0; r < 4; ++r) rl[r] = 1.0f / __shfl(lt, lgrp * 4 + r);

#pragma unroll
    for (int n = 0; n < 4; n++) {
#pragma unroll
        for (int r = 0; r < 4; r++) {
            float val = o_acc[n][r] * rl[r];
            int ia = qt * 64 + w * 16 + lgrp * 4 + r;
            size_t m = (size_t)b * 1024 + ia;
            int col = h * 64 + n * 16 + lrow;
            unsigned short hi = f2bf(val);
            float rres = val - bf2f(hi);
            A3[m * 2048 + col] = hi;
            A3[m * 2048 + 1024 + col] = f2bf(rres);
        }
    }
}

extern "C" void kernel_launch(void* const* d_in, const int* in_sizes, int n_in,
                              void* d_out, int out_size, void* d_ws,
                              size_t ws_size, hipStream_t stream) {
    const float* x = (const float*)d_in[0];
    const float* w_qkv = (const float*)d_in[1];
    const float* w_out = (const float*)d_in[2];
    const float* rel_bias = (const float*)d_in[3];
    float* out = (float*)d_out;

    char* ws = (char*)d_ws;
    size_t off = 0;
    auto alloc = [&](size_t bytes) {
        char* p = ws + off;
        off += (bytes + 255) & ~(size_t)255;
        return p;
    };
    unsigned short* A1h = (unsigned short*)alloc((size_t)4096 * 1024 * 2);
    unsigned short* W1h = (unsigned short*)alloc((size_t)3072 * 1024 * 2);
    unsigned short* Qb = (unsigned short*)alloc((size_t)64 * 1024 * 64 * 2);
    unsigned short* Kb = (unsigned short*)alloc((size_t)64 * 1024 * 64 * 2);
    unsigned short* Vb = (unsigned short*)alloc((size_t)64 * 1024 * 64 * 2);
    unsigned short* A3s = (unsigned short*)alloc((size_t)4096 * 2048 * 2);
    unsigned short* W3s = (unsigned short*)alloc((size_t)1024 * 2048 * 2);
    // V^T aliases A1h (8 MB each): A1h dead after gemm256_hi; transpose_v after.
    unsigned short* Vtg = A1h;

    hipLaunchKernelGGL(prep_hi_rows, dim3(1024), dim3(256), 0, stream, x, A1h,
                       4096 * 256);
    hipLaunchKernelGGL(prep_hi_wqkv, dim3(768), dim3(256), 0, stream, w_qkv,
                       W1h);
    hipLaunchKernelGGL(prep_split_rows, dim3(256), dim3(256), 0, stream, w_out,
                       W3s, 1024 * 256);
    hipLaunchKernelGGL(gemm256_hi, dim3(12, 16), dim3(512), 0, stream, A1h, W1h,
                       Qb, Kb, Vb);
    hipLaunchKernelGGL(transpose_v, dim3(16, 64), dim3(256), 0, stream, Vb, Vtg);
    hipLaunchKernelGGL(attn_kernel, dim3(16, 64), dim3(256), 0, stream, Qb, Kb,
                       Vtg, rel_bias, A3s);
    hipLaunchKernelGGL(gemm_split_out, dim3(8, 32), dim3(256), 0, stream, A3s,
                       W3s, out, 1024);
}

// Round 7
// 160.922 us; speedup vs baseline: 1.7918x; 1.0845x over previous
//
#include <hip/hip_runtime.h>
#include <hip/hip_bf16.h>

typedef short bf16x8 __attribute__((ext_vector_type(8)));
typedef float f32x4  __attribute__((ext_vector_type(4)));

typedef __attribute__((address_space(3))) void lds_t;
typedef __attribute__((address_space(1))) void gbl_t;

#define MFMA16(a,b,c) __builtin_amdgcn_mfma_f32_16x16x32_bf16((a),(b),(c),0,0,0)

__device__ __forceinline__ unsigned short f2bf(float f) {
    __hip_bfloat16 h = __float2bfloat16(f);
    return __builtin_bit_cast(unsigned short, h);
}
__device__ __forceinline__ float bf2f(unsigned short u) {
    __hip_bfloat16 h = __builtin_bit_cast(__hip_bfloat16, u);
    return __bfloat162float(h);
}

// f32 [R][1024] -> bf16 hi-only compact [R][1024].  float4 vectorized.
__global__ void prep_hi_rows(const float* __restrict__ src,
                             unsigned short* __restrict__ dst, int total4) {
    for (int idx = blockIdx.x * blockDim.x + threadIdx.x; idx < total4;
         idx += gridDim.x * blockDim.x) {
        int base = idx * 4;
        float4 v = *reinterpret_cast<const float4*>(src + base);
        ushort4 hi;
        hi.x = f2bf(v.x);
        hi.y = f2bf(v.y);
        hi.z = f2bf(v.z);
        hi.w = f2bf(v.w);
        *reinterpret_cast<ushort4*>(dst + base) = hi;
    }
}

// w_qkv [3072][1024], einops row permute (out row n = which*1024+h*64+d reads
// src row d*48+which*16+h) -> bf16 hi-only compact [3072][1024].
__global__ void prep_hi_wqkv(const float* __restrict__ w,
                             unsigned short* __restrict__ dst) {
    for (int idx = blockIdx.x * blockDim.x + threadIdx.x; idx < 3072 * 256;
         idx += gridDim.x * blockDim.x) {
        int base = idx * 4;
        int n = base >> 10, c = base & 1023;
        int d = n & 63, which = n >> 10, h = (n >> 6) & 15;
        int srow = d * 48 + which * 16 + h;
        float4 v = *reinterpret_cast<const float4*>(w + (size_t)srow * 1024 + c);
        ushort4 hi;
        hi.x = f2bf(v.x);
        hi.y = f2bf(v.y);
        hi.z = f2bf(v.z);
        hi.w = f2bf(v.w);
        *reinterpret_cast<ushort4*>(dst + (size_t)n * 1024 + c) = hi;
    }
}

// Split f32 rows [R][1024] -> dst [R][2048] = [hi | lo] bf16 (out-proj weight).
__global__ void prep_split_rows(const float* __restrict__ src,
                                unsigned short* __restrict__ dst, int total4) {
    for (int idx = blockIdx.x * blockDim.x + threadIdx.x; idx < total4;
         idx += gridDim.x * blockDim.x) {
        int base = idx * 4;
        int m = base >> 10, c = base & 1023;
        float4 v = *reinterpret_cast<const float4*>(src + base);
        ushort4 hi, lo;
        hi.x = f2bf(v.x); lo.x = f2bf(v.x - bf2f(hi.x));
        hi.y = f2bf(v.y); lo.y = f2bf(v.y - bf2f(hi.y));
        hi.z = f2bf(v.z); lo.z = f2bf(v.z - bf2f(hi.z));
        hi.w = f2bf(v.w); lo.w = f2bf(v.w - bf2f(hi.w));
        *reinterpret_cast<ushort4*>(dst + (size_t)m * 2048 + c) = hi;
        *reinterpret_cast<ushort4*>(dst + (size_t)m * 2048 + 1024 + c) = lo;
    }
}

// ============================================================================
// 256x256 hi-only bf16 GEMM for QKV.  (unchanged from R5 — see R4/R5 notes)
// ============================================================================
__global__ __launch_bounds__(512, 2) void gemm256_hi(
    const unsigned short* __restrict__ A, const unsigned short* __restrict__ B,
    unsigned short* __restrict__ outQ, unsigned short* __restrict__ outK,
    unsigned short* __restrict__ outV) {
    __shared__ unsigned short lds[65536];  // A ring [0,32768), B ring [32768,65536)
    const int tid = threadIdx.x;
    const int wid = tid >> 6, lane = tid & 63;
    const int lrow = lane & 15, lgrp = lane >> 4;
    const int wr = wid >> 2, wc = wid & 3;
    const int mtile = blockIdx.y * 256, ntile = blockIdx.x * 256;

    const int csw = lgrp ^ ((lrow >> 1) & 3);
    const int aoff = (wr * 128 + lrow) * 32 + csw * 8;
    const int boff = 32768 + (wc * 64 + lrow) * 32 + csw * 8;

    const int sreg = wid * 2;
    const int srow0 = sreg * 16 + (lane >> 2);
    const int srow1 = (sreg + 1) * 16 + (lane >> 2);
    const int schunk = (lane & 3) ^ ((lane >> 3) & 3);
    const int sdst0 = sreg * 512;

    f32x4 acc[8][4];
#pragma unroll
    for (int i = 0; i < 8; ++i)
#pragma unroll
        for (int j = 0; j < 4; ++j) {
            f32x4 z = {0.f, 0.f, 0.f, 0.f};
            acc[i][j] = z;
        }

#pragma unroll
    for (int s0 = 0; s0 < 2; ++s0) {
        const int kb = s0 * 32;
        __builtin_amdgcn_global_load_lds(
            (const gbl_t*)(A + (size_t)(mtile + srow0) * 1024 + kb + schunk * 8),
            (lds_t*)(lds + s0 * 8192 + sdst0), 16, 0, 0);
        __builtin_amdgcn_global_load_lds(
            (const gbl_t*)(A + (size_t)(mtile + srow1) * 1024 + kb + schunk * 8),
            (lds_t*)(lds + s0 * 8192 + sdst0 + 512), 16, 0, 0);
        __builtin_amdgcn_global_load_lds(
            (const gbl_t*)(B + (size_t)(ntile + srow0) * 1024 + kb + schunk * 8),
            (lds_t*)(lds + 32768 + s0 * 8192 + sdst0), 16, 0, 0);
        __builtin_amdgcn_global_load_lds(
            (const gbl_t*)(B + (size_t)(ntile + srow1) * 1024 + kb + schunk * 8),
            (lds_t*)(lds + 32768 + s0 * 8192 + sdst0 + 512), 16, 0, 0);
    }
    asm volatile("s_waitcnt vmcnt(4)" ::: "memory");
    __syncthreads();

    for (int s = 0; s < 32; ++s) {
        const int sa = s & 3;
        const unsigned short* sbase = lds + sa * 8192;

        bf16x8 af[8];
#pragma unroll
        for (int i = 0; i < 8; ++i)
            af[i] = *reinterpret_cast<const bf16x8*>(sbase + aoff + i * 512);
        bf16x8 b0 = *reinterpret_cast<const bf16x8*>(sbase + boff);
        bf16x8 b1 = *reinterpret_cast<const bf16x8*>(sbase + boff + 512);

        if (s <= 29) {
            const int kb2 = (s + 2) * 32;
            const int s2 = (s + 2) & 3;
            __builtin_amdgcn_global_load_lds(
                (const gbl_t*)(A + (size_t)(mtile + srow0) * 1024 + kb2 + schunk * 8),
                (lds_t*)(lds + s2 * 8192 + sdst0), 16, 0, 0);
            __builtin_amdgcn_global_load_lds(
                (const gbl_t*)(A + (size_t)(mtile + srow1) * 1024 + kb2 + schunk * 8),
                (lds_t*)(lds + s2 * 8192 + sdst0 + 512), 16, 0, 0);
        }
        __builtin_amdgcn_s_setprio(1);
#pragma unroll
        for (int i = 0; i < 8; ++i) {
            acc[i][0] = MFMA16(af[i], b0, acc[i][0]);
            acc[i][1] = MFMA16(af[i], b1, acc[i][1]);
        }
        __builtin_amdgcn_s_setprio(0);

        bf16x8 b2 = *reinterpret_cast<const bf16x8*>(sbase + boff + 1024);
        bf16x8 b3 = *reinterpret_cast<const bf16x8*>(sbase + boff + 1536);
        if (s <= 29) {
            const int kb2 = (s + 2) * 32;
            const int s2 = (s + 2) & 3;
            __builtin_amdgcn_global_load_lds(
                (const gbl_t*)(B + (size_t)(ntile + srow0) * 1024 + kb2 + schunk * 8),
                (lds_t*)(lds + 32768 + s2 * 8192 + sdst0), 16, 0, 0);
            __builtin_amdgcn_global_load_lds(
                (const gbl_t*)(B + (size_t)(ntile + srow1) * 1024 + kb2 + schunk * 8),
                (lds_t*)(lds + 32768 + s2 * 8192 + sdst0 + 512), 16, 0, 0);
        }
        __builtin_amdgcn_s_setprio(1);
#pragma unroll
        for (int i = 0; i < 8; ++i) {
            acc[i][2] = MFMA16(af[i], b2, acc[i][2]);
            acc[i][3] = MFMA16(af[i], b3, acc[i][3]);
        }
        __builtin_amdgcn_s_setprio(0);

        if (s < 31) {
            if (s <= 29)
                asm volatile("s_waitcnt vmcnt(4)" ::: "memory");
            else
                asm volatile("s_waitcnt vmcnt(0)" ::: "memory");
            __syncthreads();
        }
    }

#pragma unroll
    for (int i = 0; i < 8; ++i) {
#pragma unroll
        for (int j = 0; j < 4; ++j) {
#pragma unroll
            for (int r = 0; r < 4; ++r) {
                float v = acc[i][j][r];
                int m = mtile + wr * 128 + i * 16 + lgrp * 4 + r;
                int n = ntile + wc * 64 + j * 16 + lrow;
                int which = n >> 10;
                int hh = (n >> 6) & 15;
                int d = n & 63;
                int b = m >> 10, t = m & 1023;
                unsigned short* dstp =
                    (which == 0) ? outQ : ((which == 1) ? outK : outV);
                dstp[((size_t)((b << 4) + hh) * 1024 + t) * 64 + d] = f2bf(v);
            }
        }
    }
}

// ============================================================================
// Out-projection split GEMM v2 (R7).  C[4096][1024] = A3[hi|lo] x W3[hi|lo],
// virtual K=3072 (hi.hi + hi.lo + lo.hi), 96 steps of BK=32.
// Tile 64x128 -> grid (8,64) = 512 blocks = 2 blocks/CU (R3/R6 lesson: the
// per-step vmcnt(0)+barrier drain needs co-resident blocks to hide behind).
// 4 waves (2Mx2N), wave tile 32x64, acc[2][4].  2-slot LDS dbuf (24 KB),
// stage s+1 before computing s.  Chunk-XOR swizzle (pre-swizzled global src
// + swizzled ds_read) as in gemm256 -> 0 bank conflicts.
// ============================================================================
__global__ __launch_bounds__(256, 4) void gemm_out_v2(
    const unsigned short* __restrict__ A, const unsigned short* __restrict__ B,
    float* __restrict__ outF) {
    __shared__ unsigned short As[2][64 * 32];   // 8 KB
    __shared__ unsigned short Bs[2][128 * 32];  // 16 KB
    const int tid = threadIdx.x;
    const int wid = tid >> 6, lane = tid & 63;
    const int lrow = lane & 15, lgrp = lane >> 4;
    const int wr = wid >> 1, wc = wid & 1;
    const int mtile = blockIdx.y * 64, ntile = blockIdx.x * 128;

    const int csw = lgrp ^ ((lrow >> 1) & 3);
    const int aoff = (wr * 32 + lrow) * 32 + csw * 8;  // + i*512
    const int boff = (wc * 64 + lrow) * 32 + csw * 8;  // + j*512

    // staging: thread covers A chunk tid (row tid>>2), B chunks tid, tid+256
    const int srow = tid >> 2;                          // 0..63
    const int schunk = (tid & 3) ^ ((tid >> 3) & 3);    // inverse-swizzled src
    const unsigned short* Arow = A + (size_t)(mtile + srow) * 2048 + schunk * 8;
    const unsigned short* Brow0 = B + (size_t)(ntile + srow) * 2048 + schunk * 8;
    const unsigned short* Brow1 =
        B + (size_t)(ntile + 64 + srow) * 2048 + schunk * 8;

    f32x4 acc[2][4];
#pragma unroll
    for (int i = 0; i < 2; ++i)
#pragma unroll
        for (int j = 0; j < 4; ++j) {
            f32x4 z = {0.f, 0.f, 0.f, 0.f};
            acc[i][j] = z;
        }

    // prologue: stage step 0 into slot 0 (kb=0 -> ac=0, bc=0)
    __builtin_amdgcn_global_load_lds((const gbl_t*)(Arow),
                                     (lds_t*)(&As[0][0] + tid * 8), 16, 0, 0);
    __builtin_amdgcn_global_load_lds((const gbl_t*)(Brow0),
                                     (lds_t*)(&Bs[0][0] + tid * 8), 16, 0, 0);
    __builtin_amdgcn_global_load_lds((const gbl_t*)(Brow1),
                                     (lds_t*)(&Bs[0][0] + 2048 + tid * 8), 16, 0,
                                     0);
    asm volatile("s_waitcnt vmcnt(0)" ::: "memory");
    __syncthreads();

    for (int s = 0; s < 96; ++s) {
        const int cur = s & 1;
        if (s < 95) {
            const int kb = (s + 1) * 32;
            const int ac = (kb < 1024) ? kb : kb - 1024;
            const int bc = (kb < 2048) ? kb : kb - 2048;
            const int nx = cur ^ 1;
            __builtin_amdgcn_global_load_lds((const gbl_t*)(Arow + ac),
                                             (lds_t*)(&As[nx][0] + tid * 8), 16,
                                             0, 0);
            __builtin_amdgcn_global_load_lds((const gbl_t*)(Brow0 + bc),
                                             (lds_t*)(&Bs[nx][0] + tid * 8), 16,
                                             0, 0);
            __builtin_amdgcn_global_load_lds(
                (const gbl_t*)(Brow1 + bc), (lds_t*)(&Bs[nx][0] + 2048 + tid * 8),
                16, 0, 0);
        }
        bf16x8 af[2], bfv[4];
#pragma unroll
        for (int i = 0; i < 2; ++i)
            af[i] =
                *reinterpret_cast<const bf16x8*>(&As[cur][0] + aoff + i * 512);
#pragma unroll
        for (int j = 0; j < 4; ++j)
            bfv[j] =
                *reinterpret_cast<const bf16x8*>(&Bs[cur][0] + boff + j * 512);
        __builtin_amdgcn_s_setprio(1);
#pragma unroll
        for (int i = 0; i < 2; ++i)
#pragma unroll
            for (int j = 0; j < 4; ++j)
                acc[i][j] = MFMA16(af[i], bfv[j], acc[i][j]);
        __builtin_amdgcn_s_setprio(0);
        if (s < 95) {
            asm volatile("s_waitcnt vmcnt(0)" ::: "memory");
            __syncthreads();
        }
    }

#pragma unroll
    for (int i = 0; i < 2; ++i)
#pragma unroll
        for (int j = 0; j < 4; ++j)
#pragma unroll
            for (int r = 0; r < 4; ++r) {
                int m = mtile + wr * 32 + i * 16 + lgrp * 4 + r;
                int n = ntile + wc * 64 + j * 16 + lrow;
                outF[(size_t)m * 1024 + n] = acc[i][j][r];
            }
}

// V [bh][1024][64] -> V^T [bh][64][1024], LDS-tiled, coalesced both sides.
__global__ __launch_bounds__(256) void transpose_v(
    const unsigned short* __restrict__ Vb, unsigned short* __restrict__ Vtg) {
    __shared__ unsigned short L[64][72];
    const int tt = blockIdx.x, bh = blockIdx.y;
    const int tid = threadIdx.x;
#pragma unroll
    for (int e = 0; e < 2; ++e) {
        int chunk = e * 256 + tid;
        int r = chunk >> 3, c = (chunk & 7) * 8;
        uint4 v = *reinterpret_cast<const uint4*>(
            Vb + ((size_t)bh * 1024 + tt * 64 + r) * 64 + c);
        *reinterpret_cast<uint4*>(&L[r][c]) = v;
    }
    __syncthreads();
#pragma unroll
    for (int e = 0; e < 2; ++e) {
        int chunk = e * 256 + tid;
        int d = chunk >> 3, t0 = (chunk & 7) * 8;
        unsigned short tmp[8];
#pragma unroll
        for (int u = 0; u < 8; ++u) tmp[u] = L[t0 + u][d];
        *reinterpret_cast<uint4*>(Vtg + ((size_t)bh * 64 + d) * 1024 + tt * 64 +
                                  t0) = *reinterpret_cast<const uint4*>(tmp);
    }
}

// ============================================================================
// Flash attention (R6 structure, unchanged): swapped QK^T, row-local softmax
// in exp2 domain, defer-max, cvt_pk P-pack, K/V dbuf via global_load_lds.
// ============================================================================
__global__ __launch_bounds__(256) void attn_kernel(
    const unsigned short* __restrict__ Qb, const unsigned short* __restrict__ Kb,
    const unsigned short* __restrict__ Vtg, const float* __restrict__ rel_bias,
    unsigned short* __restrict__ A3) {
    const int qt = blockIdx.x;  // 0..15
    const int bh = blockIdx.y;  // 0..63
    const int b = bh >> 4, h = bh & 15;
    const int tid = threadIdx.x;
    const int w = tid >> 6, lane = tid & 63;
    const int lrow = lane & 15, lgrp = lane >> 4;
    const float LOG2E = 1.4426950408889634f;
    const float SCALE2 = 0.125f * 1.4426950408889634f;
    const float THR = 11.5f;  // ~8 nats in exp2 units

    __shared__ unsigned short Ks[2][64 * 64];
    __shared__ unsigned short Vs[2][64 * 64];
    __shared__ unsigned short Ps[4][16 * 64];
    __shared__ float Bias2[2][128];

    const unsigned short* Ktile = Kb + (size_t)bh * 1024 * 64;
    const unsigned short* Vtile = Vtg + (size_t)bh * 64 * 1024;

    const unsigned short* Qp =
        Qb + ((size_t)bh * 1024 + qt * 64 + w * 16 + lrow) * 64;
    bf16x8 qa0 = *reinterpret_cast<const bf16x8*>(Qp + lgrp * 8);
    bf16x8 qa1 = *reinterpret_cast<const bf16x8*>(Qp + 32 + lgrp * 8);

    const int sr0 = w * 16 + (lane >> 3);
    const int sc_lo = lane & 7;

    float m_run = -3.0e38f;
    float l_run = 0.f;
    f32x4 o_acc[4];
#pragma unroll
    for (int n = 0; n < 4; n++) {
        f32x4 z = {0.f, 0.f, 0.f, 0.f};
        o_acc[n] = z;
    }

    const int bbase = lgrp * 4 + 63 - w * 16 - lrow;

    {
#pragma unroll
        for (int i = 0; i < 2; ++i) {
            int r = sr0 + i * 8;
            int c = sc_lo ^ (r & 7);
            __builtin_amdgcn_global_load_lds(
                (const gbl_t*)(Ktile + (size_t)r * 64 + c * 8),
                (lds_t*)(&Ks[0][0] + w * 1024 + i * 512), 16, 0, 0);
            __builtin_amdgcn_global_load_lds(
                (const gbl_t*)(Vtile + (size_t)r * 1024 + c * 8),
                (lds_t*)(&Vs[0][0] + w * 1024 + i * 512), 16, 0, 0);
        }
        if (tid < 128) {
            int rowi = 0 - qt * 64 + 960 + tid;
            rowi = (rowi < 2046) ? rowi : 2046;
            Bias2[0][tid] = rel_bias[(size_t)rowi * 16 + h] * LOG2E;
        }
        asm volatile("s_waitcnt vmcnt(0)" ::: "memory");
        __syncthreads();
    }

    for (int kv = 0; kv < 16; ++kv) {
        const int cur = kv & 1;
        if (kv < 15) {
            const int j0n = (kv + 1) * 64;
#pragma unroll
            for (int i = 0; i < 2; ++i) {
                int r = sr0 + i * 8;
                int c = sc_lo ^ (r & 7);
                __builtin_amdgcn_global_load_lds(
                    (const gbl_t*)(Ktile + (size_t)(j0n + r) * 64 + c * 8),
                    (lds_t*)(&Ks[cur ^ 1][0] + w * 1024 + i * 512), 16, 0, 0);
                __builtin_amdgcn_global_load_lds(
                    (const gbl_t*)(Vtile + (size_t)r * 1024 + j0n + c * 8),
                    (lds_t*)(&Vs[cur ^ 1][0] + w * 1024 + i * 512), 16, 0, 0);
            }
            if (tid < 128) {
                int rowi = j0n - qt * 64 + 960 + tid;
                rowi = (rowi < 2046) ? rowi : 2046;
                Bias2[cur ^ 1][tid] = rel_bias[(size_t)rowi * 16 + h] * LOG2E;
            }
        }

        const unsigned short* kbuf = &Ks[cur][0];
        f32x4 s[4];
        __builtin_amdgcn_s_setprio(1);
#pragma unroll
        for (int f = 0; f < 4; ++f) {
            int krow = f * 16 + lrow;
            int sw0 = (lgrp ^ (lrow & 7)) * 8;
            int sw1 = ((4 | lgrp) ^ (lrow & 7)) * 8;
            bf16x8 kb0 = *reinterpret_cast<const bf16x8*>(kbuf + krow * 64 + sw0);
            bf16x8 kb1 = *reinterpret_cast<const bf16x8*>(kbuf + krow * 64 + sw1);
            f32x4 z = {0.f, 0.f, 0.f, 0.f};
            z = MFMA16(kb0, qa0, z);
            z = MFMA16(kb1, qa1, z);
            s[f] = z;
        }
        __builtin_amdgcn_s_setprio(0);

        float x[4][4];
        float pm = -3.0e38f;
#pragma unroll
        for (int f = 0; f < 4; ++f)
#pragma unroll
            for (int r = 0; r < 4; ++r) {
                float xv = s[f][r] * SCALE2 + Bias2[cur][bbase + f * 16 + r];
                x[f][r] = xv;
                pm = fmaxf(pm, xv);
            }
        pm = fmaxf(pm, __shfl_xor(pm, 16));
        pm = fmaxf(pm, __shfl_xor(pm, 32));

        if (!__all(pm - m_run <= THR)) {
            float mnew = fmaxf(m_run, pm);
            float corr = __builtin_amdgcn_exp2f(m_run - mnew);
            m_run = mnew;
            l_run *= corr;
            float cb[4];
#pragma unroll
            for (int r = 0; r < 4; ++r) cb[r] = __shfl(corr, lgrp * 4 + r);
#pragma unroll
            for (int n = 0; n < 4; n++)
#pragma unroll
                for (int r = 0; r < 4; r++) o_acc[n][r] *= cb[r];
        }

        float su = 0.f;
#pragma unroll
        for (int f = 0; f < 4; ++f)
#pragma unroll
            for (int r = 0; r < 4; ++r) {
                float pv = __builtin_amdgcn_exp2f(x[f][r] - m_run);
                x[f][r] = pv;
                su += pv;
            }
        l_run += su;

#pragma unroll
        for (int f = 0; f < 4; ++f) {
            unsigned int plo, phi;
            asm("v_cvt_pk_bf16_f32 %0, %1, %2"
                : "=v"(plo)
                : "v"(x[f][0]), "v"(x[f][1]));
            asm("v_cvt_pk_bf16_f32 %0, %1, %2"
                : "=v"(phi)
                : "v"(x[f][2]), "v"(x[f][3]));
            const int chunk = (f * 2 + (lgrp >> 1)) ^ (lrow & 7);
            uint2 pw;
            pw.x = plo;
            pw.y = phi;
            *reinterpret_cast<uint2*>(
                &Ps[w][lrow * 64 + chunk * 8 + (lgrp & 1) * 4]) = pw;
        }

        const unsigned short* vbuf = &Vs[cur][0];
        __builtin_amdgcn_s_setprio(1);
#pragma unroll
        for (int jc = 0; jc < 2; ++jc) {
            int pc = ((4 * jc + lgrp) ^ (lrow & 7)) * 8;
            bf16x8 pa =
                *reinterpret_cast<const bf16x8*>(&Ps[w][0] + lrow * 64 + pc);
#pragma unroll
            for (int n = 0; n < 4; n++) {
                int vrow = n * 16 + lrow;
                bf16x8 vb =
                    *reinterpret_cast<const bf16x8*>(vbuf + vrow * 64 + pc);
                o_acc[n] = MFMA16(pa, vb, o_acc[n]);
            }
        }
        __builtin_amdgcn_s_setprio(0);

        if (kv < 15) {
            asm volatile("s_waitcnt vmcnt(0)" ::: "memory");
            __syncthreads();
        }
    }

    float lt = l_run + __shfl_xor(l_run, 16);
    lt += __shfl_xor(lt, 32);
    float rl[4];
#pragma unroll
    for (int r = 0; r < 4; ++r) rl[r] = 1.0f / __shfl(lt, lgrp * 4 + r);

#pragma unroll
    for (int n = 0; n < 4; n++) {
#pragma unroll
        for (int r = 0; r < 4; r++) {
            float val = o_acc[n][r] * rl[r];
            int ia = qt * 64 + w * 16 + lgrp * 4 + r;
            size_t m = (size_t)b * 1024 + ia;
            int col = h * 64 + n * 16 + lrow;
            unsigned short hi = f2bf(val);
            float rres = val - bf2f(hi);
            A3[m * 2048 + col] = hi;
            A3[m * 2048 + 1024 + col] = f2bf(rres);
        }
    }
}

extern "C" void kernel_launch(void* const* d_in, const int* in_sizes, int n_in,
                              void* d_out, int out_size, void* d_ws,
                              size_t ws_size, hipStream_t stream) {
    const float* x = (const float*)d_in[0];
    const float* w_qkv = (const float*)d_in[1];
    const float* w_out = (const float*)d_in[2];
    const float* rel_bias = (const float*)d_in[3];
    float* out = (float*)d_out;

    char* ws = (char*)d_ws;
    size_t off = 0;
    auto alloc = [&](size_t bytes) {
        char* p = ws + off;
        off += (bytes + 255) & ~(size_t)255;
        return p;
    };
    unsigned short* A1h = (unsigned short*)alloc((size_t)4096 * 1024 * 2);
    unsigned short* W1h = (unsigned short*)alloc((size_t)3072 * 1024 * 2);
    unsigned short* Qb = (unsigned short*)alloc((size_t)64 * 1024 * 64 * 2);
    unsigned short* Kb = (unsigned short*)alloc((size_t)64 * 1024 * 64 * 2);
    unsigned short* Vb = (unsigned short*)alloc((size_t)64 * 1024 * 64 * 2);
    unsigned short* A3s = (unsigned short*)alloc((size_t)4096 * 2048 * 2);
    unsigned short* W3s = (unsigned short*)alloc((size_t)1024 * 2048 * 2);
    // V^T aliases A1h (8 MB each): A1h dead after gemm256_hi; transpose_v after.
    unsigned short* Vtg = A1h;

    hipLaunchKernelGGL(prep_hi_rows, dim3(1024), dim3(256), 0, stream, x, A1h,
                       4096 * 256);
    hipLaunchKernelGGL(prep_hi_wqkv, dim3(768), dim3(256), 0, stream, w_qkv,
                       W1h);
    hipLaunchKernelGGL(prep_split_rows, dim3(256), dim3(256), 0, stream, w_out,
                       W3s, 1024 * 256);
    hipLaunchKernelGGL(gemm256_hi, dim3(12, 16), dim3(512), 0, stream, A1h, W1h,
                       Qb, Kb, Vb);
    hipLaunchKernelGGL(transpose_v, dim3(16, 64), dim3(256), 0, stream, Vb, Vtg);
    hipLaunchKernelGGL(attn_kernel, dim3(16, 64), dim3(256), 0, stream, Qb, Kb,
                       Vtg, rel_bias, A3s);
    hipLaunchKernelGGL(gemm_out_v2, dim3(8, 64), dim3(256), 0, stream, A3s, W3s,
                       out);
}

// Round 8
// 160.870 us; speedup vs baseline: 1.7924x; 1.0003x over previous
//
#include <hip/hip_runtime.h>
#include <hip/hip_bf16.h>

typedef short bf16x8 __attribute__((ext_vector_type(8)));
typedef float f32x4  __attribute__((ext_vector_type(4)));

typedef __attribute__((address_space(3))) void lds_t;
typedef __attribute__((address_space(1))) void gbl_t;

#define MFMA16(a,b,c) __builtin_amdgcn_mfma_f32_16x16x32_bf16((a),(b),(c),0,0,0)

__device__ __forceinline__ unsigned short f2bf(float f) {
    __hip_bfloat16 h = __float2bfloat16(f);
    return __builtin_bit_cast(unsigned short, h);
}
__device__ __forceinline__ float bf2f(unsigned short u) {
    __hip_bfloat16 h = __builtin_bit_cast(__hip_bfloat16, u);
    return __bfloat162float(h);
}

// f32 [R][1024] -> bf16 hi-only compact [R][1024].  float4 vectorized.
__global__ void prep_hi_rows(const float* __restrict__ src,
                             unsigned short* __restrict__ dst, int total4) {
    for (int idx = blockIdx.x * blockDim.x + threadIdx.x; idx < total4;
         idx += gridDim.x * blockDim.x) {
        int base = idx * 4;
        float4 v = *reinterpret_cast<const float4*>(src + base);
        ushort4 hi;
        hi.x = f2bf(v.x);
        hi.y = f2bf(v.y);
        hi.z = f2bf(v.z);
        hi.w = f2bf(v.w);
        *reinterpret_cast<ushort4*>(dst + base) = hi;
    }
}

// w_qkv [3072][1024], einops row permute (out row n = which*1024+h*64+d reads
// src row d*48+which*16+h) -> bf16 hi-only compact [3072][1024].
__global__ void prep_hi_wqkv(const float* __restrict__ w,
                             unsigned short* __restrict__ dst) {
    for (int idx = blockIdx.x * blockDim.x + threadIdx.x; idx < 3072 * 256;
         idx += gridDim.x * blockDim.x) {
        int base = idx * 4;
        int n = base >> 10, c = base & 1023;
        int d = n & 63, which = n >> 10, h = (n >> 6) & 15;
        int srow = d * 48 + which * 16 + h;
        float4 v = *reinterpret_cast<const float4*>(w + (size_t)srow * 1024 + c);
        ushort4 hi;
        hi.x = f2bf(v.x);
        hi.y = f2bf(v.y);
        hi.z = f2bf(v.z);
        hi.w = f2bf(v.w);
        *reinterpret_cast<ushort4*>(dst + (size_t)n * 1024 + c) = hi;
    }
}

// Split f32 rows [R][1024] -> dst [R][2048] = [hi | lo] bf16 (out-proj weight).
__global__ void prep_split_rows(const float* __restrict__ src,
                                unsigned short* __restrict__ dst, int total4) {
    for (int idx = blockIdx.x * blockDim.x + threadIdx.x; idx < total4;
         idx += gridDim.x * blockDim.x) {
        int base = idx * 4;
        int m = base >> 10, c = base & 1023;
        float4 v = *reinterpret_cast<const float4*>(src + base);
        ushort4 hi, lo;
        hi.x = f2bf(v.x); lo.x = f2bf(v.x - bf2f(hi.x));
        hi.y = f2bf(v.y); lo.y = f2bf(v.y - bf2f(hi.y));
        hi.z = f2bf(v.z); lo.z = f2bf(v.z - bf2f(hi.z));
        hi.w = f2bf(v.w); lo.w = f2bf(v.w - bf2f(hi.w));
        *reinterpret_cast<ushort4*>(dst + (size_t)m * 2048 + c) = hi;
        *reinterpret_cast<ushort4*>(dst + (size_t)m * 2048 + 1024 + c) = lo;
    }
}

// ============================================================================
// 256x256 hi-only bf16 GEMM for QKV.  (unchanged from R5 — see R4/R5 notes)
// ============================================================================
__global__ __launch_bounds__(512, 2) void gemm256_hi(
    const unsigned short* __restrict__ A, const unsigned short* __restrict__ B,
    unsigned short* __restrict__ outQ, unsigned short* __restrict__ outK,
    unsigned short* __restrict__ outV) {
    __shared__ unsigned short lds[65536];  // A ring [0,32768), B ring [32768,65536)
    const int tid = threadIdx.x;
    const int wid = tid >> 6, lane = tid & 63;
    const int lrow = lane & 15, lgrp = lane >> 4;
    const int wr = wid >> 2, wc = wid & 3;
    const int mtile = blockIdx.y * 256, ntile = blockIdx.x * 256;

    const int csw = lgrp ^ ((lrow >> 1) & 3);
    const int aoff = (wr * 128 + lrow) * 32 + csw * 8;
    const int boff = 32768 + (wc * 64 + lrow) * 32 + csw * 8;

    const int sreg = wid * 2;
    const int srow0 = sreg * 16 + (lane >> 2);
    const int srow1 = (sreg + 1) * 16 + (lane >> 2);
    const int schunk = (lane & 3) ^ ((lane >> 3) & 3);
    const int sdst0 = sreg * 512;

    f32x4 acc[8][4];
#pragma unroll
    for (int i = 0; i < 8; ++i)
#pragma unroll
        for (int j = 0; j < 4; ++j) {
            f32x4 z = {0.f, 0.f, 0.f, 0.f};
            acc[i][j] = z;
        }

#pragma unroll
    for (int s0 = 0; s0 < 2; ++s0) {
        const int kb = s0 * 32;
        __builtin_amdgcn_global_load_lds(
            (const gbl_t*)(A + (size_t)(mtile + srow0) * 1024 + kb + schunk * 8),
            (lds_t*)(lds + s0 * 8192 + sdst0), 16, 0, 0);
        __builtin_amdgcn_global_load_lds(
            (const gbl_t*)(A + (size_t)(mtile + srow1) * 1024 + kb + schunk * 8),
            (lds_t*)(lds + s0 * 8192 + sdst0 + 512), 16, 0, 0);
        __builtin_amdgcn_global_load_lds(
            (const gbl_t*)(B + (size_t)(ntile + srow0) * 1024 + kb + schunk * 8),
            (lds_t*)(lds + 32768 + s0 * 8192 + sdst0), 16, 0, 0);
        __builtin_amdgcn_global_load_lds(
            (const gbl_t*)(B + (size_t)(ntile + srow1) * 1024 + kb + schunk * 8),
            (lds_t*)(lds + 32768 + s0 * 8192 + sdst0 + 512), 16, 0, 0);
    }
    asm volatile("s_waitcnt vmcnt(4)" ::: "memory");
    __syncthreads();

    for (int s = 0; s < 32; ++s) {
        const int sa = s & 3;
        const unsigned short* sbase = lds + sa * 8192;

        bf16x8 af[8];
#pragma unroll
        for (int i = 0; i < 8; ++i)
            af[i] = *reinterpret_cast<const bf16x8*>(sbase + aoff + i * 512);
        bf16x8 b0 = *reinterpret_cast<const bf16x8*>(sbase + boff);
        bf16x8 b1 = *reinterpret_cast<const bf16x8*>(sbase + boff + 512);

        if (s <= 29) {
            const int kb2 = (s + 2) * 32;
            const int s2 = (s + 2) & 3;
            __builtin_amdgcn_global_load_lds(
                (const gbl_t*)(A + (size_t)(mtile + srow0) * 1024 + kb2 + schunk * 8),
                (lds_t*)(lds + s2 * 8192 + sdst0), 16, 0, 0);
            __builtin_amdgcn_global_load_lds(
                (const gbl_t*)(A + (size_t)(mtile + srow1) * 1024 + kb2 + schunk * 8),
                (lds_t*)(lds + s2 * 8192 + sdst0 + 512), 16, 0, 0);
        }
        __builtin_amdgcn_s_setprio(1);
#pragma unroll
        for (int i = 0; i < 8; ++i) {
            acc[i][0] = MFMA16(af[i], b0, acc[i][0]);
            acc[i][1] = MFMA16(af[i], b1, acc[i][1]);
        }
        __builtin_amdgcn_s_setprio(0);

        bf16x8 b2 = *reinterpret_cast<const bf16x8*>(sbase + boff + 1024);
        bf16x8 b3 = *reinterpret_cast<const bf16x8*>(sbase + boff + 1536);
        if (s <= 29) {
            const int kb2 = (s + 2) * 32;
            const int s2 = (s + 2) & 3;
            __builtin_amdgcn_global_load_lds(
                (const gbl_t*)(B + (size_t)(ntile + srow0) * 1024 + kb2 + schunk * 8),
                (lds_t*)(lds + 32768 + s2 * 8192 + sdst0), 16, 0, 0);
            __builtin_amdgcn_global_load_lds(
                (const gbl_t*)(B + (size_t)(ntile + srow1) * 1024 + kb2 + schunk * 8),
                (lds_t*)(lds + 32768 + s2 * 8192 + sdst0 + 512), 16, 0, 0);
        }
        __builtin_amdgcn_s_setprio(1);
#pragma unroll
        for (int i = 0; i < 8; ++i) {
            acc[i][2] = MFMA16(af[i], b2, acc[i][2]);
            acc[i][3] = MFMA16(af[i], b3, acc[i][3]);
        }
        __builtin_amdgcn_s_setprio(0);

        if (s < 31) {
            if (s <= 29)
                asm volatile("s_waitcnt vmcnt(4)" ::: "memory");
            else
                asm volatile("s_waitcnt vmcnt(0)" ::: "memory");
            __syncthreads();
        }
    }

#pragma unroll
    for (int i = 0; i < 8; ++i) {
#pragma unroll
        for (int j = 0; j < 4; ++j) {
#pragma unroll
            for (int r = 0; r < 4; ++r) {
                float v = acc[i][j][r];
                int m = mtile + wr * 128 + i * 16 + lgrp * 4 + r;
                int n = ntile + wc * 64 + j * 16 + lrow;
                int which = n >> 10;
                int hh = (n >> 6) & 15;
                int d = n & 63;
                int b = m >> 10, t = m & 1023;
                unsigned short* dstp =
                    (which == 0) ? outQ : ((which == 1) ? outK : outV);
                dstp[((size_t)((b << 4) + hh) * 1024 + t) * 64 + d] = f2bf(v);
            }
        }
    }
}

// ============================================================================
// Out-projection split GEMM v3 (R8).  C[4096][1024] = A3[hi|lo] x W3[hi|lo],
// virtual K=3072 (hi.hi + hi.lo + lo.hi), 96 steps of BK=32.  Tile 64x128,
// 512 blocks, 4 waves (2Mx2N), acc[2][4].
// R8 fixes vs v2 (R7 post-mortem: per-step ~1400cy = vmcnt(0) drain; FETCH
// 101MB = A streamed through L2 every sweep):
//  (1) 4-slot LDS ring + counted vmcnt(3): stage slot s+2 while computing s;
//      wait only for slot s+1's 3 loads (this step's 3 stay in flight) —
//      load latency spans 2 steps, never drains to 0 mid-loop (T4).
//  (2) XCD-aware bijective swizzle (T1): xcd=h&7 owns 8 consecutive y-tiles;
//      concurrent blocks per XCD share one B-panel + 8 A-tiles (~2.5MB < L2).
// Chunk-XOR swizzle both-sides (0 conflicts, R7-verified) unchanged.
// ============================================================================
__global__ __launch_bounds__(256, 3) void gemm_out_v3(
    const unsigned short* __restrict__ A, const unsigned short* __restrict__ B,
    float* __restrict__ outF) {
    __shared__ unsigned short As[4][64 * 32];   // 16 KB ring
    __shared__ unsigned short Bs[4][128 * 32];  // 32 KB ring
    const int tid = threadIdx.x;
    const int wid = tid >> 6, lane = tid & 63;
    const int lrow = lane & 15, lgrp = lane >> 4;
    const int wr = wid >> 1, wc = wid & 1;
    // XCD swizzle: h -> (xcd, within); y = xcd*8 + (within&7), x = within>>3.
    const int h = blockIdx.x;
    const int xcd = h & 7, within = h >> 3;
    const int mtile = (xcd * 8 + (within & 7)) * 64;
    const int ntile = (within >> 3) * 128;

    const int csw = lgrp ^ ((lrow >> 1) & 3);
    const int aoff = (wr * 32 + lrow) * 32 + csw * 8;  // + i*512
    const int boff = (wc * 64 + lrow) * 32 + csw * 8;  // + j*512

    const int srow = tid >> 2;                        // 0..63
    const int schunk = (tid & 3) ^ ((tid >> 3) & 3);  // inverse-swizzled src
    const unsigned short* Arow = A + (size_t)(mtile + srow) * 2048 + schunk * 8;
    const unsigned short* Brow0 = B + (size_t)(ntile + srow) * 2048 + schunk * 8;
    const unsigned short* Brow1 =
        B + (size_t)(ntile + 64 + srow) * 2048 + schunk * 8;

    f32x4 acc[2][4];
#pragma unroll
    for (int i = 0; i < 2; ++i)
#pragma unroll
        for (int j = 0; j < 4; ++j) {
            f32x4 z = {0.f, 0.f, 0.f, 0.f};
            acc[i][j] = z;
        }

    // prologue: stage steps 0,1 into slots 0,1 (kb<1024 -> ac=bc=kb)
#pragma unroll
    for (int s0 = 0; s0 < 2; ++s0) {
        const int kb = s0 * 32;
        __builtin_amdgcn_global_load_lds((const gbl_t*)(Arow + kb),
                                         (lds_t*)(&As[s0][0] + tid * 8), 16, 0,
                                         0);
        __builtin_amdgcn_global_load_lds((const gbl_t*)(Brow0 + kb),
                                         (lds_t*)(&Bs[s0][0] + tid * 8), 16, 0,
                                         0);
        __builtin_amdgcn_global_load_lds((const gbl_t*)(Brow1 + kb),
                                         (lds_t*)(&Bs[s0][0] + 2048 + tid * 8),
                                         16, 0, 0);
    }
    asm volatile("s_waitcnt vmcnt(3)" ::: "memory");  // slot 0 landed
    __syncthreads();

    for (int s = 0; s < 96; ++s) {
        const int sa = s & 3;
        // stage slot s+2 (no reader until 2 barriers from now)
        if (s <= 93) {
            const int kb = (s + 2) * 32;
            const int ac = (kb < 1024) ? kb : kb - 1024;
            const int bc = (kb < 2048) ? kb : kb - 2048;
            const int s2 = (s + 2) & 3;
            __builtin_amdgcn_global_load_lds((const gbl_t*)(Arow + ac),
                                             (lds_t*)(&As[s2][0] + tid * 8), 16,
                                             0, 0);
            __builtin_amdgcn_global_load_lds((const gbl_t*)(Brow0 + bc),
                                             (lds_t*)(&Bs[s2][0] + tid * 8), 16,
                                             0, 0);
            __builtin_amdgcn_global_load_lds(
                (const gbl_t*)(Brow1 + bc),
                (lds_t*)(&Bs[s2][0] + 2048 + tid * 8), 16, 0, 0);
        }
        bf16x8 af[2], bfv[4];
#pragma unroll
        for (int i = 0; i < 2; ++i)
            af[i] = *reinterpret_cast<const bf16x8*>(&As[sa][0] + aoff + i * 512);
#pragma unroll
        for (int j = 0; j < 4; ++j)
            bfv[j] =
                *reinterpret_cast<const bf16x8*>(&Bs[sa][0] + boff + j * 512);
        __builtin_amdgcn_s_setprio(1);
#pragma unroll
        for (int i = 0; i < 2; ++i)
#pragma unroll
            for (int j = 0; j < 4; ++j)
                acc[i][j] = MFMA16(af[i], bfv[j], acc[i][j]);
        __builtin_amdgcn_s_setprio(0);
        // counted wait: slot s+1 (3 loads, issued at s-1) landed; this step's
        // 3 loads stay in flight.  Never 0 mid-loop (T4).
        if (s < 95) {
            if (s <= 93)
                asm volatile("s_waitcnt vmcnt(3)" ::: "memory");
            else
                asm volatile("s_waitcnt vmcnt(0)" ::: "memory");
            __syncthreads();
        }
    }

#pragma unroll
    for (int i = 0; i < 2; ++i)
#pragma unroll
        for (int j = 0; j < 4; ++j)
#pragma unroll
            for (int r = 0; r < 4; ++r) {
                int m = mtile + wr * 32 + i * 16 + lgrp * 4 + r;
                int n = ntile + wc * 64 + j * 16 + lrow;
                outF[(size_t)m * 1024 + n] = acc[i][j][r];
            }
}

// V [bh][1024][64] -> V^T [bh][64][1024], LDS-tiled, coalesced both sides.
__global__ __launch_bounds__(256) void transpose_v(
    const unsigned short* __restrict__ Vb, unsigned short* __restrict__ Vtg) {
    __shared__ unsigned short L[64][72];
    const int tt = blockIdx.x, bh = blockIdx.y;
    const int tid = threadIdx.x;
#pragma unroll
    for (int e = 0; e < 2; ++e) {
        int chunk = e * 256 + tid;
        int r = chunk >> 3, c = (chunk & 7) * 8;
        uint4 v = *reinterpret_cast<const uint4*>(
            Vb + ((size_t)bh * 1024 + tt * 64 + r) * 64 + c);
        *reinterpret_cast<uint4*>(&L[r][c]) = v;
    }
    __syncthreads();
#pragma unroll
    for (int e = 0; e < 2; ++e) {
        int chunk = e * 256 + tid;
        int d = chunk >> 3, t0 = (chunk & 7) * 8;
        unsigned short tmp[8];
#pragma unroll
        for (int u = 0; u < 8; ++u) tmp[u] = L[t0 + u][d];
        *reinterpret_cast<uint4*>(Vtg + ((size_t)bh * 64 + d) * 1024 + tt * 64 +
                                  t0) = *reinterpret_cast<const uint4*>(tmp);
    }
}

// ============================================================================
// Flash attention (R6 structure, unchanged): swapped QK^T, row-local softmax
// in exp2 domain, defer-max, cvt_pk P-pack, K/V dbuf via global_load_lds.
// ============================================================================
__global__ __launch_bounds__(256) void attn_kernel(
    const unsigned short* __restrict__ Qb, const unsigned short* __restrict__ Kb,
    const unsigned short* __restrict__ Vtg, const float* __restrict__ rel_bias,
    unsigned short* __restrict__ A3) {
    const int qt = blockIdx.x;  // 0..15
    const int bh = blockIdx.y;  // 0..63
    const int b = bh >> 4, h = bh & 15;
    const int tid = threadIdx.x;
    const int w = tid >> 6, lane = tid & 63;
    const int lrow = lane & 15, lgrp = lane >> 4;
    const float LOG2E = 1.4426950408889634f;
    const float SCALE2 = 0.125f * 1.4426950408889634f;
    const float THR = 11.5f;  // ~8 nats in exp2 units

    __shared__ unsigned short Ks[2][64 * 64];
    __shared__ unsigned short Vs[2][64 * 64];
    __shared__ unsigned short Ps[4][16 * 64];
    __shared__ float Bias2[2][128];

    const unsigned short* Ktile = Kb + (size_t)bh * 1024 * 64;
    const unsigned short* Vtile = Vtg + (size_t)bh * 64 * 1024;

    const unsigned short* Qp =
        Qb + ((size_t)bh * 1024 + qt * 64 + w * 16 + lrow) * 64;
    bf16x8 qa0 = *reinterpret_cast<const bf16x8*>(Qp + lgrp * 8);
    bf16x8 qa1 = *reinterpret_cast<const bf16x8*>(Qp + 32 + lgrp * 8);

    const int sr0 = w * 16 + (lane >> 3);
    const int sc_lo = lane & 7;

    float m_run = -3.0e38f;
    float l_run = 0.f;
    f32x4 o_acc[4];
#pragma unroll
    for (int n = 0; n < 4; n++) {
        f32x4 z = {0.f, 0.f, 0.f, 0.f};
        o_acc[n] = z;
    }

    const int bbase = lgrp * 4 + 63 - w * 16 - lrow;

    {
#pragma unroll
        for (int i = 0; i < 2; ++i) {
            int r = sr0 + i * 8;
            int c = sc_lo ^ (r & 7);
            __builtin_amdgcn_global_load_lds(
                (const gbl_t*)(Ktile + (size_t)r * 64 + c * 8),
                (lds_t*)(&Ks[0][0] + w * 1024 + i * 512), 16, 0, 0);
            __builtin_amdgcn_global_load_lds(
                (const gbl_t*)(Vtile + (size_t)r * 1024 + c * 8),
                (lds_t*)(&Vs[0][0] + w * 1024 + i * 512), 16, 0, 0);
        }
        if (tid < 128) {
            int rowi = 0 - qt * 64 + 960 + tid;
            rowi = (rowi < 2046) ? rowi : 2046;
            Bias2[0][tid] = rel_bias[(size_t)rowi * 16 + h] * LOG2E;
        }
        asm volatile("s_waitcnt vmcnt(0)" ::: "memory");
        __syncthreads();
    }

    for (int kv = 0; kv < 16; ++kv) {
        const int cur = kv & 1;
        if (kv < 15) {
            const int j0n = (kv + 1) * 64;
#pragma unroll
            for (int i = 0; i < 2; ++i) {
                int r = sr0 + i * 8;
                int c = sc_lo ^ (r & 7);
                __builtin_amdgcn_global_load_lds(
                    (const gbl_t*)(Ktile + (size_t)(j0n + r) * 64 + c * 8),
                    (lds_t*)(&Ks[cur ^ 1][0] + w * 1024 + i * 512), 16, 0, 0);
                __builtin_amdgcn_global_load_lds(
                    (const gbl_t*)(Vtile + (size_t)r * 1024 + j0n + c * 8),
                    (lds_t*)(&Vs[cur ^ 1][0] + w * 1024 + i * 512), 16, 0, 0);
            }
            if (tid < 128) {
                int rowi = j0n - qt * 64 + 960 + tid;
                rowi = (rowi < 2046) ? rowi : 2046;
                Bias2[cur ^ 1][tid] = rel_bias[(size_t)rowi * 16 + h] * LOG2E;
            }
        }

        const unsigned short* kbuf = &Ks[cur][0];
        f32x4 s[4];
        __builtin_amdgcn_s_setprio(1);
#pragma unroll
        for (int f = 0; f < 4; ++f) {
            int krow = f * 16 + lrow;
            int sw0 = (lgrp ^ (lrow & 7)) * 8;
            int sw1 = ((4 | lgrp) ^ (lrow & 7)) * 8;
            bf16x8 kb0 = *reinterpret_cast<const bf16x8*>(kbuf + krow * 64 + sw0);
            bf16x8 kb1 = *reinterpret_cast<const bf16x8*>(kbuf + krow * 64 + sw1);
            f32x4 z = {0.f, 0.f, 0.f, 0.f};
            z = MFMA16(kb0, qa0, z);
            z = MFMA16(kb1, qa1, z);
            s[f] = z;
        }
        __builtin_amdgcn_s_setprio(0);

        float x[4][4];
        float pm = -3.0e38f;
#pragma unroll
        for (int f = 0; f < 4; ++f)
#pragma unroll
            for (int r = 0; r < 4; ++r) {
                float xv = s[f][r] * SCALE2 + Bias2[cur][bbase + f * 16 + r];
                x[f][r] = xv;
                pm = fmaxf(pm, xv);
            }
        pm = fmaxf(pm, __shfl_xor(pm, 16));
        pm = fmaxf(pm, __shfl_xor(pm, 32));

        if (!__all(pm - m_run <= THR)) {
            float mnew = fmaxf(m_run, pm);
            float corr = __builtin_amdgcn_exp2f(m_run - mnew);
            m_run = mnew;
            l_run *= corr;
            float cb[4];
#pragma unroll
            for (int r = 0; r < 4; ++r) cb[r] = __shfl(corr, lgrp * 4 + r);
#pragma unroll
            for (int n = 0; n < 4; n++)
#pragma unroll
                for (int r = 0; r < 4; r++) o_acc[n][r] *= cb[r];
        }

        float su = 0.f;
#pragma unroll
        for (int f = 0; f < 4; ++f)
#pragma unroll
            for (int r = 0; r < 4; ++r) {
                float pv = __builtin_amdgcn_exp2f(x[f][r] - m_run);
                x[f][r] = pv;
                su += pv;
            }
        l_run += su;

#pragma unroll
        for (int f = 0; f < 4; ++f) {
            unsigned int plo, phi;
            asm("v_cvt_pk_bf16_f32 %0, %1, %2"
                : "=v"(plo)
                : "v"(x[f][0]), "v"(x[f][1]));
            asm("v_cvt_pk_bf16_f32 %0, %1, %2"
                : "=v"(phi)
                : "v"(x[f][2]), "v"(x[f][3]));
            const int chunk = (f * 2 + (lgrp >> 1)) ^ (lrow & 7);
            uint2 pw;
            pw.x = plo;
            pw.y = phi;
            *reinterpret_cast<uint2*>(
                &Ps[w][lrow * 64 + chunk * 8 + (lgrp & 1) * 4]) = pw;
        }

        const unsigned short* vbuf = &Vs[cur][0];
        __builtin_amdgcn_s_setprio(1);
#pragma unroll
        for (int jc = 0; jc < 2; ++jc) {
            int pc = ((4 * jc + lgrp) ^ (lrow & 7)) * 8;
            bf16x8 pa =
                *reinterpret_cast<const bf16x8*>(&Ps[w][0] + lrow * 64 + pc);
#pragma unroll
            for (int n = 0; n < 4; n++) {
                int vrow = n * 16 + lrow;
                bf16x8 vb =
                    *reinterpret_cast<const bf16x8*>(vbuf + vrow * 64 + pc);
                o_acc[n] = MFMA16(pa, vb, o_acc[n]);
            }
        }
        __builtin_amdgcn_s_setprio(0);

        if (kv < 15) {
            asm volatile("s_waitcnt vmcnt(0)" ::: "memory");
            __syncthreads();
        }
    }

    float lt = l_run + __shfl_xor(l_run, 16);
    lt += __shfl_xor(lt, 32);
    float rl[4];
#pragma unroll
    for (int r = 0; r < 4; ++r) rl[r] = 1.0f / __shfl(lt, lgrp * 4 + r);

#pragma unroll
    for (int n = 0; n < 4; n++) {
#pragma unroll
        for (int r = 0; r < 4; r++) {
            float val = o_acc[n][r] * rl[r];
            int ia = qt * 64 + w * 16 + lgrp * 4 + r;
            size_t m = (size_t)b * 1024 + ia;
            int col = h * 64 + n * 16 + lrow;
            unsigned short hi = f2bf(val);
            float rres = val - bf2f(hi);
            A3[m * 2048 + col] = hi;
            A3[m * 2048 + 1024 + col] = f2bf(rres);
        }
    }
}

extern "C" void kernel_launch(void* const* d_in, const int* in_sizes, int n_in,
                              void* d_out, int out_size, void* d_ws,
                              size_t ws_size, hipStream_t stream) {
    const float* x = (const float*)d_in[0];
    const float* w_qkv = (const float*)d_in[1];
    const float* w_out = (const float*)d_in[2];
    const float* rel_bias = (const float*)d_in[3];
    float* out = (float*)d_out;

    char* ws = (char*)d_ws;
    size_t off = 0;
    auto alloc = [&](size_t bytes) {
        char* p = ws + off;
        off += (bytes + 255) & ~(size_t)255;
        return p;
    };
    unsigned short* A1h = (unsigned short*)alloc((size_t)4096 * 1024 * 2);
    unsigned short* W1h = (unsigned short*)alloc((size_t)3072 * 1024 * 2);
    unsigned short* Qb = (unsigned short*)alloc((size_t)64 * 1024 * 64 * 2);
    unsigned short* Kb = (unsigned short*)alloc((size_t)64 * 1024 * 64 * 2);
    unsigned short* Vb = (unsigned short*)alloc((size_t)64 * 1024 * 64 * 2);
    unsigned short* A3s = (unsigned short*)alloc((size_t)4096 * 2048 * 2);
    unsigned short* W3s = (unsigned short*)alloc((size_t)1024 * 2048 * 2);
    // V^T aliases A1h (8 MB each): A1h dead after gemm256_hi; transpose_v after.
    unsigned short* Vtg = A1h;

    hipLaunchKernelGGL(prep_hi_rows, dim3(1024), dim3(256), 0, stream, x, A1h,
                       4096 * 256);
    hipLaunchKernelGGL(prep_hi_wqkv, dim3(768), dim3(256), 0, stream, w_qkv,
                       W1h);
    hipLaunchKernelGGL(prep_split_rows, dim3(256), dim3(256), 0, stream, w_out,
                       W3s, 1024 * 256);
    hipLaunchKernelGGL(gemm256_hi, dim3(12, 16), dim3(512), 0, stream, A1h, W1h,
                       Qb, Kb, Vb);
    hipLaunchKernelGGL(transpose_v, dim3(16, 64), dim3(256), 0, stream, Vb, Vtg);
    hipLaunchKernelGGL(attn_kernel, dim3(16, 64), dim3(256), 0, stream, Qb, Kb,
                       Vtg, rel_bias, A3s);
    hipLaunchKernelGGL(gemm_out_v3, dim3(512), dim3(256), 0, stream, A3s, W3s,
                       out);
}

// Round 9
// 128.325 us; speedup vs baseline: 2.2470x; 1.2536x over previous
//
#include <hip/hip_runtime.h>
#include <hip/hip_bf16.h>

typedef short bf16x8 __attribute__((ext_vector_type(8)));
typedef float f32x4  __attribute__((ext_vector_type(4)));

typedef __attribute__((address_space(3))) void lds_t;
typedef __attribute__((address_space(1))) void gbl_t;

#define MFMA16(a,b,c) __builtin_amdgcn_mfma_f32_16x16x32_bf16((a),(b),(c),0,0,0)

__device__ __forceinline__ unsigned short f2bf(float f) {
    __hip_bfloat16 h = __float2bfloat16(f);
    return __builtin_bit_cast(unsigned short, h);
}
__device__ __forceinline__ float bf2f(unsigned short u) {
    __hip_bfloat16 h = __builtin_bit_cast(__hip_bfloat16, u);
    return __bfloat162float(h);
}

// f32 [R][1024] -> bf16 hi-only compact [R][1024].  float4 vectorized.
__global__ void prep_hi_rows(const float* __restrict__ src,
                             unsigned short* __restrict__ dst, int total4) {
    for (int idx = blockIdx.x * blockDim.x + threadIdx.x; idx < total4;
         idx += gridDim.x * blockDim.x) {
        int base = idx * 4;
        float4 v = *reinterpret_cast<const float4*>(src + base);
        ushort4 hi;
        hi.x = f2bf(v.x);
        hi.y = f2bf(v.y);
        hi.z = f2bf(v.z);
        hi.w = f2bf(v.w);
        *reinterpret_cast<ushort4*>(dst + base) = hi;
    }
}

// w_qkv [3072][1024], einops row permute (out row n = which*1024+h*64+d reads
// src row d*48+which*16+h) -> bf16 hi-only compact [3072][1024].
__global__ void prep_hi_wqkv(const float* __restrict__ w,
                             unsigned short* __restrict__ dst) {
    for (int idx = blockIdx.x * blockDim.x + threadIdx.x; idx < 3072 * 256;
         idx += gridDim.x * blockDim.x) {
        int base = idx * 4;
        int n = base >> 10, c = base & 1023;
        int d = n & 63, which = n >> 10, h = (n >> 6) & 15;
        int srow = d * 48 + which * 16 + h;
        float4 v = *reinterpret_cast<const float4*>(w + (size_t)srow * 1024 + c);
        ushort4 hi;
        hi.x = f2bf(v.x);
        hi.y = f2bf(v.y);
        hi.z = f2bf(v.z);
        hi.w = f2bf(v.w);
        *reinterpret_cast<ushort4*>(dst + (size_t)n * 1024 + c) = hi;
    }
}

// ============================================================================
// 256x256 hi-only bf16 GEMM for QKV.  (unchanged from R5 — see R4/R5 notes)
// ============================================================================
__global__ __launch_bounds__(512, 2) void gemm256_hi(
    const unsigned short* __restrict__ A, const unsigned short* __restrict__ B,
    unsigned short* __restrict__ outQ, unsigned short* __restrict__ outK,
    unsigned short* __restrict__ outV) {
    __shared__ unsigned short lds[65536];  // A ring [0,32768), B ring [32768,65536)
    const int tid = threadIdx.x;
    const int wid = tid >> 6, lane = tid & 63;
    const int lrow = lane & 15, lgrp = lane >> 4;
    const int wr = wid >> 2, wc = wid & 3;
    const int mtile = blockIdx.y * 256, ntile = blockIdx.x * 256;

    const int csw = lgrp ^ ((lrow >> 1) & 3);
    const int aoff = (wr * 128 + lrow) * 32 + csw * 8;
    const int boff = 32768 + (wc * 64 + lrow) * 32 + csw * 8;

    const int sreg = wid * 2;
    const int srow0 = sreg * 16 + (lane >> 2);
    const int srow1 = (sreg + 1) * 16 + (lane >> 2);
    const int schunk = (lane & 3) ^ ((lane >> 3) & 3);
    const int sdst0 = sreg * 512;

    f32x4 acc[8][4];
#pragma unroll
    for (int i = 0; i < 8; ++i)
#pragma unroll
        for (int j = 0; j < 4; ++j) {
            f32x4 z = {0.f, 0.f, 0.f, 0.f};
            acc[i][j] = z;
        }

#pragma unroll
    for (int s0 = 0; s0 < 2; ++s0) {
        const int kb = s0 * 32;
        __builtin_amdgcn_global_load_lds(
            (const gbl_t*)(A + (size_t)(mtile + srow0) * 1024 + kb + schunk * 8),
            (lds_t*)(lds + s0 * 8192 + sdst0), 16, 0, 0);
        __builtin_amdgcn_global_load_lds(
            (const gbl_t*)(A + (size_t)(mtile + srow1) * 1024 + kb + schunk * 8),
            (lds_t*)(lds + s0 * 8192 + sdst0 + 512), 16, 0, 0);
        __builtin_amdgcn_global_load_lds(
            (const gbl_t*)(B + (size_t)(ntile + srow0) * 1024 + kb + schunk * 8),
            (lds_t*)(lds + 32768 + s0 * 8192 + sdst0), 16, 0, 0);
        __builtin_amdgcn_global_load_lds(
            (const gbl_t*)(B + (size_t)(ntile + srow1) * 1024 + kb + schunk * 8),
            (lds_t*)(lds + 32768 + s0 * 8192 + sdst0 + 512), 16, 0, 0);
    }
    asm volatile("s_waitcnt vmcnt(4)" ::: "memory");
    __syncthreads();

    for (int s = 0; s < 32; ++s) {
        const int sa = s & 3;
        const unsigned short* sbase = lds + sa * 8192;

        bf16x8 af[8];
#pragma unroll
        for (int i = 0; i < 8; ++i)
            af[i] = *reinterpret_cast<const bf16x8*>(sbase + aoff + i * 512);
        bf16x8 b0 = *reinterpret_cast<const bf16x8*>(sbase + boff);
        bf16x8 b1 = *reinterpret_cast<const bf16x8*>(sbase + boff + 512);

        if (s <= 29) {
            const int kb2 = (s + 2) * 32;
            const int s2 = (s + 2) & 3;
            __builtin_amdgcn_global_load_lds(
                (const gbl_t*)(A + (size_t)(mtile + srow0) * 1024 + kb2 + schunk * 8),
                (lds_t*)(lds + s2 * 8192 + sdst0), 16, 0, 0);
            __builtin_amdgcn_global_load_lds(
                (const gbl_t*)(A + (size_t)(mtile + srow1) * 1024 + kb2 + schunk * 8),
                (lds_t*)(lds + s2 * 8192 + sdst0 + 512), 16, 0, 0);
        }
        __builtin_amdgcn_s_setprio(1);
#pragma unroll
        for (int i = 0; i < 8; ++i) {
            acc[i][0] = MFMA16(af[i], b0, acc[i][0]);
            acc[i][1] = MFMA16(af[i], b1, acc[i][1]);
        }
        __builtin_amdgcn_s_setprio(0);

        bf16x8 b2 = *reinterpret_cast<const bf16x8*>(sbase + boff + 1024);
        bf16x8 b3 = *reinterpret_cast<const bf16x8*>(sbase + boff + 1536);
        if (s <= 29) {
            const int kb2 = (s + 2) * 32;
            const int s2 = (s + 2) & 3;
            __builtin_amdgcn_global_load_lds(
                (const gbl_t*)(B + (size_t)(ntile + srow0) * 1024 + kb2 + schunk * 8),
                (lds_t*)(lds + 32768 + s2 * 8192 + sdst0), 16, 0, 0);
            __builtin_amdgcn_global_load_lds(
                (const gbl_t*)(B + (size_t)(ntile + srow1) * 1024 + kb2 + schunk * 8),
                (lds_t*)(lds + 32768 + s2 * 8192 + sdst0 + 512), 16, 0, 0);
        }
        __builtin_amdgcn_s_setprio(1);
#pragma unroll
        for (int i = 0; i < 8; ++i) {
            acc[i][2] = MFMA16(af[i], b2, acc[i][2]);
            acc[i][3] = MFMA16(af[i], b3, acc[i][3]);
        }
        __builtin_amdgcn_s_setprio(0);

        if (s < 31) {
            if (s <= 29)
                asm volatile("s_waitcnt vmcnt(4)" ::: "memory");
            else
                asm volatile("s_waitcnt vmcnt(0)" ::: "memory");
            __syncthreads();
        }
    }

#pragma unroll
    for (int i = 0; i < 8; ++i) {
#pragma unroll
        for (int j = 0; j < 4; ++j) {
#pragma unroll
            for (int r = 0; r < 4; ++r) {
                float v = acc[i][j][r];
                int m = mtile + wr * 128 + i * 16 + lgrp * 4 + r;
                int n = ntile + wc * 64 + j * 16 + lrow;
                int which = n >> 10;
                int hh = (n >> 6) & 15;
                int d = n & 63;
                int b = m >> 10, t = m & 1023;
                unsigned short* dstp =
                    (which == 0) ? outQ : ((which == 1) ? outK : outV);
                dstp[((size_t)((b << 4) + hh) * 1024 + t) * 64 + d] = f2bf(v);
            }
        }
    }
}

// ============================================================================
// Out-projection GEMM v4 (R9): HI-ONLY bf16, K=1024 (32 steps of BK=32).
// R8 post-mortem: the virtual-K=3072 split was unnecessary — the A operand
// (attention output) has magnitude ||p||2*sigma_v ~ 0.05, so hi-only cross-term
// error is absmax ~2e-4, negligible vs the 0.00195 bf16-storage floor and the
// 6.56e-3 threshold.  3x fewer steps on the same v3 skeleton:
// 64x128 tile, 512 blocks, 4-slot ring, counted vmcnt(3), XCD swizzle,
// chunk-XOR swizzle (0 conflicts).  A [4096][1024] compact, B [1024][1024].
// ============================================================================
__global__ __launch_bounds__(256, 3) void gemm_out_v4(
    const unsigned short* __restrict__ A, const unsigned short* __restrict__ B,
    float* __restrict__ outF) {
    __shared__ unsigned short As[4][64 * 32];   // 16 KB ring
    __shared__ unsigned short Bs[4][128 * 32];  // 32 KB ring
    const int tid = threadIdx.x;
    const int wid = tid >> 6, lane = tid & 63;
    const int lrow = lane & 15, lgrp = lane >> 4;
    const int wr = wid >> 1, wc = wid & 1;
    // XCD swizzle: h -> (xcd, within); y = xcd*8 + (within&7), x = within>>3.
    const int h = blockIdx.x;
    const int xcd = h & 7, within = h >> 3;
    const int mtile = (xcd * 8 + (within & 7)) * 64;
    const int ntile = (within >> 3) * 128;

    const int csw = lgrp ^ ((lrow >> 1) & 3);
    const int aoff = (wr * 32 + lrow) * 32 + csw * 8;  // + i*512
    const int boff = (wc * 64 + lrow) * 32 + csw * 8;  // + j*512

    const int srow = tid >> 2;                        // 0..63
    const int schunk = (tid & 3) ^ ((tid >> 3) & 3);  // inverse-swizzled src
    const unsigned short* Arow = A + (size_t)(mtile + srow) * 1024 + schunk * 8;
    const unsigned short* Brow0 = B + (size_t)(ntile + srow) * 1024 + schunk * 8;
    const unsigned short* Brow1 =
        B + (size_t)(ntile + 64 + srow) * 1024 + schunk * 8;

    f32x4 acc[2][4];
#pragma unroll
    for (int i = 0; i < 2; ++i)
#pragma unroll
        for (int j = 0; j < 4; ++j) {
            f32x4 z = {0.f, 0.f, 0.f, 0.f};
            acc[i][j] = z;
        }

    // prologue: stage steps 0,1 into slots 0,1
#pragma unroll
    for (int s0 = 0; s0 < 2; ++s0) {
        const int kb = s0 * 32;
        __builtin_amdgcn_global_load_lds((const gbl_t*)(Arow + kb),
                                         (lds_t*)(&As[s0][0] + tid * 8), 16, 0,
                                         0);
        __builtin_amdgcn_global_load_lds((const gbl_t*)(Brow0 + kb),
                                         (lds_t*)(&Bs[s0][0] + tid * 8), 16, 0,
                                         0);
        __builtin_amdgcn_global_load_lds((const gbl_t*)(Brow1 + kb),
                                         (lds_t*)(&Bs[s0][0] + 2048 + tid * 8),
                                         16, 0, 0);
    }
    asm volatile("s_waitcnt vmcnt(3)" ::: "memory");  // slot 0 landed
    __syncthreads();

    for (int s = 0; s < 32; ++s) {
        const int sa = s & 3;
        if (s <= 29) {
            const int kb = (s + 2) * 32;
            const int s2 = (s + 2) & 3;
            __builtin_amdgcn_global_load_lds((const gbl_t*)(Arow + kb),
                                             (lds_t*)(&As[s2][0] + tid * 8), 16,
                                             0, 0);
            __builtin_amdgcn_global_load_lds((const gbl_t*)(Brow0 + kb),
                                             (lds_t*)(&Bs[s2][0] + tid * 8), 16,
                                             0, 0);
            __builtin_amdgcn_global_load_lds(
                (const gbl_t*)(Brow1 + kb),
                (lds_t*)(&Bs[s2][0] + 2048 + tid * 8), 16, 0, 0);
        }
        bf16x8 af[2], bfv[4];
#pragma unroll
        for (int i = 0; i < 2; ++i)
            af[i] = *reinterpret_cast<const bf16x8*>(&As[sa][0] + aoff + i * 512);
#pragma unroll
        for (int j = 0; j < 4; ++j)
            bfv[j] =
                *reinterpret_cast<const bf16x8*>(&Bs[sa][0] + boff + j * 512);
        __builtin_amdgcn_s_setprio(1);
#pragma unroll
        for (int i = 0; i < 2; ++i)
#pragma unroll
            for (int j = 0; j < 4; ++j)
                acc[i][j] = MFMA16(af[i], bfv[j], acc[i][j]);
        __builtin_amdgcn_s_setprio(0);
        if (s < 31) {
            if (s <= 29)
                asm volatile("s_waitcnt vmcnt(3)" ::: "memory");
            else
                asm volatile("s_waitcnt vmcnt(0)" ::: "memory");
            __syncthreads();
        }
    }

#pragma unroll
    for (int i = 0; i < 2; ++i)
#pragma unroll
        for (int j = 0; j < 4; ++j)
#pragma unroll
            for (int r = 0; r < 4; ++r) {
                int m = mtile + wr * 32 + i * 16 + lgrp * 4 + r;
                int n = ntile + wc * 64 + j * 16 + lrow;
                outF[(size_t)m * 1024 + n] = acc[i][j][r];
            }
}

// V [bh][1024][64] -> V^T [bh][64][1024], LDS-tiled, coalesced both sides.
__global__ __launch_bounds__(256) void transpose_v(
    const unsigned short* __restrict__ Vb, unsigned short* __restrict__ Vtg) {
    __shared__ unsigned short L[64][72];
    const int tt = blockIdx.x, bh = blockIdx.y;
    const int tid = threadIdx.x;
#pragma unroll
    for (int e = 0; e < 2; ++e) {
        int chunk = e * 256 + tid;
        int r = chunk >> 3, c = (chunk & 7) * 8;
        uint4 v = *reinterpret_cast<const uint4*>(
            Vb + ((size_t)bh * 1024 + tt * 64 + r) * 64 + c);
        *reinterpret_cast<uint4*>(&L[r][c]) = v;
    }
    __syncthreads();
#pragma unroll
    for (int e = 0; e < 2; ++e) {
        int chunk = e * 256 + tid;
        int d = chunk >> 3, t0 = (chunk & 7) * 8;
        unsigned short tmp[8];
#pragma unroll
        for (int u = 0; u < 8; ++u) tmp[u] = L[t0 + u][d];
        *reinterpret_cast<uint4*>(Vtg + ((size_t)bh * 64 + d) * 1024 + tt * 64 +
                                  t0) = *reinterpret_cast<const uint4*>(tmp);
    }
}

// ============================================================================
// Flash attention (R6 structure): swapped QK^T, row-local softmax in exp2
// domain, defer-max, cvt_pk P-pack, K/V dbuf via global_load_lds.
// R9 change: epilogue writes COMPACT hi-only A3 [4096][1024] (out-proj is now
// hi-only; lo writes and residual math dropped).
// ============================================================================
__global__ __launch_bounds__(256) void attn_kernel(
    const unsigned short* __restrict__ Qb, const unsigned short* __restrict__ Kb,
    const unsigned short* __restrict__ Vtg, const float* __restrict__ rel_bias,
    unsigned short* __restrict__ A3) {
    const int qt = blockIdx.x;  // 0..15
    const int bh = blockIdx.y;  // 0..63
    const int b = bh >> 4, h = bh & 15;
    const int tid = threadIdx.x;
    const int w = tid >> 6, lane = tid & 63;
    const int lrow = lane & 15, lgrp = lane >> 4;
    const float LOG2E = 1.4426950408889634f;
    const float SCALE2 = 0.125f * 1.4426950408889634f;
    const float THR = 11.5f;  // ~8 nats in exp2 units

    __shared__ unsigned short Ks[2][64 * 64];
    __shared__ unsigned short Vs[2][64 * 64];
    __shared__ unsigned short Ps[4][16 * 64];
    __shared__ float Bias2[2][128];

    const unsigned short* Ktile = Kb + (size_t)bh * 1024 * 64;
    const unsigned short* Vtile = Vtg + (size_t)bh * 64 * 1024;

    const unsigned short* Qp =
        Qb + ((size_t)bh * 1024 + qt * 64 + w * 16 + lrow) * 64;
    bf16x8 qa0 = *reinterpret_cast<const bf16x8*>(Qp + lgrp * 8);
    bf16x8 qa1 = *reinterpret_cast<const bf16x8*>(Qp + 32 + lgrp * 8);

    const int sr0 = w * 16 + (lane >> 3);
    const int sc_lo = lane & 7;

    float m_run = -3.0e38f;
    float l_run = 0.f;
    f32x4 o_acc[4];
#pragma unroll
    for (int n = 0; n < 4; n++) {
        f32x4 z = {0.f, 0.f, 0.f, 0.f};
        o_acc[n] = z;
    }

    const int bbase = lgrp * 4 + 63 - w * 16 - lrow;

    {
#pragma unroll
        for (int i = 0; i < 2; ++i) {
            int r = sr0 + i * 8;
            int c = sc_lo ^ (r & 7);
            __builtin_amdgcn_global_load_lds(
                (const gbl_t*)(Ktile + (size_t)r * 64 + c * 8),
                (lds_t*)(&Ks[0][0] + w * 1024 + i * 512), 16, 0, 0);
            __builtin_amdgcn_global_load_lds(
                (const gbl_t*)(Vtile + (size_t)r * 1024 + c * 8),
                (lds_t*)(&Vs[0][0] + w * 1024 + i * 512), 16, 0, 0);
        }
        if (tid < 128) {
            int rowi = 0 - qt * 64 + 960 + tid;
            rowi = (rowi < 2046) ? rowi : 2046;
            Bias2[0][tid] = rel_bias[(size_t)rowi * 16 + h] * LOG2E;
        }
        asm volatile("s_waitcnt vmcnt(0)" ::: "memory");
        __syncthreads();
    }

    for (int kv = 0; kv < 16; ++kv) {
        const int cur = kv & 1;
        if (kv < 15) {
            const int j0n = (kv + 1) * 64;
#pragma unroll
            for (int i = 0; i < 2; ++i) {
                int r = sr0 + i * 8;
                int c = sc_lo ^ (r & 7);
                __builtin_amdgcn_global_load_lds(
                    (const gbl_t*)(Ktile + (size_t)(j0n + r) * 64 + c * 8),
                    (lds_t*)(&Ks[cur ^ 1][0] + w * 1024 + i * 512), 16, 0, 0);
                __builtin_amdgcn_global_load_lds(
                    (const gbl_t*)(Vtile + (size_t)r * 1024 + j0n + c * 8),
                    (lds_t*)(&Vs[cur ^ 1][0] + w * 1024 + i * 512), 16, 0, 0);
            }
            if (tid < 128) {
                int rowi = j0n - qt * 64 + 960 + tid;
                rowi = (rowi < 2046) ? rowi : 2046;
                Bias2[cur ^ 1][tid] = rel_bias[(size_t)rowi * 16 + h] * LOG2E;
            }
        }

        const unsigned short* kbuf = &Ks[cur][0];
        f32x4 s[4];
        __builtin_amdgcn_s_setprio(1);
#pragma unroll
        for (int f = 0; f < 4; ++f) {
            int krow = f * 16 + lrow;
            int sw0 = (lgrp ^ (lrow & 7)) * 8;
            int sw1 = ((4 | lgrp) ^ (lrow & 7)) * 8;
            bf16x8 kb0 = *reinterpret_cast<const bf16x8*>(kbuf + krow * 64 + sw0);
            bf16x8 kb1 = *reinterpret_cast<const bf16x8*>(kbuf + krow * 64 + sw1);
            f32x4 z = {0.f, 0.f, 0.f, 0.f};
            z = MFMA16(kb0, qa0, z);
            z = MFMA16(kb1, qa1, z);
            s[f] = z;
        }
        __builtin_amdgcn_s_setprio(0);

        float x[4][4];
        float pm = -3.0e38f;
#pragma unroll
        for (int f = 0; f < 4; ++f)
#pragma unroll
            for (int r = 0; r < 4; ++r) {
                float xv = s[f][r] * SCALE2 + Bias2[cur][bbase + f * 16 + r];
                x[f][r] = xv;
                pm = fmaxf(pm, xv);
            }
        pm = fmaxf(pm, __shfl_xor(pm, 16));
        pm = fmaxf(pm, __shfl_xor(pm, 32));

        if (!__all(pm - m_run <= THR)) {
            float mnew = fmaxf(m_run, pm);
            float corr = __builtin_amdgcn_exp2f(m_run - mnew);
            m_run = mnew;
            l_run *= corr;
            float cb[4];
#pragma unroll
            for (int r = 0; r < 4; ++r) cb[r] = __shfl(corr, lgrp * 4 + r);
#pragma unroll
            for (int n = 0; n < 4; n++)
#pragma unroll
                for (int r = 0; r < 4; r++) o_acc[n][r] *= cb[r];
        }

        float su = 0.f;
#pragma unroll
        for (int f = 0; f < 4; ++f)
#pragma unroll
            for (int r = 0; r < 4; ++r) {
                float pv = __builtin_amdgcn_exp2f(x[f][r] - m_run);
                x[f][r] = pv;
                su += pv;
            }
        l_run += su;

#pragma unroll
        for (int f = 0; f < 4; ++f) {
            unsigned int plo, phi;
            asm("v_cvt_pk_bf16_f32 %0, %1, %2"
                : "=v"(plo)
                : "v"(x[f][0]), "v"(x[f][1]));
            asm("v_cvt_pk_bf16_f32 %0, %1, %2"
                : "=v"(phi)
                : "v"(x[f][2]), "v"(x[f][3]));
            const int chunk = (f * 2 + (lgrp >> 1)) ^ (lrow & 7);
            uint2 pw;
            pw.x = plo;
            pw.y = phi;
            *reinterpret_cast<uint2*>(
                &Ps[w][lrow * 64 + chunk * 8 + (lgrp & 1) * 4]) = pw;
        }

        const unsigned short* vbuf = &Vs[cur][0];
        __builtin_amdgcn_s_setprio(1);
#pragma unroll
        for (int jc = 0; jc < 2; ++jc) {
            int pc = ((4 * jc + lgrp) ^ (lrow & 7)) * 8;
            bf16x8 pa =
                *reinterpret_cast<const bf16x8*>(&Ps[w][0] + lrow * 64 + pc);
#pragma unroll
            for (int n = 0; n < 4; n++) {
                int vrow = n * 16 + lrow;
                bf16x8 vb =
                    *reinterpret_cast<const bf16x8*>(vbuf + vrow * 64 + pc);
                o_acc[n] = MFMA16(pa, vb, o_acc[n]);
            }
        }
        __builtin_amdgcn_s_setprio(0);

        if (kv < 15) {
            asm volatile("s_waitcnt vmcnt(0)" ::: "memory");
            __syncthreads();
        }
    }

    float lt = l_run + __shfl_xor(l_run, 16);
    lt += __shfl_xor(lt, 32);
    float rl[4];
#pragma unroll
    for (int r = 0; r < 4; ++r) rl[r] = 1.0f / __shfl(lt, lgrp * 4 + r);

    // compact hi-only epilogue (R9)
#pragma unroll
    for (int n = 0; n < 4; n++) {
#pragma unroll
        for (int r = 0; r < 4; r++) {
            float val = o_acc[n][r] * rl[r];
            int ia = qt * 64 + w * 16 + lgrp * 4 + r;
            size_t m = (size_t)b * 1024 + ia;
            int col = h * 64 + n * 16 + lrow;
            A3[m * 1024 + col] = f2bf(val);
        }
    }
}

extern "C" void kernel_launch(void* const* d_in, const int* in_sizes, int n_in,
                              void* d_out, int out_size, void* d_ws,
                              size_t ws_size, hipStream_t stream) {
    const float* x = (const float*)d_in[0];
    const float* w_qkv = (const float*)d_in[1];
    const float* w_out = (const float*)d_in[2];
    const float* rel_bias = (const float*)d_in[3];
    float* out = (float*)d_out;

    char* ws = (char*)d_ws;
    size_t off = 0;
    auto alloc = [&](size_t bytes) {
        char* p = ws + off;
        off += (bytes + 255) & ~(size_t)255;
        return p;
    };
    unsigned short* A1h = (unsigned short*)alloc((size_t)4096 * 1024 * 2);
    unsigned short* W1h = (unsigned short*)alloc((size_t)3072 * 1024 * 2);
    unsigned short* Qb = (unsigned short*)alloc((size_t)64 * 1024 * 64 * 2);
    unsigned short* Kb = (unsigned short*)alloc((size_t)64 * 1024 * 64 * 2);
    unsigned short* Vb = (unsigned short*)alloc((size_t)64 * 1024 * 64 * 2);
    unsigned short* A3h = (unsigned short*)alloc((size_t)4096 * 1024 * 2);
    unsigned short* W3h = (unsigned short*)alloc((size_t)1024 * 1024 * 2);
    // V^T aliases A1h (8 MB each): A1h dead after gemm256_hi; transpose_v after.
    unsigned short* Vtg = A1h;

    hipLaunchKernelGGL(prep_hi_rows, dim3(1024), dim3(256), 0, stream, x, A1h,
                       4096 * 256);
    hipLaunchKernelGGL(prep_hi_wqkv, dim3(768), dim3(256), 0, stream, w_qkv,
                       W1h);
    hipLaunchKernelGGL(prep_hi_rows, dim3(256), dim3(256), 0, stream, w_out,
                       W3h, 1024 * 256);
    hipLaunchKernelGGL(gemm256_hi, dim3(12, 16), dim3(512), 0, stream, A1h, W1h,
                       Qb, Kb, Vb);
    hipLaunchKernelGGL(transpose_v, dim3(16, 64), dim3(256), 0, stream, Vb, Vtg);
    hipLaunchKernelGGL(attn_kernel, dim3(16, 64), dim3(256), 0, stream, Qb, Kb,
                       Vtg, rel_bias, A3h);
    hipLaunchKernelGGL(gemm_out_v4, dim3(512), dim3(256), 0, stream, A3h, W3h,
                       out);
}

// Round 10
// 113.083 us; speedup vs baseline: 2.5499x; 1.1348x over previous
//
#include <hip/hip_runtime.h>
#include <hip/hip_bf16.h>

typedef short bf16x8 __attribute__((ext_vector_type(8)));
typedef float f32x4  __attribute__((ext_vector_type(4)));

typedef __attribute__((address_space(3))) void lds_t;
typedef __attribute__((address_space(1))) void gbl_t;

#define MFMA16(a,b,c) __builtin_amdgcn_mfma_f32_16x16x32_bf16((a),(b),(c),0,0,0)

__device__ __forceinline__ unsigned short f2bf(float f) {
    __hip_bfloat16 h = __float2bfloat16(f);
    return __builtin_bit_cast(unsigned short, h);
}
__device__ __forceinline__ float bf2f(unsigned short u) {
    __hip_bfloat16 h = __builtin_bit_cast(__hip_bfloat16, u);
    return __bfloat162float(h);
}

// f32 [R][1024] -> bf16 hi-only compact [R][1024].  float4 vectorized.
__global__ void prep_hi_rows(const float* __restrict__ src,
                             unsigned short* __restrict__ dst, int total4) {
    for (int idx = blockIdx.x * blockDim.x + threadIdx.x; idx < total4;
         idx += gridDim.x * blockDim.x) {
        int base = idx * 4;
        float4 v = *reinterpret_cast<const float4*>(src + base);
        ushort4 hi;
        hi.x = f2bf(v.x);
        hi.y = f2bf(v.y);
        hi.z = f2bf(v.z);
        hi.w = f2bf(v.w);
        *reinterpret_cast<ushort4*>(dst + base) = hi;
    }
}

// w_qkv [3072][1024], einops row permute (out row n = which*1024+h*64+d reads
// src row d*48+which*16+h) -> bf16 hi-only compact [3072][1024].
__global__ void prep_hi_wqkv(const float* __restrict__ w,
                             unsigned short* __restrict__ dst) {
    for (int idx = blockIdx.x * blockDim.x + threadIdx.x; idx < 3072 * 256;
         idx += gridDim.x * blockDim.x) {
        int base = idx * 4;
        int n = base >> 10, c = base & 1023;
        int d = n & 63, which = n >> 10, h = (n >> 6) & 15;
        int srow = d * 48 + which * 16 + h;
        float4 v = *reinterpret_cast<const float4*>(w + (size_t)srow * 1024 + c);
        ushort4 hi;
        hi.x = f2bf(v.x);
        hi.y = f2bf(v.y);
        hi.z = f2bf(v.z);
        hi.w = f2bf(v.w);
        *reinterpret_cast<ushort4*>(dst + (size_t)n * 1024 + c) = hi;
    }
}

// ============================================================================
// 256x256 hi-only bf16 GEMM for QKV.  (unchanged from R5 — see R4/R5 notes)
// ============================================================================
__global__ __launch_bounds__(512, 2) void gemm256_hi(
    const unsigned short* __restrict__ A, const unsigned short* __restrict__ B,
    unsigned short* __restrict__ outQ, unsigned short* __restrict__ outK,
    unsigned short* __restrict__ outV) {
    __shared__ unsigned short lds[65536];  // A ring [0,32768), B ring [32768,65536)
    const int tid = threadIdx.x;
    const int wid = tid >> 6, lane = tid & 63;
    const int lrow = lane & 15, lgrp = lane >> 4;
    const int wr = wid >> 2, wc = wid & 3;
    const int mtile = blockIdx.y * 256, ntile = blockIdx.x * 256;

    const int csw = lgrp ^ ((lrow >> 1) & 3);
    const int aoff = (wr * 128 + lrow) * 32 + csw * 8;
    const int boff = 32768 + (wc * 64 + lrow) * 32 + csw * 8;

    const int sreg = wid * 2;
    const int srow0 = sreg * 16 + (lane >> 2);
    const int srow1 = (sreg + 1) * 16 + (lane >> 2);
    const int schunk = (lane & 3) ^ ((lane >> 3) & 3);
    const int sdst0 = sreg * 512;

    f32x4 acc[8][4];
#pragma unroll
    for (int i = 0; i < 8; ++i)
#pragma unroll
        for (int j = 0; j < 4; ++j) {
            f32x4 z = {0.f, 0.f, 0.f, 0.f};
            acc[i][j] = z;
        }

#pragma unroll
    for (int s0 = 0; s0 < 2; ++s0) {
        const int kb = s0 * 32;
        __builtin_amdgcn_global_load_lds(
            (const gbl_t*)(A + (size_t)(mtile + srow0) * 1024 + kb + schunk * 8),
            (lds_t*)(lds + s0 * 8192 + sdst0), 16, 0, 0);
        __builtin_amdgcn_global_load_lds(
            (const gbl_t*)(A + (size_t)(mtile + srow1) * 1024 + kb + schunk * 8),
            (lds_t*)(lds + s0 * 8192 + sdst0 + 512), 16, 0, 0);
        __builtin_amdgcn_global_load_lds(
            (const gbl_t*)(B + (size_t)(ntile + srow0) * 1024 + kb + schunk * 8),
            (lds_t*)(lds + 32768 + s0 * 8192 + sdst0), 16, 0, 0);
        __builtin_amdgcn_global_load_lds(
            (const gbl_t*)(B + (size_t)(ntile + srow1) * 1024 + kb + schunk * 8),
            (lds_t*)(lds + 32768 + s0 * 8192 + sdst0 + 512), 16, 0, 0);
    }
    asm volatile("s_waitcnt vmcnt(4)" ::: "memory");
    __syncthreads();

    for (int s = 0; s < 32; ++s) {
        const int sa = s & 3;
        const unsigned short* sbase = lds + sa * 8192;

        bf16x8 af[8];
#pragma unroll
        for (int i = 0; i < 8; ++i)
            af[i] = *reinterpret_cast<const bf16x8*>(sbase + aoff + i * 512);
        bf16x8 b0 = *reinterpret_cast<const bf16x8*>(sbase + boff);
        bf16x8 b1 = *reinterpret_cast<const bf16x8*>(sbase + boff + 512);

        if (s <= 29) {
            const int kb2 = (s + 2) * 32;
            const int s2 = (s + 2) & 3;
            __builtin_amdgcn_global_load_lds(
                (const gbl_t*)(A + (size_t)(mtile + srow0) * 1024 + kb2 + schunk * 8),
                (lds_t*)(lds + s2 * 8192 + sdst0), 16, 0, 0);
            __builtin_amdgcn_global_load_lds(
                (const gbl_t*)(A + (size_t)(mtile + srow1) * 1024 + kb2 + schunk * 8),
                (lds_t*)(lds + s2 * 8192 + sdst0 + 512), 16, 0, 0);
        }
        __builtin_amdgcn_s_setprio(1);
#pragma unroll
        for (int i = 0; i < 8; ++i) {
            acc[i][0] = MFMA16(af[i], b0, acc[i][0]);
            acc[i][1] = MFMA16(af[i], b1, acc[i][1]);
        }
        __builtin_amdgcn_s_setprio(0);

        bf16x8 b2 = *reinterpret_cast<const bf16x8*>(sbase + boff + 1024);
        bf16x8 b3 = *reinterpret_cast<const bf16x8*>(sbase + boff + 1536);
        if (s <= 29) {
            const int kb2 = (s + 2) * 32;
            const int s2 = (s + 2) & 3;
            __builtin_amdgcn_global_load_lds(
                (const gbl_t*)(B + (size_t)(ntile + srow0) * 1024 + kb2 + schunk * 8),
                (lds_t*)(lds + 32768 + s2 * 8192 + sdst0), 16, 0, 0);
            __builtin_amdgcn_global_load_lds(
                (const gbl_t*)(B + (size_t)(ntile + srow1) * 1024 + kb2 + schunk * 8),
                (lds_t*)(lds + 32768 + s2 * 8192 + sdst0 + 512), 16, 0, 0);
        }
        __builtin_amdgcn_s_setprio(1);
#pragma unroll
        for (int i = 0; i < 8; ++i) {
            acc[i][2] = MFMA16(af[i], b2, acc[i][2]);
            acc[i][3] = MFMA16(af[i], b3, acc[i][3]);
        }
        __builtin_amdgcn_s_setprio(0);

        if (s < 31) {
            if (s <= 29)
                asm volatile("s_waitcnt vmcnt(4)" ::: "memory");
            else
                asm volatile("s_waitcnt vmcnt(0)" ::: "memory");
            __syncthreads();
        }
    }

#pragma unroll
    for (int i = 0; i < 8; ++i) {
#pragma unroll
        for (int j = 0; j < 4; ++j) {
#pragma unroll
            for (int r = 0; r < 4; ++r) {
                float v = acc[i][j][r];
                int m = mtile + wr * 128 + i * 16 + lgrp * 4 + r;
                int n = ntile + wc * 64 + j * 16 + lrow;
                int which = n >> 10;
                int hh = (n >> 6) & 15;
                int d = n & 63;
                int b = m >> 10, t = m & 1023;
                unsigned short* dstp =
                    (which == 0) ? outQ : ((which == 1) ? outK : outV);
                dstp[((size_t)((b << 4) + hh) * 1024 + t) * 64 + d] = f2bf(v);
            }
        }
    }
}

// ============================================================================
// Out-projection GEMM v4 (R9, unchanged): hi-only bf16, K=1024, 64x128 tile,
// 512 blocks, 4-slot ring, counted vmcnt(3), XCD swizzle, 0 conflicts.
// ============================================================================
__global__ __launch_bounds__(256, 3) void gemm_out_v4(
    const unsigned short* __restrict__ A, const unsigned short* __restrict__ B,
    float* __restrict__ outF) {
    __shared__ unsigned short As[4][64 * 32];   // 16 KB ring
    __shared__ unsigned short Bs[4][128 * 32];  // 32 KB ring
    const int tid = threadIdx.x;
    const int wid = tid >> 6, lane = tid & 63;
    const int lrow = lane & 15, lgrp = lane >> 4;
    const int wr = wid >> 1, wc = wid & 1;
    const int h = blockIdx.x;
    const int xcd = h & 7, within = h >> 3;
    const int mtile = (xcd * 8 + (within & 7)) * 64;
    const int ntile = (within >> 3) * 128;

    const int csw = lgrp ^ ((lrow >> 1) & 3);
    const int aoff = (wr * 32 + lrow) * 32 + csw * 8;  // + i*512
    const int boff = (wc * 64 + lrow) * 32 + csw * 8;  // + j*512

    const int srow = tid >> 2;                        // 0..63
    const int schunk = (tid & 3) ^ ((tid >> 3) & 3);  // inverse-swizzled src
    const unsigned short* Arow = A + (size_t)(mtile + srow) * 1024 + schunk * 8;
    const unsigned short* Brow0 = B + (size_t)(ntile + srow) * 1024 + schunk * 8;
    const unsigned short* Brow1 =
        B + (size_t)(ntile + 64 + srow) * 1024 + schunk * 8;

    f32x4 acc[2][4];
#pragma unroll
    for (int i = 0; i < 2; ++i)
#pragma unroll
        for (int j = 0; j < 4; ++j) {
            f32x4 z = {0.f, 0.f, 0.f, 0.f};
            acc[i][j] = z;
        }

#pragma unroll
    for (int s0 = 0; s0 < 2; ++s0) {
        const int kb = s0 * 32;
        __builtin_amdgcn_global_load_lds((const gbl_t*)(Arow + kb),
                                         (lds_t*)(&As[s0][0] + tid * 8), 16, 0,
                                         0);
        __builtin_amdgcn_global_load_lds((const gbl_t*)(Brow0 + kb),
                                         (lds_t*)(&Bs[s0][0] + tid * 8), 16, 0,
                                         0);
        __builtin_amdgcn_global_load_lds((const gbl_t*)(Brow1 + kb),
                                         (lds_t*)(&Bs[s0][0] + 2048 + tid * 8),
                                         16, 0, 0);
    }
    asm volatile("s_waitcnt vmcnt(3)" ::: "memory");  // slot 0 landed
    __syncthreads();

    for (int s = 0; s < 32; ++s) {
        const int sa = s & 3;
        if (s <= 29) {
            const int kb = (s + 2) * 32;
            const int s2 = (s + 2) & 3;
            __builtin_amdgcn_global_load_lds((const gbl_t*)(Arow + kb),
                                             (lds_t*)(&As[s2][0] + tid * 8), 16,
                                             0, 0);
            __builtin_amdgcn_global_load_lds((const gbl_t*)(Brow0 + kb),
                                             (lds_t*)(&Bs[s2][0] + tid * 8), 16,
                                             0, 0);
            __builtin_amdgcn_global_load_lds(
                (const gbl_t*)(Brow1 + kb),
                (lds_t*)(&Bs[s2][0] + 2048 + tid * 8), 16, 0, 0);
        }
        bf16x8 af[2], bfv[4];
#pragma unroll
        for (int i = 0; i < 2; ++i)
            af[i] = *reinterpret_cast<const bf16x8*>(&As[sa][0] + aoff + i * 512);
#pragma unroll
        for (int j = 0; j < 4; ++j)
            bfv[j] =
                *reinterpret_cast<const bf16x8*>(&Bs[sa][0] + boff + j * 512);
        __builtin_amdgcn_s_setprio(1);
#pragma unroll
        for (int i = 0; i < 2; ++i)
#pragma unroll
            for (int j = 0; j < 4; ++j)
                acc[i][j] = MFMA16(af[i], bfv[j], acc[i][j]);
        __builtin_amdgcn_s_setprio(0);
        if (s < 31) {
            if (s <= 29)
                asm volatile("s_waitcnt vmcnt(3)" ::: "memory");
            else
                asm volatile("s_waitcnt vmcnt(0)" ::: "memory");
            __syncthreads();
        }
    }

#pragma unroll
    for (int i = 0; i < 2; ++i)
#pragma unroll
        for (int j = 0; j < 4; ++j)
#pragma unroll
            for (int r = 0; r < 4; ++r) {
                int m = mtile + wr * 32 + i * 16 + lgrp * 4 + r;
                int n = ntile + wc * 64 + j * 16 + lrow;
                outF[(size_t)m * 1024 + n] = acc[i][j][r];
            }
}

// V [bh][1024][64] -> V^T [bh][64][1024], LDS-tiled, coalesced both sides.
__global__ __launch_bounds__(256) void transpose_v(
    const unsigned short* __restrict__ Vb, unsigned short* __restrict__ Vtg) {
    __shared__ unsigned short L[64][72];
    const int tt = blockIdx.x, bh = blockIdx.y;
    const int tid = threadIdx.x;
#pragma unroll
    for (int e = 0; e < 2; ++e) {
        int chunk = e * 256 + tid;
        int r = chunk >> 3, c = (chunk & 7) * 8;
        uint4 v = *reinterpret_cast<const uint4*>(
            Vb + ((size_t)bh * 1024 + tt * 64 + r) * 64 + c);
        *reinterpret_cast<uint4*>(&L[r][c]) = v;
    }
    __syncthreads();
#pragma unroll
    for (int e = 0; e < 2; ++e) {
        int chunk = e * 256 + tid;
        int d = chunk >> 3, t0 = (chunk & 7) * 8;
        unsigned short tmp[8];
#pragma unroll
        for (int u = 0; u < 8; ++u) tmp[u] = L[t0 + u][d];
        *reinterpret_cast<uint4*>(Vtg + ((size_t)bh * 64 + d) * 1024 + tt * 64 +
                                  t0) = *reinterpret_cast<const uint4*>(tmp);
    }
}

// ============================================================================
// Flash attention R10: QBLK=128, 8 waves/block (512 thr), grid (8, 64).
// R9 post-mortem: 4-wave blocks at 20% occupancy can't hide the per-tile
// barrier+softmax chain, and 16 q-tile blocks re-stream K/V (FETCH 70MB).
// Doubling the Q tile halves K/V traffic and gives 8 waves x 3 blocks/CU
// (LDS ~50KB) of co-resident waves at different phases.  Per-wave math is
// byte-identical to R6-R9 (swapped QK^T, exp2 softmax, defer-max, cvt_pk).
// Staging: each wave stages 8 K-rows + 8 V^T-rows (1 global_load_lds each,
// same XOR swizzle/layout).  Bias strip widens to 192 (idx = jl-il+127).
// ============================================================================
__global__ __launch_bounds__(512) void attn_kernel(
    const unsigned short* __restrict__ Qb, const unsigned short* __restrict__ Kb,
    const unsigned short* __restrict__ Vtg, const float* __restrict__ rel_bias,
    unsigned short* __restrict__ A3) {
    const int qt = blockIdx.x;  // 0..7 (128 q-rows each)
    const int bh = blockIdx.y;  // 0..63
    const int b = bh >> 4, h = bh & 15;
    const int tid = threadIdx.x;
    const int w = tid >> 6, lane = tid & 63;  // w in 0..7
    const int lrow = lane & 15, lgrp = lane >> 4;
    const float LOG2E = 1.4426950408889634f;
    const float SCALE2 = 0.125f * 1.4426950408889634f;
    const float THR = 11.5f;  // ~8 nats in exp2 units

    __shared__ unsigned short Ks[2][64 * 64];  // 16 KB
    __shared__ unsigned short Vs[2][64 * 64];  // 16 KB
    __shared__ unsigned short Ps[8][16 * 64];  // 16 KB
    __shared__ float Bias2[2][192];

    const unsigned short* Ktile = Kb + (size_t)bh * 1024 * 64;
    const unsigned short* Vtile = Vtg + (size_t)bh * 64 * 1024;

    const unsigned short* Qp =
        Qb + ((size_t)bh * 1024 + qt * 128 + w * 16 + lrow) * 64;
    bf16x8 qa0 = *reinterpret_cast<const bf16x8*>(Qp + lgrp * 8);
    bf16x8 qa1 = *reinterpret_cast<const bf16x8*>(Qp + 32 + lgrp * 8);

    // staging: wave w covers rows [w*8, w*8+8) of K and of V^T (1 issue each)
    const int sr0 = w * 8 + (lane >> 3);
    const int sc_lo = lane & 7;

    float m_run = -3.0e38f;
    float l_run = 0.f;
    f32x4 o_acc[4];
#pragma unroll
    for (int n = 0; n < 4; n++) {
        f32x4 z = {0.f, 0.f, 0.f, 0.f};
        o_acc[n] = z;
    }

    // Bias2 index for (f, r): bbase + f*16 + r  =  jl - il + 127, range [0,190]
    const int bbase = lgrp * 4 + 127 - w * 16 - lrow;

    {
        {
            int r = sr0;
            int c = sc_lo ^ (r & 7);
            __builtin_amdgcn_global_load_lds(
                (const gbl_t*)(Ktile + (size_t)r * 64 + c * 8),
                (lds_t*)(&Ks[0][0] + w * 512), 16, 0, 0);
            __builtin_amdgcn_global_load_lds(
                (const gbl_t*)(Vtile + (size_t)r * 1024 + c * 8),
                (lds_t*)(&Vs[0][0] + w * 512), 16, 0, 0);
        }
        if (tid < 192) {
            int rowi = 0 - qt * 128 + 896 + tid;
            rowi = (rowi < 2046) ? rowi : 2046;
            Bias2[0][tid] = rel_bias[(size_t)rowi * 16 + h] * LOG2E;
        }
        asm volatile("s_waitcnt vmcnt(0)" ::: "memory");
        __syncthreads();
    }

    for (int kv = 0; kv < 16; ++kv) {
        const int cur = kv & 1;
        if (kv < 15) {
            const int j0n = (kv + 1) * 64;
            int r = sr0;
            int c = sc_lo ^ (r & 7);
            __builtin_amdgcn_global_load_lds(
                (const gbl_t*)(Ktile + (size_t)(j0n + r) * 64 + c * 8),
                (lds_t*)(&Ks[cur ^ 1][0] + w * 512), 16, 0, 0);
            __builtin_amdgcn_global_load_lds(
                (const gbl_t*)(Vtile + (size_t)r * 1024 + j0n + c * 8),
                (lds_t*)(&Vs[cur ^ 1][0] + w * 512), 16, 0, 0);
            if (tid < 192) {
                int rowi = j0n - qt * 128 + 896 + tid;
                rowi = (rowi < 2046) ? rowi : 2046;
                Bias2[cur ^ 1][tid] = rel_bias[(size_t)rowi * 16 + h] * LOG2E;
            }
        }

        // ---- S^T = K Q^T (swapped): lane holds S[j=f*16+lgrp*4+r][i=lrow] ----
        const unsigned short* kbuf = &Ks[cur][0];
        f32x4 s[4];
        __builtin_amdgcn_s_setprio(1);
#pragma unroll
        for (int f = 0; f < 4; ++f) {
            int krow = f * 16 + lrow;
            int sw0 = (lgrp ^ (lrow & 7)) * 8;
            int sw1 = ((4 | lgrp) ^ (lrow & 7)) * 8;
            bf16x8 kb0 = *reinterpret_cast<const bf16x8*>(kbuf + krow * 64 + sw0);
            bf16x8 kb1 = *reinterpret_cast<const bf16x8*>(kbuf + krow * 64 + sw1);
            f32x4 z = {0.f, 0.f, 0.f, 0.f};
            z = MFMA16(kb0, qa0, z);
            z = MFMA16(kb1, qa1, z);
            s[f] = z;
        }
        __builtin_amdgcn_s_setprio(0);

        // ---- softmax, row-local (exp2 domain) ----
        float x[4][4];
        float pm = -3.0e38f;
#pragma unroll
        for (int f = 0; f < 4; ++f)
#pragma unroll
            for (int r = 0; r < 4; ++r) {
                float xv = s[f][r] * SCALE2 + Bias2[cur][bbase + f * 16 + r];
                x[f][r] = xv;
                pm = fmaxf(pm, xv);
            }
        pm = fmaxf(pm, __shfl_xor(pm, 16));
        pm = fmaxf(pm, __shfl_xor(pm, 32));

        if (!__all(pm - m_run <= THR)) {
            float mnew = fmaxf(m_run, pm);
            float corr = __builtin_amdgcn_exp2f(m_run - mnew);
            m_run = mnew;
            l_run *= corr;
            float cb[4];
#pragma unroll
            for (int r = 0; r < 4; ++r) cb[r] = __shfl(corr, lgrp * 4 + r);
#pragma unroll
            for (int n = 0; n < 4; n++)
#pragma unroll
                for (int r = 0; r < 4; r++) o_acc[n][r] *= cb[r];
        }

        float su = 0.f;
#pragma unroll
        for (int f = 0; f < 4; ++f)
#pragma unroll
            for (int r = 0; r < 4; ++r) {
                float pv = __builtin_amdgcn_exp2f(x[f][r] - m_run);
                x[f][r] = pv;
                su += pv;
            }
        l_run += su;

        // ---- P -> Ps (swizzled layout; 4x b64 writes) ----
#pragma unroll
        for (int f = 0; f < 4; ++f) {
            unsigned int plo, phi;
            asm("v_cvt_pk_bf16_f32 %0, %1, %2"
                : "=v"(plo)
                : "v"(x[f][0]), "v"(x[f][1]));
            asm("v_cvt_pk_bf16_f32 %0, %1, %2"
                : "=v"(phi)
                : "v"(x[f][2]), "v"(x[f][3]));
            const int chunk = (f * 2 + (lgrp >> 1)) ^ (lrow & 7);
            uint2 pw;
            pw.x = plo;
            pw.y = phi;
            *reinterpret_cast<uint2*>(
                &Ps[w][lrow * 64 + chunk * 8 + (lgrp & 1) * 4]) = pw;
        }

        // ---- O += P V ----
        const unsigned short* vbuf = &Vs[cur][0];
        __builtin_amdgcn_s_setprio(1);
#pragma unroll
        for (int jc = 0; jc < 2; ++jc) {
            int pc = ((4 * jc + lgrp) ^ (lrow & 7)) * 8;
            bf16x8 pa =
                *reinterpret_cast<const bf16x8*>(&Ps[w][0] + lrow * 64 + pc);
#pragma unroll
            for (int n = 0; n < 4; n++) {
                int vrow = n * 16 + lrow;
                bf16x8 vb =
                    *reinterpret_cast<const bf16x8*>(vbuf + vrow * 64 + pc);
                o_acc[n] = MFMA16(pa, vb, o_acc[n]);
            }
        }
        __builtin_amdgcn_s_setprio(0);

        if (kv < 15) {
            asm volatile("s_waitcnt vmcnt(0)" ::: "memory");
            __syncthreads();
        }
    }

    float lt = l_run + __shfl_xor(l_run, 16);
    lt += __shfl_xor(lt, 32);
    float rl[4];
#pragma unroll
    for (int r = 0; r < 4; ++r) rl[r] = 1.0f / __shfl(lt, lgrp * 4 + r);

    // compact hi-only epilogue
#pragma unroll
    for (int n = 0; n < 4; n++) {
#pragma unroll
        for (int r = 0; r < 4; r++) {
            float val = o_acc[n][r] * rl[r];
            int ia = qt * 128 + w * 16 + lgrp * 4 + r;
            size_t m = (size_t)b * 1024 + ia;
            int col = h * 64 + n * 16 + lrow;
            A3[m * 1024 + col] = f2bf(val);
        }
    }
}

extern "C" void kernel_launch(void* const* d_in, const int* in_sizes, int n_in,
                              void* d_out, int out_size, void* d_ws,
                              size_t ws_size, hipStream_t stream) {
    const float* x = (const float*)d_in[0];
    const float* w_qkv = (const float*)d_in[1];
    const float* w_out = (const float*)d_in[2];
    const float* rel_bias = (const float*)d_in[3];
    float* out = (float*)d_out;

    char* ws = (char*)d_ws;
    size_t off = 0;
    auto alloc = [&](size_t bytes) {
        char* p = ws + off;
        off += (bytes + 255) & ~(size_t)255;
        return p;
    };
    unsigned short* A1h = (unsigned short*)alloc((size_t)4096 * 1024 * 2);
    unsigned short* W1h = (unsigned short*)alloc((size_t)3072 * 1024 * 2);
    unsigned short* Qb = (unsigned short*)alloc((size_t)64 * 1024 * 64 * 2);
    unsigned short* Kb = (unsigned short*)alloc((size_t)64 * 1024 * 64 * 2);
    unsigned short* Vb = (unsigned short*)alloc((size_t)64 * 1024 * 64 * 2);
    unsigned short* A3h = (unsigned short*)alloc((size_t)4096 * 1024 * 2);
    unsigned short* W3h = (unsigned short*)alloc((size_t)1024 * 1024 * 2);
    // V^T aliases A1h (8 MB each): A1h dead after gemm256_hi; transpose_v after.
    unsigned short* Vtg = A1h;

    hipLaunchKernelGGL(prep_hi_rows, dim3(1024), dim3(256), 0, stream, x, A1h,
                       4096 * 256);
    hipLaunchKernelGGL(prep_hi_wqkv, dim3(768), dim3(256), 0, stream, w_qkv,
                       W1h);
    hipLaunchKernelGGL(prep_hi_rows, dim3(256), dim3(256), 0, stream, w_out,
                       W3h, 1024 * 256);
    hipLaunchKernelGGL(gemm256_hi, dim3(12, 16), dim3(512), 0, stream, A1h, W1h,
                       Qb, Kb, Vb);
    hipLaunchKernelGGL(transpose_v, dim3(16, 64), dim3(256), 0, stream, Vb, Vtg);
    hipLaunchKernelGGL(attn_kernel, dim3(8, 64), dim3(512), 0, stream, Qb, Kb,
                       Vtg, rel_bias, A3h);
    hipLaunchKernelGGL(gemm_out_v4, dim3(512), dim3(256), 0, stream, A3h, W3h,
                       out);
}